// Round 1
// baseline (7805.913 us; speedup 1.0000x reference)
//
#include <hip/hip_runtime.h>
#include <math.h>

typedef __bf16 bf16_t;
typedef bf16_t bf16x4 __attribute__((ext_vector_type(4)));
typedef bf16_t bf16x8 __attribute__((ext_vector_type(8)));
typedef float  f32x4  __attribute__((ext_vector_type(4)));

#define RMS_EPS 1e-6f

enum { EP_STORE = 0, EP_RESID = 1, EP_ATTN = 2 };

static __device__ __forceinline__ f32x4 mfma16(bf16x8 a, bf16x8 b, f32x4 c) {
    return __builtin_amdgcn_mfma_f32_16x16x32_bf16(a, b, c, 0, 0, 0);
}

// C[M,N] = A[M,K] * B[N,K]^T   (A,B fp32 row-major; split-bf16 hi/lo, 3 MFMAs)
// grid: (M/BM, N/BN, batch); strides sA_,sB_,sC_ are per-batch element offsets.
template<int BM, int BN, int WM, int WN, int EPIL, bool CAUSAL_K>
__global__ __launch_bounds__(256, 2)
void gemm_kernel(const float* __restrict__ A, const float* __restrict__ B,
                 float* __restrict__ C, int K, int lda, int ldb, int ldc,
                 long long sA_, long long sB_, long long sC_, float scale)
{
    constexpr int LDK = 40;  // 32 + 8 pad (keeps 16B row-stride alignment: 80B)
    __shared__ __align__(16) bf16_t sAh[BM][LDK], sAl[BM][LDK];
    __shared__ __align__(16) bf16_t sBh[BN][LDK], sBl[BN][LDK];

    const int bm = blockIdx.x, bn = blockIdx.y;
    const int row0 = bm * BM, col0 = bn * BN;
    A += (size_t)blockIdx.z * sA_;
    B += (size_t)blockIdx.z * sB_;
    C += (size_t)blockIdx.z * sC_;

    const int tid  = threadIdx.x;
    const int lane = tid & 63;
    const int wave = tid >> 6;
    constexpr int NWN = BN / WN;
    const int wm = wave / NWN, wn = wave % NWN;
    constexpr int MF = WM / 16, NF = WN / 16;
    const int lr = lane & 15, lg = lane >> 4;

    f32x4 acc[MF][NF];
    #pragma unroll
    for (int m = 0; m < MF; ++m)
        #pragma unroll
        for (int n = 0; n < NF; ++n) acc[m][n] = (f32x4){0.f, 0.f, 0.f, 0.f};

    int kend = K;
    if constexpr (EPIL == EP_ATTN) { if (col0 >= row0 + BM) kend = 0; }  // fully-masked tile
    if constexpr (CAUSAL_K) { int lim = row0 + BM; if (lim < kend) kend = lim; }

    for (int k0 = 0; k0 < kend; k0 += 32) {
        __syncthreads();
        #pragma unroll
        for (int i = 0; i < BM / 32; ++i) {
            int idx = i * 256 + tid;
            int r = idx >> 3, c = (idx & 7) * 4;
            f32x4 val = *(const f32x4*)(A + (size_t)(row0 + r) * lda + k0 + c);
            bf16x4 hv, lv;
            #pragma unroll
            for (int j = 0; j < 4; ++j) {
                bf16_t hb = (bf16_t)val[j];
                hv[j] = hb;
                lv[j] = (bf16_t)(val[j] - (float)hb);
            }
            *(bf16x4*)&sAh[r][c] = hv;
            *(bf16x4*)&sAl[r][c] = lv;
        }
        #pragma unroll
        for (int i = 0; i < BN / 32; ++i) {
            int idx = i * 256 + tid;
            int r = idx >> 3, c = (idx & 7) * 4;
            f32x4 val = *(const f32x4*)(B + (size_t)(col0 + r) * ldb + k0 + c);
            bf16x4 hv, lv;
            #pragma unroll
            for (int j = 0; j < 4; ++j) {
                bf16_t hb = (bf16_t)val[j];
                hv[j] = hb;
                lv[j] = (bf16_t)(val[j] - (float)hb);
            }
            *(bf16x4*)&sBh[r][c] = hv;
            *(bf16x4*)&sBl[r][c] = lv;
        }
        __syncthreads();

        bf16x8 ah[MF], al[MF], bh[NF], bl[NF];
        #pragma unroll
        for (int m = 0; m < MF; ++m) {
            ah[m] = *(const bf16x8*)&sAh[wm * WM + m * 16 + lr][8 * lg];
            al[m] = *(const bf16x8*)&sAl[wm * WM + m * 16 + lr][8 * lg];
        }
        #pragma unroll
        for (int n = 0; n < NF; ++n) {
            bh[n] = *(const bf16x8*)&sBh[wn * WN + n * 16 + lr][8 * lg];
            bl[n] = *(const bf16x8*)&sBl[wn * WN + n * 16 + lr][8 * lg];
        }
        #pragma unroll
        for (int m = 0; m < MF; ++m)
            #pragma unroll
            for (int n = 0; n < NF; ++n) {
                acc[m][n] = mfma16(ah[m], bh[n], acc[m][n]);
                acc[m][n] = mfma16(ah[m], bl[n], acc[m][n]);
                acc[m][n] = mfma16(al[m], bh[n], acc[m][n]);
            }
    }

    #pragma unroll
    for (int m = 0; m < MF; ++m)
        #pragma unroll
        for (int n = 0; n < NF; ++n)
            #pragma unroll
            for (int r = 0; r < 4; ++r) {
                int grow = row0 + wm * WM + m * 16 + lg * 4 + r;
                int gcol = col0 + wn * WN + n * 16 + lr;
                size_t off = (size_t)grow * ldc + gcol;
                float v = acc[m][n][r];
                if constexpr (EPIL == EP_STORE) {
                    C[off] = v;
                } else if constexpr (EPIL == EP_RESID) {
                    C[off] += v;
                } else {  // EP_ATTN: scale, softcap, causal mask
                    v *= scale;
                    v = 50.0f * tanhf(v * 0.02f);
                    if (gcol > grow) v = -1e30f;
                    C[off] = v;
                }
            }
}

__global__ __launch_bounds__(256)
void gather_kernel(const int* __restrict__ ids, const float* __restrict__ embed,
                   float* __restrict__ h)
{
    int t = blockIdx.x;
    int row = ids[t];
    const f32x4* src = (const f32x4*)(embed + (size_t)row * 1024);
    f32x4* dst = (f32x4*)(h + (size_t)t * 1024);
    dst[threadIdx.x] = src[threadIdx.x];
}

__global__ __launch_bounds__(256)
void rmsnorm_kernel(const float* __restrict__ in, const float* __restrict__ w,
                    float* __restrict__ out)
{
    int row = blockIdx.x, tid = threadIdx.x;
    f32x4 v = *(const f32x4*)(in + (size_t)row * 1024 + tid * 4);
    float ss = v[0]*v[0] + v[1]*v[1] + v[2]*v[2] + v[3]*v[3];
    #pragma unroll
    for (int m = 1; m < 64; m <<= 1) ss += __shfl_xor(ss, m, 64);
    __shared__ float red[4];
    if ((tid & 63) == 0) red[tid >> 6] = ss;
    __syncthreads();
    float tot = red[0] + red[1] + red[2] + red[3];
    float inv = rsqrtf(tot * (1.0f / 1024.0f) + RMS_EPS);
    f32x4 wv = *(const f32x4*)(w + tid * 4);
    f32x4 ov;
    #pragma unroll
    for (int j = 0; j < 4; ++j) ov[j] = v[j] * inv * wv[j];
    *(f32x4*)(out + (size_t)row * 1024 + tid * 4) = ov;
}

// Per-(t,head) RMS-norm over Dh=64 + RoPE. NOTE the reference's quirk:
// _rope uses cos[:n] with n = x.shape[1] = H (head axis), so the rotation
// angle is  head_index * freq  — independent of the sequence position t.
__global__ __launch_bounds__(256)
void qknorm_rope_kernel(float* __restrict__ q, float* __restrict__ k,
                        const float* __restrict__ qn, const float* __restrict__ kn)
{
    int t = blockIdx.x, tid = threadIdx.x;
    int hh = tid >> 4;        // head 0..15
    int i  = (tid & 15) * 4;  // dim within head, multiple of 4
    size_t base = (size_t)t * 1024 + hh * 64 + i;

    int p0 = i >> 1;
    float f0 = powf(10000.f, -(float)p0 / 32.f);
    float f1 = powf(10000.f, -(float)(p0 + 1) / 32.f);
    float a0 = (float)hh * f0, a1 = (float)hh * f1;
    float c0 = cosf(a0), s0 = sinf(a0);
    float c1 = cosf(a1), s1 = sinf(a1);

    f32x4 qw = *(const f32x4*)(qn + i);
    f32x4 kw = *(const f32x4*)(kn + i);

    {
        f32x4 v = *(f32x4*)(q + base);
        float ss = v[0]*v[0] + v[1]*v[1] + v[2]*v[2] + v[3]*v[3];
        #pragma unroll
        for (int m = 1; m < 16; m <<= 1) ss += __shfl_xor(ss, m, 64);
        float inv = rsqrtf(ss * (1.0f / 64.0f) + RMS_EPS);
        float x0 = v[0]*inv*qw[0], x1 = v[1]*inv*qw[1];
        float x2 = v[2]*inv*qw[2], x3 = v[3]*inv*qw[3];
        f32x4 r;
        r[0] = x0*c0 - x1*s0;  r[1] = x0*s0 + x1*c0;
        r[2] = x2*c1 - x3*s1;  r[3] = x2*s1 + x3*c1;
        *(f32x4*)(q + base) = r;
    }
    {
        f32x4 v = *(f32x4*)(k + base);
        float ss = v[0]*v[0] + v[1]*v[1] + v[2]*v[2] + v[3]*v[3];
        #pragma unroll
        for (int m = 1; m < 16; m <<= 1) ss += __shfl_xor(ss, m, 64);
        float inv = rsqrtf(ss * (1.0f / 64.0f) + RMS_EPS);
        float x0 = v[0]*inv*kw[0], x1 = v[1]*inv*kw[1];
        float x2 = v[2]*inv*kw[2], x3 = v[3]*inv*kw[3];
        f32x4 r;
        r[0] = x0*c0 - x1*s0;  r[1] = x0*s0 + x1*c0;
        r[2] = x2*c1 - x3*s1;  r[3] = x2*s1 + x3*c1;
        *(f32x4*)(k + base) = r;
    }
}

__global__ __launch_bounds__(256)
void transpose_kernel(const float* __restrict__ in, float* __restrict__ out)
{
    __shared__ float tile[32][33];
    int bx = blockIdx.x * 32, by = blockIdx.y * 32;
    int r = threadIdx.x >> 5, c = threadIdx.x & 31;
    #pragma unroll
    for (int rr = r; rr < 32; rr += 8)
        tile[rr][c] = in[(size_t)(by + rr) * 1024 + bx + c];
    __syncthreads();
    #pragma unroll
    for (int rr = r; rr < 32; rr += 8)
        out[(size_t)(bx + rr) * 1024 + by + c] = tile[c][rr];
}

__global__ __launch_bounds__(256)
void softmax_kernel(float* __restrict__ s)
{
    float* row = s + (size_t)blockIdx.x * 1024;
    int tid = threadIdx.x;
    f32x4 v = *(const f32x4*)(row + tid * 4);
    float mx = fmaxf(fmaxf(v[0], v[1]), fmaxf(v[2], v[3]));
    #pragma unroll
    for (int m = 1; m < 64; m <<= 1) mx = fmaxf(mx, __shfl_xor(mx, m, 64));
    __shared__ float red[8];
    if ((tid & 63) == 0) red[tid >> 6] = mx;
    __syncthreads();
    mx = fmaxf(fmaxf(red[0], red[1]), fmaxf(red[2], red[3]));
    f32x4 e;
    float sum = 0.f;
    #pragma unroll
    for (int j = 0; j < 4; ++j) { e[j] = expf(v[j] - mx); sum += e[j]; }
    #pragma unroll
    for (int m = 1; m < 64; m <<= 1) sum += __shfl_xor(sum, m, 64);
    if ((tid & 63) == 0) red[4 + (tid >> 6)] = sum;
    __syncthreads();
    sum = red[4] + red[5] + red[6] + red[7];
    float inv = 1.0f / sum;
    #pragma unroll
    for (int j = 0; j < 4; ++j) e[j] *= inv;
    *(f32x4*)(row + tid * 4) = e;
}

__global__ __launch_bounds__(256)
void silu_mul_kernel(const float* g, const float* u, float* out)
{
    size_t i = ((size_t)blockIdx.x * 256 + threadIdx.x) * 4;
    f32x4 gv = *(const f32x4*)(g + i);
    f32x4 uv = *(const f32x4*)(u + i);
    f32x4 ov;
    #pragma unroll
    for (int j = 0; j < 4; ++j) {
        float sg = gv[j] / (1.0f + expf(-gv[j]));
        ov[j] = sg * uv[j];
    }
    *(f32x4*)(out + i) = ov;
}

extern "C" void kernel_launch(void* const* d_in, const int* in_sizes, int n_in,
                              void* d_out, int out_size, void* d_ws, size_t ws_size,
                              hipStream_t stream)
{
    (void)in_sizes; (void)n_in; (void)out_size; (void)ws_size;
    const int*   x_ids = (const int*)  d_in[0];
    const float* embed = (const float*)d_in[1];
    const float* ln1   = (const float*)d_in[2];
    const float* Wq    = (const float*)d_in[3];
    const float* Wk    = (const float*)d_in[4];
    const float* Wv    = (const float*)d_in[5];
    const float* Wo    = (const float*)d_in[6];
    const float* qn    = (const float*)d_in[7];
    const float* kn    = (const float*)d_in[8];
    const float* ln2   = (const float*)d_in[9];
    const float* Wg    = (const float*)d_in[10];
    const float* Wu    = (const float*)d_in[11];
    const float* Wd    = (const float*)d_in[12];
    const float* lnout = (const float*)d_in[13];
    float* out = (float*)d_out;

    char* ws = (char*)d_ws;
    const size_t MB = 1 << 20;
    float* h  = (float*)(ws + 0 * MB);    //  4 MB [1024][1024]
    float* hn = (float*)(ws + 4 * MB);    //  4 MB
    float* q  = (float*)(ws + 8 * MB);    //  4 MB
    float* k  = (float*)(ws + 12 * MB);   //  4 MB
    float* v  = (float*)(ws + 16 * MB);   //  4 MB
    float* vT = (float*)(ws + 20 * MB);   //  4 MB [1024][1024] transposed
    float* o  = (float*)(ws + 24 * MB);   //  4 MB
    float* g  = (float*)(ws + 28 * MB);   // 16 MB [1024][4096]
    float* u  = (float*)(ws + 44 * MB);   // 16 MB
    float* sc = (float*)(ws + 60 * MB);   // 64 MB [16][1024][1024]

    gather_kernel<<<1024, 256, 0, stream>>>(x_ids, embed, h);

    for (int l = 0; l < 6; ++l) {
        const float* wq = Wq + (size_t)l * 1024 * 1024;
        const float* wk = Wk + (size_t)l * 1024 * 1024;
        const float* wv = Wv + (size_t)l * 1024 * 1024;
        const float* wo = Wo + (size_t)l * 1024 * 1024;
        const float* wg = Wg + (size_t)l * 4096 * 1024;
        const float* wu = Wu + (size_t)l * 4096 * 1024;
        const float* wd = Wd + (size_t)l * 1024 * 4096;

        rmsnorm_kernel<<<1024, 256, 0, stream>>>(h, ln1 + l * 1024, hn);

        gemm_kernel<128,128,64,64,EP_STORE,false><<<dim3(8,8,1),256,0,stream>>>(
            hn, wq, q, 1024, 1024, 1024, 1024, 0, 0, 0, 0.f);
        gemm_kernel<128,128,64,64,EP_STORE,false><<<dim3(8,8,1),256,0,stream>>>(
            hn, wk, k, 1024, 1024, 1024, 1024, 0, 0, 0, 0.f);
        gemm_kernel<128,128,64,64,EP_STORE,false><<<dim3(8,8,1),256,0,stream>>>(
            hn, wv, v, 1024, 1024, 1024, 1024, 0, 0, 0, 0.f);

        qknorm_rope_kernel<<<1024, 256, 0, stream>>>(q, k, qn + l * 64, kn + l * 64);

        transpose_kernel<<<dim3(32,32), 256, 0, stream>>>(v, vT);

        // scores[h] = softcap(mask(q_h k_h^T * scale))   K = 64
        gemm_kernel<128,128,64,64,EP_ATTN,false><<<dim3(8,8,16),256,0,stream>>>(
            q, k, sc, 64, 1024, 1024, 1024,
            64, 64, (long long)1024 * 1024, 0.125f);

        softmax_kernel<<<16 * 1024, 256, 0, stream>>>(sc);

        // o[h] = P_h @ V_h   (A = P [1024,1024], B = vT rows d, causal K limit)
        gemm_kernel<128,64,64,32,EP_STORE,true><<<dim3(8,1,16),256,0,stream>>>(
            sc, vT, o, 1024, 1024, 1024, 1024,
            (long long)1024 * 1024, (long long)64 * 1024, 64, 0.f);

        gemm_kernel<128,128,64,64,EP_RESID,false><<<dim3(8,8,1),256,0,stream>>>(
            o, wo, h, 1024, 1024, 1024, 1024, 0, 0, 0, 0.f);

        rmsnorm_kernel<<<1024, 256, 0, stream>>>(h, ln2 + l * 1024, hn);

        gemm_kernel<128,128,64,64,EP_STORE,false><<<dim3(8,32,1),256,0,stream>>>(
            hn, wg, g, 1024, 1024, 1024, 4096, 0, 0, 0, 0.f);
        gemm_kernel<128,128,64,64,EP_STORE,false><<<dim3(8,32,1),256,0,stream>>>(
            hn, wu, u, 1024, 1024, 1024, 4096, 0, 0, 0, 0.f);

        silu_mul_kernel<<<4096, 256, 0, stream>>>(g, u, g);

        gemm_kernel<128,128,64,64,EP_RESID,false><<<dim3(8,8,1),256,0,stream>>>(
            g, wd, h, 4096, 4096, 4096, 1024, 0, 0, 0, 0.f);
    }

    rmsnorm_kernel<<<1024, 256, 0, stream>>>(h, lnout, hn);
    gemm_kernel<128,128,64,64,EP_STORE,false><<<dim3(8,250,1),256,0,stream>>>(
        hn, embed, out, 1024, 1024, 1024, 32000, 0, 0, 0, 0.f);
}

// Round 2
// 3302.808 us; speedup vs baseline: 2.3634x; 2.3634x over previous
//
#include <hip/hip_runtime.h>
#include <math.h>

typedef __bf16 bf16_t;
typedef bf16_t bf16x4 __attribute__((ext_vector_type(4)));
typedef bf16_t bf16x8 __attribute__((ext_vector_type(8)));
typedef float  f32x4  __attribute__((ext_vector_type(4)));

#define RMS_EPS 1e-6f

enum { EP_STORE = 0, EP_RESID = 1, EP_ATTN = 2, EP_SPLIT = 3 };

static __device__ __forceinline__ f32x4 mfma16(bf16x8 a, bf16x8 b, f32x4 c) {
    return __builtin_amdgcn_mfma_f32_16x16x32_bf16(a, b, c, 0, 0, 0);
}

// async global->LDS, 16B per lane. LDS dest must be wave-uniform base (HW adds lane*16).
#define GLDS(gp, lp) __builtin_amdgcn_global_load_lds( \
    (const __attribute__((address_space(1))) void*)(gp), \
    (__attribute__((address_space(3))) void*)(lp), 16, 0, 0)

// C[M,N] = A[M,K]*B[N,K]^T, A,B given as bf16 hi/lo planes (split-fp32, 3 MFMAs).
// LDS tiles [ROWS][32] bf16, 16B chunks XOR-swizzled: chunk' = c ^ ((r>>1)&3).
// Swizzle applied on the GLOBAL source (gload_lds writes linearly) and on ds_read.
template<int BM, int BN, int EPIL, bool CAUSAL>
__global__ __launch_bounds__(256, 2)
void gemm_bf16(const bf16_t* __restrict__ Ah, const bf16_t* __restrict__ Al,
               const bf16_t* __restrict__ Bh, const bf16_t* __restrict__ Bl,
               float* __restrict__ Cf, bf16_t* __restrict__ Ch, bf16_t* __restrict__ Cl,
               int K, int lda, int ldb, int ldc,
               long long sA, long long sB, long long sC, float scale)
{
    __shared__ __align__(16) bf16_t sAh[BM*32], sAl[BM*32], sBh[BN*32], sBl[BN*32];

    const int gx = gridDim.x;
    int id = blockIdx.x + gx * blockIdx.y;
    if (gridDim.z == 1) {  // bijective XCD swizzle (m204)
        int nwg = gx * gridDim.y;
        int q = nwg >> 3, r = nwg & 7;
        int xcd = id & 7, ix = id >> 3;
        id = (xcd < r ? xcd * (q + 1) : r * (q + 1) + (xcd - r) * q) + ix;
    }
    const int bm = id % gx, bn = id / gx;
    const int row0 = bm * BM, col0 = bn * BN;

    Ah += (size_t)blockIdx.z * sA;  Al += (size_t)blockIdx.z * sA;
    Bh += (size_t)blockIdx.z * sB;  Bl += (size_t)blockIdx.z * sB;

    const int tid = threadIdx.x, lane = tid & 63, wave = tid >> 6;
    const int lr = lane & 15, lg = lane >> 4;
    constexpr int WM = BM / 2, WN = BN / 2, MF = WM / 16, NF = WN / 16;
    const int wm = wave >> 1, wn = wave & 1;

    f32x4 acc[MF][NF];
    #pragma unroll
    for (int m = 0; m < MF; ++m)
        #pragma unroll
        for (int n = 0; n < NF; ++n) acc[m][n] = (f32x4){0.f, 0.f, 0.f, 0.f};

    int kend = K;
    if constexpr (EPIL == EP_ATTN) { if (col0 >= row0 + BM) kend = 0; }  // fully-masked tile
    if constexpr (CAUSAL) { int lim = row0 + BM; if (lim < kend) kend = lim; }

    for (int k0 = 0; k0 < kend; k0 += 32) {
        __syncthreads();
        #pragma unroll
        for (int i = wave; i < BM / 16; i += 4) {
            int s = i * 64 + lane, rr = s >> 2, c = s & 3;
            size_t go = (size_t)(row0 + rr) * lda + k0 + ((c ^ ((rr >> 1) & 3)) << 3);
            GLDS(Ah + go, sAh + i * 512);
            GLDS(Al + go, sAl + i * 512);
        }
        #pragma unroll
        for (int i = wave; i < BN / 16; i += 4) {
            int s = i * 64 + lane, rr = s >> 2, c = s & 3;
            size_t go = (size_t)(col0 + rr) * ldb + k0 + ((c ^ ((rr >> 1) & 3)) << 3);
            GLDS(Bh + go, sBh + i * 512);
            GLDS(Bl + go, sBl + i * 512);
        }
        __syncthreads();  // compiler emits vmcnt(0) drain here

        bf16x8 ah[MF], al[MF], bh[NF], bl[NF];
        #pragma unroll
        for (int m = 0; m < MF; ++m) {
            int rr = wm * WM + m * 16 + lr;
            int by = rr * 64 + ((lg ^ ((rr >> 1) & 3)) << 4);
            ah[m] = *(const bf16x8*)((const char*)sAh + by);
            al[m] = *(const bf16x8*)((const char*)sAl + by);
        }
        #pragma unroll
        for (int n = 0; n < NF; ++n) {
            int rr = wn * WN + n * 16 + lr;
            int by = rr * 64 + ((lg ^ ((rr >> 1) & 3)) << 4);
            bh[n] = *(const bf16x8*)((const char*)sBh + by);
            bl[n] = *(const bf16x8*)((const char*)sBl + by);
        }
        #pragma unroll
        for (int m = 0; m < MF; ++m)
            #pragma unroll
            for (int n = 0; n < NF; ++n) {
                acc[m][n] = mfma16(ah[m], bh[n], acc[m][n]);
                acc[m][n] = mfma16(ah[m], bl[n], acc[m][n]);
                acc[m][n] = mfma16(al[m], bh[n], acc[m][n]);
            }
    }

    #pragma unroll
    for (int m = 0; m < MF; ++m)
        #pragma unroll
        for (int n = 0; n < NF; ++n)
            #pragma unroll
            for (int r = 0; r < 4; ++r) {
                int grow = row0 + wm * WM + m * 16 + lg * 4 + r;
                int gcol = col0 + wn * WN + n * 16 + lr;
                size_t off = (size_t)blockIdx.z * sC + (size_t)grow * ldc + gcol;
                float v = acc[m][n][r];
                if constexpr (EPIL == EP_STORE) {
                    Cf[off] = v;
                } else if constexpr (EPIL == EP_RESID) {
                    Cf[off] += v;
                } else if constexpr (EPIL == EP_ATTN) {
                    v *= scale;
                    v = 50.0f * tanhf(v * 0.02f);
                    if (gcol > grow) v = -1e30f;
                    Cf[off] = v;
                } else {  // EP_SPLIT
                    bf16_t hb = (bf16_t)v;
                    Ch[off] = hb;
                    Cl[off] = (bf16_t)(v - (float)hb);
                }
            }
}

__global__ __launch_bounds__(256)
void split_kernel(const float* __restrict__ src, bf16_t* __restrict__ hi,
                  bf16_t* __restrict__ lo)
{
    size_t i = (size_t)blockIdx.x * 256 + threadIdx.x;
    f32x4 v = ((const f32x4*)src)[i];
    bf16x4 hv, lv;
    #pragma unroll
    for (int j = 0; j < 4; ++j) {
        bf16_t hb = (bf16_t)v[j];
        hv[j] = hb;
        lv[j] = (bf16_t)(v[j] - (float)hb);
    }
    ((bf16x4*)hi)[i] = hv;
    ((bf16x4*)lo)[i] = lv;
}

__global__ __launch_bounds__(256)
void gather_kernel(const int* __restrict__ ids, const float* __restrict__ embed,
                   float* __restrict__ h)
{
    int t = blockIdx.x;
    int row = ids[t];
    const f32x4* src = (const f32x4*)(embed + (size_t)row * 1024);
    f32x4* dst = (f32x4*)(h + (size_t)t * 1024);
    dst[threadIdx.x] = src[threadIdx.x];
}

__global__ __launch_bounds__(256)
void rmsnorm_split(const float* __restrict__ in, const float* __restrict__ w,
                   bf16_t* __restrict__ outh, bf16_t* __restrict__ outl)
{
    int row = blockIdx.x, tid = threadIdx.x;
    f32x4 v = *(const f32x4*)(in + (size_t)row * 1024 + tid * 4);
    float ss = v[0]*v[0] + v[1]*v[1] + v[2]*v[2] + v[3]*v[3];
    #pragma unroll
    for (int m = 1; m < 64; m <<= 1) ss += __shfl_xor(ss, m, 64);
    __shared__ float red[4];
    if ((tid & 63) == 0) red[tid >> 6] = ss;
    __syncthreads();
    float tot = red[0] + red[1] + red[2] + red[3];
    float inv = rsqrtf(tot * (1.0f / 1024.0f) + RMS_EPS);
    f32x4 wv = *(const f32x4*)(w + tid * 4);
    bf16x4 hv, lv;
    #pragma unroll
    for (int j = 0; j < 4; ++j) {
        float x = v[j] * inv * wv[j];
        bf16_t hb = (bf16_t)x;
        hv[j] = hb;
        lv[j] = (bf16_t)(x - (float)hb);
    }
    ((bf16x4*)outh)[(size_t)row * 256 + tid] = hv;
    ((bf16x4*)outl)[(size_t)row * 256 + tid] = lv;
}

// Per-(t,head) RMS over Dh=64 + RoPE; reference quirk: angle = head_index * freq
// (cos[:n] with n = H). In-place on split q/k planes.
__global__ __launch_bounds__(256)
void qknorm_rope_split(bf16_t* __restrict__ qh, bf16_t* __restrict__ ql,
                       bf16_t* __restrict__ kh, bf16_t* __restrict__ kl,
                       const float* __restrict__ qn, const float* __restrict__ kn)
{
    int t = blockIdx.x, tid = threadIdx.x;
    int hh = tid >> 4;
    int i  = (tid & 15) * 4;
    size_t b4 = ((size_t)t * 1024 + hh * 64 + i) >> 2;

    int p0 = i >> 1;
    float f0 = powf(10000.f, -(float)p0 / 32.f);
    float f1 = powf(10000.f, -(float)(p0 + 1) / 32.f);
    float a0 = (float)hh * f0, a1 = (float)hh * f1;
    float c0 = cosf(a0), s0 = sinf(a0);
    float c1 = cosf(a1), s1 = sinf(a1);

    f32x4 qw = *(const f32x4*)(qn + i);
    f32x4 kw = *(const f32x4*)(kn + i);

    {
        bf16x4 h4 = ((const bf16x4*)qh)[b4], l4 = ((const bf16x4*)ql)[b4];
        float x[4];
        #pragma unroll
        for (int j = 0; j < 4; ++j) x[j] = (float)h4[j] + (float)l4[j];
        float ss = x[0]*x[0] + x[1]*x[1] + x[2]*x[2] + x[3]*x[3];
        #pragma unroll
        for (int m = 1; m < 16; m <<= 1) ss += __shfl_xor(ss, m, 64);
        float inv = rsqrtf(ss * (1.0f / 64.0f) + RMS_EPS);
        float x0 = x[0]*inv*qw[0], x1 = x[1]*inv*qw[1];
        float x2 = x[2]*inv*qw[2], x3 = x[3]*inv*qw[3];
        float r[4];
        r[0] = x0*c0 - x1*s0;  r[1] = x0*s0 + x1*c0;
        r[2] = x2*c1 - x3*s1;  r[3] = x2*s1 + x3*c1;
        bf16x4 oh4, ol4;
        #pragma unroll
        for (int j = 0; j < 4; ++j) {
            bf16_t hb = (bf16_t)r[j];
            oh4[j] = hb;
            ol4[j] = (bf16_t)(r[j] - (float)hb);
        }
        ((bf16x4*)qh)[b4] = oh4;
        ((bf16x4*)ql)[b4] = ol4;
    }
    {
        bf16x4 h4 = ((const bf16x4*)kh)[b4], l4 = ((const bf16x4*)kl)[b4];
        float x[4];
        #pragma unroll
        for (int j = 0; j < 4; ++j) x[j] = (float)h4[j] + (float)l4[j];
        float ss = x[0]*x[0] + x[1]*x[1] + x[2]*x[2] + x[3]*x[3];
        #pragma unroll
        for (int m = 1; m < 16; m <<= 1) ss += __shfl_xor(ss, m, 64);
        float inv = rsqrtf(ss * (1.0f / 64.0f) + RMS_EPS);
        float x0 = x[0]*inv*kw[0], x1 = x[1]*inv*kw[1];
        float x2 = x[2]*inv*kw[2], x3 = x[3]*inv*kw[3];
        float r[4];
        r[0] = x0*c0 - x1*s0;  r[1] = x0*s0 + x1*c0;
        r[2] = x2*c1 - x3*s1;  r[3] = x2*s1 + x3*c1;
        bf16x4 oh4, ol4;
        #pragma unroll
        for (int j = 0; j < 4; ++j) {
            bf16_t hb = (bf16_t)r[j];
            oh4[j] = hb;
            ol4[j] = (bf16_t)(r[j] - (float)hb);
        }
        ((bf16x4*)kh)[b4] = oh4;
        ((bf16x4*)kl)[b4] = ol4;
    }
}

// 1024x1024 bf16 transpose; blockIdx.z selects hi/lo plane.
__global__ __launch_bounds__(256)
void transpose_split(const bf16_t* __restrict__ inh, const bf16_t* __restrict__ inl,
                     bf16_t* __restrict__ outh, bf16_t* __restrict__ outl)
{
    __shared__ bf16_t tile[32][33];
    const bf16_t* in = blockIdx.z ? inl : inh;
    bf16_t* out      = blockIdx.z ? outl : outh;
    int bx = blockIdx.x * 32, by = blockIdx.y * 32;
    int r = threadIdx.x >> 5, c = threadIdx.x & 31;
    #pragma unroll
    for (int rr = r; rr < 32; rr += 8)
        tile[rr][c] = in[(size_t)(by + rr) * 1024 + bx + c];
    __syncthreads();
    #pragma unroll
    for (int rr = r; rr < 32; rr += 8)
        out[(size_t)(bx + rr) * 1024 + by + c] = tile[c][rr];
}

__global__ __launch_bounds__(256)
void softmax_split(const float* __restrict__ sc, bf16_t* __restrict__ ph,
                   bf16_t* __restrict__ pl)
{
    size_t row = blockIdx.x;
    int tid = threadIdx.x;
    f32x4 v = ((const f32x4*)(sc + row * 1024))[tid];
    float mx = fmaxf(fmaxf(v[0], v[1]), fmaxf(v[2], v[3]));
    #pragma unroll
    for (int m = 1; m < 64; m <<= 1) mx = fmaxf(mx, __shfl_xor(mx, m, 64));
    __shared__ float red[8];
    if ((tid & 63) == 0) red[tid >> 6] = mx;
    __syncthreads();
    mx = fmaxf(fmaxf(red[0], red[1]), fmaxf(red[2], red[3]));
    f32x4 e;
    float sum = 0.f;
    #pragma unroll
    for (int j = 0; j < 4; ++j) { e[j] = expf(v[j] - mx); sum += e[j]; }
    #pragma unroll
    for (int m = 1; m < 64; m <<= 1) sum += __shfl_xor(sum, m, 64);
    if ((tid & 63) == 0) red[4 + (tid >> 6)] = sum;
    __syncthreads();
    sum = red[4] + red[5] + red[6] + red[7];
    float inv = 1.0f / sum;
    bf16x4 hv, lv;
    #pragma unroll
    for (int j = 0; j < 4; ++j) {
        float p = e[j] * inv;
        bf16_t hb = (bf16_t)p;
        hv[j] = hb;
        lv[j] = (bf16_t)(p - (float)hb);
    }
    ((bf16x4*)(ph + row * 1024))[tid] = hv;
    ((bf16x4*)(pl + row * 1024))[tid] = lv;
}

__global__ __launch_bounds__(256)
void silu_mul_split(bf16_t* __restrict__ gh, bf16_t* __restrict__ gl,
                    const bf16_t* __restrict__ uh, const bf16_t* __restrict__ ul)
{
    size_t i = (size_t)blockIdx.x * 256 + threadIdx.x;
    bf16x4 gh4 = ((const bf16x4*)gh)[i], gl4 = ((const bf16x4*)gl)[i];
    bf16x4 uh4 = ((const bf16x4*)uh)[i], ul4 = ((const bf16x4*)ul)[i];
    bf16x4 hv, lv;
    #pragma unroll
    for (int j = 0; j < 4; ++j) {
        float g = (float)gh4[j] + (float)gl4[j];
        float u = (float)uh4[j] + (float)ul4[j];
        float o = (g / (1.0f + expf(-g))) * u;
        bf16_t hb = (bf16_t)o;
        hv[j] = hb;
        lv[j] = (bf16_t)(o - (float)hb);
    }
    ((bf16x4*)gh)[i] = hv;
    ((bf16x4*)gl)[i] = lv;
}

extern "C" void kernel_launch(void* const* d_in, const int* in_sizes, int n_in,
                              void* d_out, int out_size, void* d_ws, size_t ws_size,
                              hipStream_t stream)
{
    (void)in_sizes; (void)n_in; (void)out_size; (void)ws_size;
    const int*   x_ids = (const int*)  d_in[0];
    const float* embed = (const float*)d_in[1];
    const float* ln1   = (const float*)d_in[2];
    const float* Wq    = (const float*)d_in[3];
    const float* Wk    = (const float*)d_in[4];
    const float* Wv    = (const float*)d_in[5];
    const float* Wo    = (const float*)d_in[6];
    const float* qn    = (const float*)d_in[7];
    const float* kn    = (const float*)d_in[8];
    const float* ln2   = (const float*)d_in[9];
    const float* Wg    = (const float*)d_in[10];
    const float* Wu    = (const float*)d_in[11];
    const float* Wd    = (const float*)d_in[12];
    const float* lnout = (const float*)d_in[13];
    float* out = (float*)d_out;

    char* ws = (char*)d_ws;
    const size_t MB = 1 << 20;
    float*  h   = (float*) (ws +   0 * MB);  // 4 MB fp32 residual
    bf16_t* hnh = (bf16_t*)(ws +   4 * MB);
    bf16_t* hnl = (bf16_t*)(ws +   6 * MB);
    bf16_t* qh  = (bf16_t*)(ws +   8 * MB);
    bf16_t* ql  = (bf16_t*)(ws +  10 * MB);
    bf16_t* kh  = (bf16_t*)(ws +  12 * MB);
    bf16_t* kl  = (bf16_t*)(ws +  14 * MB);
    bf16_t* vh  = (bf16_t*)(ws +  16 * MB);
    bf16_t* vl  = (bf16_t*)(ws +  18 * MB);
    bf16_t* vTh = (bf16_t*)(ws +  20 * MB);
    bf16_t* vTl = (bf16_t*)(ws +  22 * MB);
    bf16_t* oh  = (bf16_t*)(ws +  24 * MB);
    bf16_t* ol  = (bf16_t*)(ws +  26 * MB);
    bf16_t* gh  = (bf16_t*)(ws +  28 * MB);  // 8 MB
    bf16_t* gl  = (bf16_t*)(ws +  36 * MB);
    bf16_t* uh  = (bf16_t*)(ws +  44 * MB);
    bf16_t* ul  = (bf16_t*)(ws +  52 * MB);
    float*  sc  = (float*) (ws +  60 * MB);  // 64 MB scores; reused: MLP weight splits, embed-hi
    bf16_t* ph  = (bf16_t*)(ws + 124 * MB);  // 32 MB
    bf16_t* pl  = (bf16_t*)(ws + 156 * MB);  // 32 MB; ph+pl reused for embed-lo
    bf16_t* wqh = (bf16_t*)(ws + 188 * MB);
    bf16_t* wql = (bf16_t*)(ws + 190 * MB);
    bf16_t* wkh = (bf16_t*)(ws + 192 * MB);
    bf16_t* wkl = (bf16_t*)(ws + 194 * MB);
    bf16_t* wvh = (bf16_t*)(ws + 196 * MB);
    bf16_t* wvl = (bf16_t*)(ws + 198 * MB);
    bf16_t* woh = (bf16_t*)(ws + 200 * MB);
    bf16_t* wol = (bf16_t*)(ws + 202 * MB);  // ends 204 MB
    // MLP weight splits overlay the (dead-by-then) sc region:
    bf16_t* wgh = (bf16_t*)(ws +  60 * MB);
    bf16_t* wgl = (bf16_t*)(ws +  68 * MB);
    bf16_t* wuh = (bf16_t*)(ws +  76 * MB);
    bf16_t* wul = (bf16_t*)(ws +  84 * MB);
    bf16_t* wdh = (bf16_t*)(ws +  92 * MB);
    bf16_t* wdl = (bf16_t*)(ws + 100 * MB);
    // embed split (final logits) overlays sc and ph/pl:
    bf16_t* eh  = (bf16_t*)(ws +  60 * MB);  // 62.5 MB
    bf16_t* el  = (bf16_t*)(ws + 124 * MB);  // 62.5 MB

    const long long M1 = 1024 * 1024;

    gather_kernel<<<1024, 256, 0, stream>>>(x_ids, embed, h);

    for (int l = 0; l < 6; ++l) {
        const float* wq = Wq + (size_t)l * M1;
        const float* wk = Wk + (size_t)l * M1;
        const float* wv = Wv + (size_t)l * M1;
        const float* wo = Wo + (size_t)l * M1;
        const float* wg = Wg + (size_t)l * 4 * M1;
        const float* wu = Wu + (size_t)l * 4 * M1;
        const float* wd = Wd + (size_t)l * 4 * M1;

        split_kernel<<<1024, 256, 0, stream>>>(wq, wqh, wql);
        split_kernel<<<1024, 256, 0, stream>>>(wk, wkh, wkl);
        split_kernel<<<1024, 256, 0, stream>>>(wv, wvh, wvl);
        split_kernel<<<1024, 256, 0, stream>>>(wo, woh, wol);

        rmsnorm_split<<<1024, 256, 0, stream>>>(h, ln1 + l * 1024, hnh, hnl);

        gemm_bf16<128,128,EP_SPLIT,false><<<dim3(8,8,1),256,0,stream>>>(
            hnh, hnl, wqh, wql, nullptr, qh, ql, 1024, 1024, 1024, 1024, 0, 0, 0, 0.f);
        gemm_bf16<128,128,EP_SPLIT,false><<<dim3(8,8,1),256,0,stream>>>(
            hnh, hnl, wkh, wkl, nullptr, kh, kl, 1024, 1024, 1024, 1024, 0, 0, 0, 0.f);
        gemm_bf16<128,128,EP_SPLIT,false><<<dim3(8,8,1),256,0,stream>>>(
            hnh, hnl, wvh, wvl, nullptr, vh, vl, 1024, 1024, 1024, 1024, 0, 0, 0, 0.f);

        qknorm_rope_split<<<1024, 256, 0, stream>>>(qh, ql, kh, kl, qn + l * 64, kn + l * 64);
        transpose_split<<<dim3(32,32,2), 256, 0, stream>>>(vh, vl, vTh, vTl);

        // scores[h] = softcap(mask(q_h k_h^T * 0.125)); per-head k-slice via sA=sB=64
        gemm_bf16<128,128,EP_ATTN,false><<<dim3(8,8,16),256,0,stream>>>(
            qh, ql, kh, kl, sc, nullptr, nullptr, 64, 1024, 1024, 1024,
            64, 64, M1, 0.125f);

        softmax_split<<<16 * 1024, 256, 0, stream>>>(sc, ph, pl);

        // o[h] = P_h @ V_h  (B = vT per head [64][1024]; causal K limit; out split)
        gemm_bf16<64,64,EP_SPLIT,true><<<dim3(16,1,16),256,0,stream>>>(
            ph, pl, vTh, vTl, nullptr, oh, ol, 1024, 1024, 1024, 1024,
            M1, 64 * 1024, 64, 0.f);

        // sc region now dead: split MLP weights into it
        split_kernel<<<4096, 256, 0, stream>>>(wg, wgh, wgl);
        split_kernel<<<4096, 256, 0, stream>>>(wu, wuh, wul);
        split_kernel<<<4096, 256, 0, stream>>>(wd, wdh, wdl);

        gemm_bf16<128,128,EP_RESID,false><<<dim3(8,8,1),256,0,stream>>>(
            oh, ol, woh, wol, h, nullptr, nullptr, 1024, 1024, 1024, 1024, 0, 0, 0, 0.f);

        rmsnorm_split<<<1024, 256, 0, stream>>>(h, ln2 + l * 1024, hnh, hnl);

        gemm_bf16<128,128,EP_SPLIT,false><<<dim3(8,32,1),256,0,stream>>>(
            hnh, hnl, wgh, wgl, nullptr, gh, gl, 1024, 1024, 1024, 4096, 0, 0, 0, 0.f);
        gemm_bf16<128,128,EP_SPLIT,false><<<dim3(8,32,1),256,0,stream>>>(
            hnh, hnl, wuh, wul, nullptr, uh, ul, 1024, 1024, 1024, 4096, 0, 0, 0, 0.f);

        silu_mul_split<<<4096, 256, 0, stream>>>(gh, gl, uh, ul);

        gemm_bf16<128,128,EP_RESID,false><<<dim3(8,8,1),256,0,stream>>>(
            gh, gl, wdh, wdl, h, nullptr, nullptr, 4096, 4096, 4096, 1024, 0, 0, 0, 0.f);
    }

    rmsnorm_split<<<1024, 256, 0, stream>>>(h, lnout, hnh, hnl);
    split_kernel<<<32000, 256, 0, stream>>>(embed, eh, el);
    gemm_bf16<128,128,EP_STORE,false><<<dim3(8,250,1),256,0,stream>>>(
        hnh, hnl, eh, el, out, nullptr, nullptr, 1024, 1024, 1024, 32000, 0, 0, 0, 0.f);
}

// Round 3
// 1830.920 us; speedup vs baseline: 4.2634x; 1.8039x over previous
//
#include <hip/hip_runtime.h>
#include <math.h>

typedef __bf16 bf16_t;
typedef bf16_t bf16x4 __attribute__((ext_vector_type(4)));
typedef bf16_t bf16x8 __attribute__((ext_vector_type(8)));
typedef float  f32x4  __attribute__((ext_vector_type(4)));

#define RMS_EPS 1e-6f

enum { EP_STORE = 0, EP_RESID = 1, EP_ATTN = 2, EP_SPLIT = 3 };

static __device__ __forceinline__ f32x4 mfma16(bf16x8 a, bf16x8 b, f32x4 c) {
    return __builtin_amdgcn_mfma_f32_16x16x32_bf16(a, b, c, 0, 0, 0);
}

#define GLDS(gp, lp) __builtin_amdgcn_global_load_lds( \
    (const __attribute__((address_space(1))) void*)(gp), \
    (__attribute__((address_space(3))) void*)(lp), 16, 0, 0)

// C[M,N] = A[M,K]*B[N,K]^T.  PLANES==3: hi/lo split-fp32, 3 MFMAs.
// PLANES==1: hi-only, 1 MFMA (for scores / logits — error ~1e-3, analysis in journal).
// LDS [rows][32] bf16; 16B chunks XOR-swizzled via pre-swizzled global source.
template<int BM, int BN, int PLANES, int EPIL, bool CAUSAL>
__global__ __launch_bounds__(256, 4)
void gemm_bf16(const bf16_t* __restrict__ Ah, const bf16_t* __restrict__ Al,
               const bf16_t* __restrict__ Bh, const bf16_t* __restrict__ Bl,
               float* __restrict__ Cf, bf16_t* __restrict__ Ch, bf16_t* __restrict__ Cl,
               int K, int lda, int ldb, int ldc,
               long long sA, long long sB, long long sC, float scale)
{
    __shared__ __align__(16) bf16_t sAh[BM*32], sBh[BN*32];
    __shared__ __align__(16) bf16_t sAl[PLANES >= 3 ? BM*32 : 8];
    __shared__ __align__(16) bf16_t sBl[PLANES >= 3 ? BN*32 : 8];

    const int gx = gridDim.x;
    int id = blockIdx.x + gx * blockIdx.y;
    if (gridDim.z == 1) {  // bijective XCD swizzle (m204)
        int nwg = gx * gridDim.y;
        int q = nwg >> 3, r = nwg & 7;
        int xcd = id & 7, ix = id >> 3;
        id = (xcd < r ? xcd * (q + 1) : r * (q + 1) + (xcd - r) * q) + ix;
    }
    const int bm = id % gx, bn = id / gx;
    const int row0 = bm * BM, col0 = bn * BN;

    if constexpr (EPIL == EP_ATTN) {
        if (col0 >= row0 + BM) return;  // fully-masked tile: no write (softmax masks)
    }

    Ah += (size_t)blockIdx.z * sA;  Bh += (size_t)blockIdx.z * sB;
    if constexpr (PLANES >= 3) { Al += (size_t)blockIdx.z * sA; Bl += (size_t)blockIdx.z * sB; }

    const int tid = threadIdx.x, lane = tid & 63, wave = tid >> 6;
    const int lr = lane & 15, lg = lane >> 4;
    constexpr int WM = BM / 2, WN = BN / 2, MF = WM / 16, NF = WN / 16;
    const int wm = wave >> 1, wn = wave & 1;

    f32x4 acc[MF][NF];
    #pragma unroll
    for (int m = 0; m < MF; ++m)
        #pragma unroll
        for (int n = 0; n < NF; ++n) acc[m][n] = (f32x4){0.f, 0.f, 0.f, 0.f};

    int kend = K;
    if constexpr (CAUSAL) { int lim = row0 + BM; if (lim < kend) kend = lim; }

    for (int k0 = 0; k0 < kend; k0 += 32) {
        __syncthreads();
        #pragma unroll
        for (int i = wave; i < BM / 16; i += 4) {
            int s = i * 64 + lane, rr = s >> 2, c = s & 3;
            size_t go = (size_t)(row0 + rr) * lda + k0 + ((c ^ ((rr >> 1) & 3)) << 3);
            GLDS(Ah + go, sAh + i * 512);
            if constexpr (PLANES >= 3) GLDS(Al + go, sAl + i * 512);
        }
        #pragma unroll
        for (int i = wave; i < BN / 16; i += 4) {
            int s = i * 64 + lane, rr = s >> 2, c = s & 3;
            size_t go = (size_t)(col0 + rr) * ldb + k0 + ((c ^ ((rr >> 1) & 3)) << 3);
            GLDS(Bh + go, sBh + i * 512);
            if constexpr (PLANES >= 3) GLDS(Bl + go, sBl + i * 512);
        }
        __syncthreads();

        bf16x8 ah[MF], al[MF], bh[NF], bl[NF];
        #pragma unroll
        for (int m = 0; m < MF; ++m) {
            int rr = wm * WM + m * 16 + lr;
            int by = rr * 64 + ((lg ^ ((rr >> 1) & 3)) << 4);
            ah[m] = *(const bf16x8*)((const char*)sAh + by);
            if constexpr (PLANES >= 3) al[m] = *(const bf16x8*)((const char*)sAl + by);
        }
        #pragma unroll
        for (int n = 0; n < NF; ++n) {
            int rr = wn * WN + n * 16 + lr;
            int by = rr * 64 + ((lg ^ ((rr >> 1) & 3)) << 4);
            bh[n] = *(const bf16x8*)((const char*)sBh + by);
            if constexpr (PLANES >= 3) bl[n] = *(const bf16x8*)((const char*)sBl + by);
        }
        #pragma unroll
        for (int m = 0; m < MF; ++m)
            #pragma unroll
            for (int n = 0; n < NF; ++n) {
                acc[m][n] = mfma16(ah[m], bh[n], acc[m][n]);
                if constexpr (PLANES >= 3) {
                    acc[m][n] = mfma16(ah[m], bl[n], acc[m][n]);
                    acc[m][n] = mfma16(al[m], bh[n], acc[m][n]);
                }
            }
    }

    #pragma unroll
    for (int m = 0; m < MF; ++m)
        #pragma unroll
        for (int n = 0; n < NF; ++n)
            #pragma unroll
            for (int r = 0; r < 4; ++r) {
                int grow = row0 + wm * WM + m * 16 + lg * 4 + r;
                int gcol = col0 + wn * WN + n * 16 + lr;
                size_t off = (size_t)blockIdx.z * sC + (size_t)grow * ldc + gcol;
                float v = acc[m][n][r];
                if constexpr (EPIL == EP_STORE) {
                    Cf[off] = v;
                } else if constexpr (EPIL == EP_RESID) {
                    Cf[off] += v;
                } else if constexpr (EPIL == EP_ATTN) {
                    v *= scale;
                    v = 50.0f * tanhf(v * 0.02f);
                    if (gcol > grow) v = -1e30f;
                    Cf[off] = v;
                } else {  // EP_SPLIT
                    bf16_t hb = (bf16_t)v;
                    Ch[off] = hb;
                    Cl[off] = (bf16_t)(v - (float)hb);
                }
            }
}

// generic fp32 -> bf16 hi(/lo) split; lo may be null. 1024 elements per block.
__global__ __launch_bounds__(256)
void split_kernel(const float* __restrict__ src, bf16_t* __restrict__ hi,
                  bf16_t* __restrict__ lo)
{
    size_t i = (size_t)blockIdx.x * 256 + threadIdx.x;
    f32x4 v = ((const f32x4*)src)[i];
    bf16x4 hv, lv;
    #pragma unroll
    for (int j = 0; j < 4; ++j) {
        bf16_t hb = (bf16_t)v[j];
        hv[j] = hb;
        lv[j] = (bf16_t)(v[j] - (float)hb);
    }
    ((bf16x4*)hi)[i] = hv;
    if (lo) ((bf16x4*)lo)[i] = lv;
}

// pack wq|wk|wv|wo (each [1024x1024]) into wA planes [4096x1024]
__global__ __launch_bounds__(256)
void split_attn(const float* __restrict__ wq, const float* __restrict__ wk,
                const float* __restrict__ wv, const float* __restrict__ wo,
                bf16_t* __restrict__ hi, bf16_t* __restrict__ lo)
{
    int b = blockIdx.x;
    const float* src = b < 1024 ? wq : b < 2048 ? wk : b < 3072 ? wv : wo;
    size_t so = ((size_t)(b & 1023) * 1024) / 4 + threadIdx.x;
    size_t dof = ((size_t)b * 1024) / 4 + threadIdx.x;
    f32x4 v = ((const f32x4*)src)[so];
    bf16x4 hv, lv;
    #pragma unroll
    for (int j = 0; j < 4; ++j) {
        bf16_t hb = (bf16_t)v[j];
        hv[j] = hb;
        lv[j] = (bf16_t)(v[j] - (float)hb);
    }
    ((bf16x4*)hi)[dof] = hv;
    ((bf16x4*)lo)[dof] = lv;
}

// pack wg|wu (each [4096x1024]) into wGU planes [8192x1024]
__global__ __launch_bounds__(256)
void split_gu(const float* __restrict__ wg, const float* __restrict__ wu,
              bf16_t* __restrict__ hi, bf16_t* __restrict__ lo)
{
    int b = blockIdx.x;
    const float* src = b < 4096 ? wg : wu;
    size_t so = ((size_t)(b & 4095) * 1024) / 4 + threadIdx.x;
    size_t dof = ((size_t)b * 1024) / 4 + threadIdx.x;
    f32x4 v = ((const f32x4*)src)[so];
    bf16x4 hv, lv;
    #pragma unroll
    for (int j = 0; j < 4; ++j) {
        bf16_t hb = (bf16_t)v[j];
        hv[j] = hb;
        lv[j] = (bf16_t)(v[j] - (float)hb);
    }
    ((bf16x4*)hi)[dof] = hv;
    ((bf16x4*)lo)[dof] = lv;
}

__global__ __launch_bounds__(256)
void gather_kernel(const int* __restrict__ ids, const float* __restrict__ embed,
                   float* __restrict__ h)
{
    int t = blockIdx.x;
    int row = ids[t];
    const f32x4* src = (const f32x4*)(embed + (size_t)row * 1024);
    f32x4* dst = (f32x4*)(h + (size_t)t * 1024);
    dst[threadIdx.x] = src[threadIdx.x];
}

__global__ __launch_bounds__(256)
void rmsnorm_split(const float* __restrict__ in, const float* __restrict__ w,
                   bf16_t* __restrict__ outh, bf16_t* __restrict__ outl)
{
    int row = blockIdx.x, tid = threadIdx.x;
    f32x4 v = *(const f32x4*)(in + (size_t)row * 1024 + tid * 4);
    float ss = v[0]*v[0] + v[1]*v[1] + v[2]*v[2] + v[3]*v[3];
    #pragma unroll
    for (int m = 1; m < 64; m <<= 1) ss += __shfl_xor(ss, m, 64);
    __shared__ float red[4];
    if ((tid & 63) == 0) red[tid >> 6] = ss;
    __syncthreads();
    float tot = red[0] + red[1] + red[2] + red[3];
    float inv = rsqrtf(tot * (1.0f / 1024.0f) + RMS_EPS);
    f32x4 wv = *(const f32x4*)(w + tid * 4);
    bf16x4 hv, lv;
    #pragma unroll
    for (int j = 0; j < 4; ++j) {
        float x = v[j] * inv * wv[j];
        bf16_t hb = (bf16_t)x;
        hv[j] = hb;
        lv[j] = (bf16_t)(x - (float)hb);
    }
    ((bf16x4*)outh)[(size_t)row * 256 + tid] = hv;
    ((bf16x4*)outl)[(size_t)row * 256 + tid] = lv;
}

// Per-(t,head) RMS over Dh=64 + RoPE on the packed qkv buffer [1024][3072]
// (q cols 0-1023, k cols 1024-2047). Reads hi+lo for precision, writes hi only
// (scores GEMM is 1-plane). Reference quirk: rotation angle = head_index*freq.
__global__ __launch_bounds__(256)
void qknorm_rope(bf16_t* __restrict__ qkvh, bf16_t* __restrict__ qkvl,
                 const float* __restrict__ qn, const float* __restrict__ kn)
{
    int t = blockIdx.x, tid = threadIdx.x;
    int hh = tid >> 4;
    int i  = (tid & 15) * 4;
    size_t qb = ((size_t)t * 3072 + hh * 64 + i) >> 2;
    size_t kb = qb + (1024 >> 2);

    int p0 = i >> 1;
    float f0 = powf(10000.f, -(float)p0 / 32.f);
    float f1 = powf(10000.f, -(float)(p0 + 1) / 32.f);
    float a0 = (float)hh * f0, a1 = (float)hh * f1;
    float c0 = cosf(a0), s0 = sinf(a0);
    float c1 = cosf(a1), s1 = sinf(a1);

    f32x4 qw = *(const f32x4*)(qn + i);
    f32x4 kw = *(const f32x4*)(kn + i);

    {
        bf16x4 h4 = ((const bf16x4*)qkvh)[qb], l4 = ((const bf16x4*)qkvl)[qb];
        float x[4];
        #pragma unroll
        for (int j = 0; j < 4; ++j) x[j] = (float)h4[j] + (float)l4[j];
        float ss = x[0]*x[0] + x[1]*x[1] + x[2]*x[2] + x[3]*x[3];
        #pragma unroll
        for (int m = 1; m < 16; m <<= 1) ss += __shfl_xor(ss, m, 64);
        float inv = rsqrtf(ss * (1.0f / 64.0f) + RMS_EPS);
        float x0 = x[0]*inv*qw[0], x1 = x[1]*inv*qw[1];
        float x2 = x[2]*inv*qw[2], x3 = x[3]*inv*qw[3];
        bf16x4 o4;
        o4[0] = (bf16_t)(x0*c0 - x1*s0);  o4[1] = (bf16_t)(x0*s0 + x1*c0);
        o4[2] = (bf16_t)(x2*c1 - x3*s1);  o4[3] = (bf16_t)(x2*s1 + x3*c1);
        ((bf16x4*)qkvh)[qb] = o4;
    }
    {
        bf16x4 h4 = ((const bf16x4*)qkvh)[kb], l4 = ((const bf16x4*)qkvl)[kb];
        float x[4];
        #pragma unroll
        for (int j = 0; j < 4; ++j) x[j] = (float)h4[j] + (float)l4[j];
        float ss = x[0]*x[0] + x[1]*x[1] + x[2]*x[2] + x[3]*x[3];
        #pragma unroll
        for (int m = 1; m < 16; m <<= 1) ss += __shfl_xor(ss, m, 64);
        float inv = rsqrtf(ss * (1.0f / 64.0f) + RMS_EPS);
        float x0 = x[0]*inv*kw[0], x1 = x[1]*inv*kw[1];
        float x2 = x[2]*inv*kw[2], x3 = x[3]*inv*kw[3];
        bf16x4 o4;
        o4[0] = (bf16_t)(x0*c0 - x1*s0);  o4[1] = (bf16_t)(x0*s0 + x1*c0);
        o4[2] = (bf16_t)(x2*c1 - x3*s1);  o4[3] = (bf16_t)(x2*s1 + x3*c1);
        ((bf16x4*)qkvh)[kb] = o4;
    }
}

// v (cols 2048-3071 of qkv, stride 3072) -> vT [1024][1024]; z selects hi/lo plane.
__global__ __launch_bounds__(256)
void transpose_v(const bf16_t* __restrict__ inh, const bf16_t* __restrict__ inl,
                 bf16_t* __restrict__ outh, bf16_t* __restrict__ outl)
{
    __shared__ bf16_t tile[32][33];
    const bf16_t* in = blockIdx.z ? inl : inh;
    bf16_t* out      = blockIdx.z ? outl : outh;
    int bx = blockIdx.x * 32, by = blockIdx.y * 32;
    int r = threadIdx.x >> 5, c = threadIdx.x & 31;
    #pragma unroll
    for (int rr = r; rr < 32; rr += 8)
        tile[rr][c] = in[(size_t)(by + rr) * 3072 + 2048 + bx + c];
    __syncthreads();
    #pragma unroll
    for (int rr = r; rr < 32; rr += 8)
        out[(size_t)(bx + rr) * 1024 + by + c] = tile[c][rr];
}

// causal-aware softmax (masks j>t itself; skipped score tiles hold garbage)
__global__ __launch_bounds__(256)
void softmax_split(const float* __restrict__ sc, bf16_t* __restrict__ ph,
                   bf16_t* __restrict__ pl)
{
    size_t row = blockIdx.x;
    int t = (int)(row & 1023);
    int tid = threadIdx.x;
    f32x4 v = ((const f32x4*)(sc + row * 1024))[tid];
    int c0 = tid * 4;
    #pragma unroll
    for (int j = 0; j < 4; ++j) if (c0 + j > t) v[j] = -1e30f;
    float mx = fmaxf(fmaxf(v[0], v[1]), fmaxf(v[2], v[3]));
    #pragma unroll
    for (int m = 1; m < 64; m <<= 1) mx = fmaxf(mx, __shfl_xor(mx, m, 64));
    __shared__ float red[8];
    if ((tid & 63) == 0) red[tid >> 6] = mx;
    __syncthreads();
    mx = fmaxf(fmaxf(red[0], red[1]), fmaxf(red[2], red[3]));
    f32x4 e;
    float sum = 0.f;
    #pragma unroll
    for (int j = 0; j < 4; ++j) { e[j] = expf(v[j] - mx); sum += e[j]; }
    #pragma unroll
    for (int m = 1; m < 64; m <<= 1) sum += __shfl_xor(sum, m, 64);
    if ((tid & 63) == 0) red[4 + (tid >> 6)] = sum;
    __syncthreads();
    sum = red[4] + red[5] + red[6] + red[7];
    float inv = 1.0f / sum;
    bf16x4 hv, lv;
    #pragma unroll
    for (int j = 0; j < 4; ++j) {
        float p = e[j] * inv;
        bf16_t hb = (bf16_t)p;
        hv[j] = hb;
        lv[j] = (bf16_t)(p - (float)hb);
    }
    ((bf16x4*)(ph + row * 1024))[tid] = hv;
    ((bf16x4*)(pl + row * 1024))[tid] = lv;
}

// silu(g)*u over gu planes [1024][8192] (g cols 0-4095, u 4096-8191) -> sil planes [1024][4096]
__global__ __launch_bounds__(256)
void silu_mul(const bf16_t* __restrict__ guh, const bf16_t* __restrict__ gul,
              bf16_t* __restrict__ sh, bf16_t* __restrict__ sl)
{
    size_t idx = (size_t)blockIdx.x * 1024 + threadIdx.x * 4;
    size_t rrow = idx >> 12, col = idx & 4095;
    size_t gb = (rrow * 8192 + col) >> 2;
    size_t ub = gb + (4096 >> 2);
    bf16x4 gh4 = ((const bf16x4*)guh)[gb], gl4 = ((const bf16x4*)gul)[gb];
    bf16x4 uh4 = ((const bf16x4*)guh)[ub], ul4 = ((const bf16x4*)gul)[ub];
    bf16x4 hv, lv;
    #pragma unroll
    for (int j = 0; j < 4; ++j) {
        float g = (float)gh4[j] + (float)gl4[j];
        float u = (float)uh4[j] + (float)ul4[j];
        float o = (g / (1.0f + expf(-g))) * u;
        bf16_t hb = (bf16_t)o;
        hv[j] = hb;
        lv[j] = (bf16_t)(o - (float)hb);
    }
    ((bf16x4*)sh)[idx >> 2] = hv;
    ((bf16x4*)sl)[idx >> 2] = lv;
}

extern "C" void kernel_launch(void* const* d_in, const int* in_sizes, int n_in,
                              void* d_out, int out_size, void* d_ws, size_t ws_size,
                              hipStream_t stream)
{
    (void)in_sizes; (void)n_in; (void)out_size; (void)ws_size;
    const int*   x_ids = (const int*)  d_in[0];
    const float* embed = (const float*)d_in[1];
    const float* ln1   = (const float*)d_in[2];
    const float* Wq    = (const float*)d_in[3];
    const float* Wk    = (const float*)d_in[4];
    const float* Wv    = (const float*)d_in[5];
    const float* Wo    = (const float*)d_in[6];
    const float* qn    = (const float*)d_in[7];
    const float* kn    = (const float*)d_in[8];
    const float* ln2   = (const float*)d_in[9];
    const float* Wg    = (const float*)d_in[10];
    const float* Wu    = (const float*)d_in[11];
    const float* Wd    = (const float*)d_in[12];
    const float* lnout = (const float*)d_in[13];
    float* out = (float*)d_out;

    char* ws = (char*)d_ws;
    const size_t MB = 1 << 20;
    float*  h    = (float*) (ws +   0 * MB);  // 4 MB fp32 residual
    bf16_t* hnh  = (bf16_t*)(ws +   4 * MB);
    bf16_t* hnl  = (bf16_t*)(ws +   6 * MB);
    bf16_t* qkvh = (bf16_t*)(ws +   8 * MB);  // 6 MB [1024][3072]
    bf16_t* qkvl = (bf16_t*)(ws +  14 * MB);
    bf16_t* vTh  = (bf16_t*)(ws +  20 * MB);
    bf16_t* vTl  = (bf16_t*)(ws +  22 * MB);
    bf16_t* oh   = (bf16_t*)(ws +  24 * MB);
    bf16_t* ol   = (bf16_t*)(ws +  26 * MB);
    bf16_t* wAh  = (bf16_t*)(ws +  28 * MB);  // 8 MB [4096][1024] packed wq|wk|wv|wo
    bf16_t* wAl  = (bf16_t*)(ws +  36 * MB);
    float*  sc   = (float*) (ws +  44 * MB);  // 64 MB scores [16][1024][1024]
    bf16_t* ph   = (bf16_t*)(ws + 108 * MB);  // 32 MB
    bf16_t* pl   = (bf16_t*)(ws + 140 * MB);  // 32 MB; high-water 172 MB
    // overlays (dead sc/ph/pl regions, valid after softmax/PV):
    bf16_t* wGUh = (bf16_t*)(ws +  44 * MB);  // 16 MB [8192][1024] packed wg|wu
    bf16_t* wGUl = (bf16_t*)(ws +  60 * MB);
    bf16_t* wdh  = (bf16_t*)(ws +  76 * MB);  // 8 MB [1024][4096]
    bf16_t* wdl  = (bf16_t*)(ws +  84 * MB);
    bf16_t* guh  = (bf16_t*)(ws +  92 * MB);  // 16 MB [1024][8192]
    bf16_t* gul  = (bf16_t*)(ws + 108 * MB);
    bf16_t* silh = (bf16_t*)(ws + 124 * MB);  // 8 MB [1024][4096]
    bf16_t* sill = (bf16_t*)(ws + 132 * MB);
    bf16_t* eh   = (bf16_t*)(ws +  44 * MB);  // 62.5 MB embed-hi (logits, 1-plane)

    const long long M1 = 1024 * 1024;

    gather_kernel<<<1024, 256, 0, stream>>>(x_ids, embed, h);

    for (int l = 0; l < 6; ++l) {
        const float* wq = Wq + (size_t)l * M1;
        const float* wk = Wk + (size_t)l * M1;
        const float* wv = Wv + (size_t)l * M1;
        const float* wo = Wo + (size_t)l * M1;
        const float* wg = Wg + (size_t)l * 4 * M1;
        const float* wu = Wu + (size_t)l * 4 * M1;
        const float* wd = Wd + (size_t)l * 4 * M1;

        split_attn<<<4096, 256, 0, stream>>>(wq, wk, wv, wo, wAh, wAl);
        rmsnorm_split<<<1024, 256, 0, stream>>>(h, ln1 + l * 1024, hnh, hnl);

        // fused QKV: [1024][3072] = hn @ wA[0:3072]^T
        gemm_bf16<64,128,3,EP_SPLIT,false><<<dim3(16,24,1),256,0,stream>>>(
            hnh, hnl, wAh, wAl, nullptr, qkvh, qkvl,
            1024, 1024, 1024, 3072, 0, 0, 0, 0.f);

        qknorm_rope<<<1024, 256, 0, stream>>>(qkvh, qkvl, qn + l * 64, kn + l * 64);
        transpose_v<<<dim3(32,32,2), 256, 0, stream>>>(qkvh, qkvl, vTh, vTl);

        // scores (1-plane): per-head q·k^T, softcap+mask; masked tiles skipped
        gemm_bf16<128,128,1,EP_ATTN,false><<<dim3(8,8,16),256,0,stream>>>(
            qkvh, nullptr, qkvh + 1024, nullptr, sc, nullptr, nullptr,
            64, 3072, 3072, 1024, 64, 64, M1, 0.125f);

        softmax_split<<<16 * 1024, 256, 0, stream>>>(sc, ph, pl);

        // o[h] = P_h @ V_h
        gemm_bf16<64,64,3,EP_SPLIT,true><<<dim3(16,1,16),256,0,stream>>>(
            ph, pl, vTh, vTl, nullptr, oh, ol,
            1024, 1024, 1024, 1024, M1, 64 * 1024, 64, 0.f);

        // sc/ph/pl dead: stage MLP weight planes into their region
        split_gu<<<8192, 256, 0, stream>>>(wg, wu, wGUh, wGUl);
        split_kernel<<<4096, 256, 0, stream>>>(wd, wdh, wdl);

        gemm_bf16<64,64,3,EP_RESID,false><<<dim3(16,16,1),256,0,stream>>>(
            oh, ol, wAh + 3 * M1, wAl + 3 * M1, h, nullptr, nullptr,
            1024, 1024, 1024, 1024, 0, 0, 0, 0.f);

        rmsnorm_split<<<1024, 256, 0, stream>>>(h, ln2 + l * 1024, hnh, hnl);

        // fused gate+up: [1024][8192]
        gemm_bf16<128,128,3,EP_SPLIT,false><<<dim3(8,64,1),256,0,stream>>>(
            hnh, hnl, wGUh, wGUl, nullptr, guh, gul,
            1024, 1024, 1024, 8192, 0, 0, 0, 0.f);

        silu_mul<<<4096, 256, 0, stream>>>(guh, gul, silh, sill);

        gemm_bf16<64,64,3,EP_RESID,false><<<dim3(16,16,1),256,0,stream>>>(
            silh, sill, wdh, wdl, h, nullptr, nullptr,
            4096, 4096, 4096, 1024, 0, 0, 0, 0.f);
    }

    rmsnorm_split<<<1024, 256, 0, stream>>>(h, lnout, hnh, hnl);
    split_kernel<<<32000, 256, 0, stream>>>(embed, eh, nullptr);
    // logits (1-plane): [1024][32000]
    gemm_bf16<128,128,1,EP_STORE,false><<<dim3(8,250,1),256,0,stream>>>(
        hnh, nullptr, eh, nullptr, out, nullptr, nullptr,
        1024, 1024, 1024, 32000, 0, 0, 0, 0.f);
}

// Round 4
// 1713.327 us; speedup vs baseline: 4.5560x; 1.0686x over previous
//
#include <hip/hip_runtime.h>
#include <math.h>

typedef __bf16 bf16_t;
typedef bf16_t bf16x4 __attribute__((ext_vector_type(4)));
typedef bf16_t bf16x8 __attribute__((ext_vector_type(8)));
typedef float  f32x4  __attribute__((ext_vector_type(4)));

#define RMS_EPS 1e-6f

enum { EP_STORE = 0, EP_RESID = 1, EP_SPLIT = 2 };

static __device__ __forceinline__ f32x4 mfma16(bf16x8 a, bf16x8 b, f32x4 c) {
    return __builtin_amdgcn_mfma_f32_16x16x32_bf16(a, b, c, 0, 0, 0);
}

#define GLDS(gp, lp) __builtin_amdgcn_global_load_lds( \
    (const __attribute__((address_space(1))) void*)(gp), \
    (__attribute__((address_space(3))) void*)(lp), 16, 0, 0)

// C[M,N] = A[M,K]*B[N,K]^T.
// PLANES==3: full split-fp32 (ah·bh + al·bh + ah·bl).
// PLANES==2: A split, B hi-only (ah·bh + al·bh) — GU/Wd (error ~1e-3 rel).
// PLANES==1: hi-only (logits).
// LDS [rows][32] bf16; 16B chunks XOR-swizzled via pre-swizzled global source.
template<int BM, int BN, int PLANES, int EPIL>
__global__ __launch_bounds__(256, 4)
void gemm_bf16(const bf16_t* __restrict__ Ah, const bf16_t* __restrict__ Al,
               const bf16_t* __restrict__ Bh, const bf16_t* __restrict__ Bl,
               float* __restrict__ Cf, bf16_t* __restrict__ Ch, bf16_t* __restrict__ Cl,
               int K, int lda, int ldb, int ldc)
{
    __shared__ __align__(16) bf16_t sAh[BM*32], sBh[BN*32];
    __shared__ __align__(16) bf16_t sAl[PLANES >= 2 ? BM*32 : 8];
    __shared__ __align__(16) bf16_t sBl[PLANES >= 3 ? BN*32 : 8];

    const int gx = gridDim.x;
    int id = blockIdx.x + gx * blockIdx.y;
    {   // bijective XCD swizzle (m204)
        int nwg = gx * gridDim.y;
        int q = nwg >> 3, r = nwg & 7;
        int xcd = id & 7, ix = id >> 3;
        id = (xcd < r ? xcd * (q + 1) : r * (q + 1) + (xcd - r) * q) + ix;
    }
    const int bm = id % gx, bn = id / gx;
    const int row0 = bm * BM, col0 = bn * BN;

    const int tid = threadIdx.x, lane = tid & 63, wave = tid >> 6;
    const int lr = lane & 15, lg = lane >> 4;
    constexpr int WM = BM / 2, WN = BN / 2, MF = WM / 16, NF = WN / 16;
    const int wm = wave >> 1, wn = wave & 1;

    f32x4 acc[MF][NF];
    #pragma unroll
    for (int m = 0; m < MF; ++m)
        #pragma unroll
        for (int n = 0; n < NF; ++n) acc[m][n] = (f32x4){0.f, 0.f, 0.f, 0.f};

    for (int k0 = 0; k0 < K; k0 += 32) {
        __syncthreads();
        #pragma unroll
        for (int i = wave; i < BM / 16; i += 4) {
            int s = i * 64 + lane, rr = s >> 2, c = s & 3;
            size_t go = (size_t)(row0 + rr) * lda + k0 + ((c ^ ((rr >> 1) & 3)) << 3);
            GLDS(Ah + go, sAh + i * 512);
            if constexpr (PLANES >= 2) GLDS(Al + go, sAl + i * 512);
        }
        #pragma unroll
        for (int i = wave; i < BN / 16; i += 4) {
            int s = i * 64 + lane, rr = s >> 2, c = s & 3;
            size_t go = (size_t)(col0 + rr) * ldb + k0 + ((c ^ ((rr >> 1) & 3)) << 3);
            GLDS(Bh + go, sBh + i * 512);
            if constexpr (PLANES >= 3) GLDS(Bl + go, sBl + i * 512);
        }
        __syncthreads();

        bf16x8 ah[MF], al[MF], bh[NF], bl[NF];
        #pragma unroll
        for (int m = 0; m < MF; ++m) {
            int rr = wm * WM + m * 16 + lr;
            int by = rr * 64 + ((lg ^ ((rr >> 1) & 3)) << 4);
            ah[m] = *(const bf16x8*)((const char*)sAh + by);
            if constexpr (PLANES >= 2) al[m] = *(const bf16x8*)((const char*)sAl + by);
        }
        #pragma unroll
        for (int n = 0; n < NF; ++n) {
            int rr = wn * WN + n * 16 + lr;
            int by = rr * 64 + ((lg ^ ((rr >> 1) & 3)) << 4);
            bh[n] = *(const bf16x8*)((const char*)sBh + by);
            if constexpr (PLANES >= 3) bl[n] = *(const bf16x8*)((const char*)sBl + by);
        }
        #pragma unroll
        for (int m = 0; m < MF; ++m)
            #pragma unroll
            for (int n = 0; n < NF; ++n) {
                acc[m][n] = mfma16(ah[m], bh[n], acc[m][n]);
                if constexpr (PLANES >= 2) acc[m][n] = mfma16(al[m], bh[n], acc[m][n]);
                if constexpr (PLANES >= 3) acc[m][n] = mfma16(ah[m], bl[n], acc[m][n]);
            }
    }

    #pragma unroll
    for (int m = 0; m < MF; ++m)
        #pragma unroll
        for (int n = 0; n < NF; ++n)
            #pragma unroll
            for (int r = 0; r < 4; ++r) {
                int grow = row0 + wm * WM + m * 16 + lg * 4 + r;
                int gcol = col0 + wn * WN + n * 16 + lr;
                size_t off = (size_t)grow * ldc + gcol;
                float v = acc[m][n][r];
                if constexpr (EPIL == EP_STORE) {
                    Cf[off] = v;
                } else if constexpr (EPIL == EP_RESID) {
                    Cf[off] += v;
                } else {  // EP_SPLIT
                    bf16_t hb = (bf16_t)v;
                    Ch[off] = hb;
                    Cl[off] = (bf16_t)(v - (float)hb);
                }
            }
}

// Flash attention: QBLK=32 q-rows/block, 2 waves (16 rows each), KB=64 keys/tile.
// Q,K hi-only from packed qkv; V hi+lo from vT planes; softcap+causal+online
// softmax in fp32; P split hi/lo through per-wave LDS; 3-term P·V (= old PV).
__global__ __launch_bounds__(128, 2)
void flash_attn(const bf16_t* __restrict__ qkvh,
                const bf16_t* __restrict__ vTh, const bf16_t* __restrict__ vTl,
                bf16_t* __restrict__ oh, bf16_t* __restrict__ ol)
{
    __shared__ __align__(16) bf16_t sQ[32*64], sK[64*64], sVh[64*64], sVl[64*64];
    __shared__ __align__(16) bf16_t sPh[32*64], sPl[32*64];

    const int q0 = blockIdx.x * 32;
    const int hh = blockIdx.y;
    const int tid = threadIdx.x, lane = tid & 63, w = tid >> 6;
    const int lr = lane & 15, lg = lane >> 4;

    // stage Q rows q0..q0+31 (wave w: rows w*16..+15, 2 GLDS of 8 rows)
    #pragma unroll
    for (int ii = 0; ii < 2; ++ii) {
        int r0 = w * 16 + ii * 8;
        int r  = r0 + (lane >> 3);
        int i  = lane & 7;
        GLDS(qkvh + (size_t)(q0 + r) * 3072 + hh * 64 + ((i ^ (r & 7)) << 3),
             sQ + r0 * 64);
    }
    __syncthreads();

    bf16x8 qa[2];
    #pragma unroll
    for (int ks = 0; ks < 2; ++ks) {
        int r = w * 16 + lr;
        qa[ks] = *(const bf16x8*)((const char*)sQ + r * 128 +
                                  ((((ks << 2) | lg) ^ (r & 7)) << 4));
    }

    f32x4 o_acc[4];
    #pragma unroll
    for (int n = 0; n < 4; ++n) o_acc[n] = (f32x4){0.f, 0.f, 0.f, 0.f};
    float m_run[4] = {-1e30f, -1e30f, -1e30f, -1e30f};
    float l_run[4] = {0.f, 0.f, 0.f, 0.f};

    const int ntiles = ((q0 + 31) >> 6) + 1;
    for (int t = 0; t < ntiles; ++t) {
        const int kv0 = t * 64;
        #pragma unroll
        for (int ii = 0; ii < 4; ++ii) {
            int r0 = w * 32 + ii * 8;
            int r  = r0 + (lane >> 3);
            int i  = lane & 7;
            GLDS(qkvh + (size_t)(kv0 + r) * 3072 + 1024 + hh * 64 + ((i ^ (r & 7)) << 3),
                 sK + r0 * 64);
            GLDS(vTh + (size_t)(hh * 64 + r) * 1024 + kv0 + ((i ^ (r & 7)) << 3),
                 sVh + r0 * 64);
            GLDS(vTl + (size_t)(hh * 64 + r) * 1024 + kv0 + ((i ^ (r & 7)) << 3),
                 sVl + r0 * 64);
        }
        __syncthreads();

        // S = Q·K^T  (rows: q = lg*4+j, cols: key = n*16+lr)
        f32x4 s_acc[4];
        #pragma unroll
        for (int n = 0; n < 4; ++n) s_acc[n] = (f32x4){0.f, 0.f, 0.f, 0.f};
        #pragma unroll
        for (int ks = 0; ks < 2; ++ks)
            #pragma unroll
            for (int n = 0; n < 4; ++n) {
                int r = n * 16 + lr;
                bf16x8 kb = *(const bf16x8*)((const char*)sK + r * 128 +
                                             ((((ks << 2) | lg) ^ (r & 7)) << 4));
                s_acc[n] = mfma16(qa[ks], kb, s_acc[n]);
            }

        // softcap + mask + online softmax update + P write
        #pragma unroll
        for (int j = 0; j < 4; ++j) {
            int qr = q0 + w * 16 + lg * 4 + j;
            float p[4];
            float mx = -1e30f;
            #pragma unroll
            for (int n = 0; n < 4; ++n) {
                float v = s_acc[n][j] * 0.125f;
                v = 50.f * tanhf(v * 0.02f);
                int key = kv0 + n * 16 + lr;
                if (key > qr) v = -1e30f;
                p[n] = v;
                mx = fmaxf(mx, v);
            }
            #pragma unroll
            for (int m = 1; m < 16; m <<= 1) mx = fmaxf(mx, __shfl_xor(mx, m, 64));
            float mn = fmaxf(m_run[j], mx);
            float ef = __expf(m_run[j] - mn);
            m_run[j] = mn;
            float rs = 0.f;
            #pragma unroll
            for (int n = 0; n < 4; ++n) {
                float e = expf(p[n] - mn);
                p[n] = e;
                rs += e;
            }
            #pragma unroll
            for (int m = 1; m < 16; m <<= 1) rs += __shfl_xor(rs, m, 64);
            l_run[j] = l_run[j] * ef + rs;
            #pragma unroll
            for (int n = 0; n < 4; ++n) o_acc[n][j] *= ef;
            int r = w * 16 + lg * 4 + j;
            #pragma unroll
            for (int n = 0; n < 4; ++n) {
                int c = n * 16 + lr;
                int byo = r * 128 + ((((c >> 3) ^ (r & 7)) << 4)) + ((c & 7) << 1);
                bf16_t hb = (bf16_t)p[n];
                *(bf16_t*)((char*)sPh + byo) = hb;
                *(bf16_t*)((char*)sPl + byo) = (bf16_t)(p[n] - (float)hb);
            }
        }

        // O += P·V (3 terms: Ph·Vh + Pl·Vh + Ph·Vl); P read within-wave (no barrier)
        #pragma unroll
        for (int ks = 0; ks < 2; ++ks) {
            int pr = w * 16 + lr;
            int pby = pr * 128 + ((((ks << 2) | lg) ^ (pr & 7)) << 4);
            bf16x8 pa  = *(const bf16x8*)((const char*)sPh + pby);
            bf16x8 pl_ = *(const bf16x8*)((const char*)sPl + pby);
            #pragma unroll
            for (int n = 0; n < 4; ++n) {
                int vr = n * 16 + lr;
                int vby = vr * 128 + ((((ks << 2) | lg) ^ (vr & 7)) << 4);
                bf16x8 vhf = *(const bf16x8*)((const char*)sVh + vby);
                bf16x8 vlf = *(const bf16x8*)((const char*)sVl + vby);
                o_acc[n] = mfma16(pa,  vhf, o_acc[n]);
                o_acc[n] = mfma16(pl_, vhf, o_acc[n]);
                o_acc[n] = mfma16(pa,  vlf, o_acc[n]);
            }
        }
        __syncthreads();
    }

    #pragma unroll
    for (int j = 0; j < 4; ++j) {
        float inv = 1.0f / l_run[j];
        int qr = q0 + w * 16 + lg * 4 + j;
        #pragma unroll
        for (int n = 0; n < 4; ++n) {
            float v = o_acc[n][j] * inv;
            size_t off = (size_t)qr * 1024 + hh * 64 + n * 16 + lr;
            bf16_t hb = (bf16_t)v;
            oh[off] = hb;
            ol[off] = (bf16_t)(v - (float)hb);
        }
    }
}

__global__ __launch_bounds__(256)
void split_kernel(const float* __restrict__ src, bf16_t* __restrict__ hi,
                  bf16_t* __restrict__ lo)
{
    size_t i = (size_t)blockIdx.x * 256 + threadIdx.x;
    f32x4 v = ((const f32x4*)src)[i];
    bf16x4 hv, lv;
    #pragma unroll
    for (int j = 0; j < 4; ++j) {
        bf16_t hb = (bf16_t)v[j];
        hv[j] = hb;
        lv[j] = (bf16_t)(v[j] - (float)hb);
    }
    ((bf16x4*)hi)[i] = hv;
    if (lo) ((bf16x4*)lo)[i] = lv;
}

// pack wq|wk|wv|wo into wA planes [4096x1024] (hi+lo)
__global__ __launch_bounds__(256)
void split_attn(const float* __restrict__ wq, const float* __restrict__ wk,
                const float* __restrict__ wv, const float* __restrict__ wo,
                bf16_t* __restrict__ hi, bf16_t* __restrict__ lo)
{
    int b = blockIdx.x;
    const float* src = b < 1024 ? wq : b < 2048 ? wk : b < 3072 ? wv : wo;
    size_t so = (size_t)(b & 1023) * 256 + threadIdx.x;
    size_t dof = (size_t)b * 256 + threadIdx.x;
    f32x4 v = ((const f32x4*)src)[so];
    bf16x4 hv, lv;
    #pragma unroll
    for (int j = 0; j < 4; ++j) {
        bf16_t hb = (bf16_t)v[j];
        hv[j] = hb;
        lv[j] = (bf16_t)(v[j] - (float)hb);
    }
    ((bf16x4*)hi)[dof] = hv;
    ((bf16x4*)lo)[dof] = lv;
}

// pack wg|wu -> wGU hi [8192x1024], wd -> wd hi [1024x4096] (hi-only: 2-plane GEMMs)
__global__ __launch_bounds__(256)
void split_mlp(const float* __restrict__ wg, const float* __restrict__ wu,
               const float* __restrict__ wd, bf16_t* __restrict__ gu_hi,
               bf16_t* __restrict__ wd_hi)
{
    int b = blockIdx.x;
    const float* src;
    bf16_t* dst;
    size_t so, doff;
    if (b < 8192) {
        src = b < 4096 ? wg : wu;
        so  = (size_t)(b & 4095) * 256 + threadIdx.x;
        doff = (size_t)b * 256 + threadIdx.x;
        dst = gu_hi;
    } else {
        src = wd;
        so  = (size_t)(b - 8192) * 256 + threadIdx.x;
        doff = so;
        dst = wd_hi;
    }
    f32x4 v = ((const f32x4*)src)[so];
    bf16x4 hv;
    #pragma unroll
    for (int j = 0; j < 4; ++j) hv[j] = (bf16_t)v[j];
    ((bf16x4*)dst)[doff] = hv;
}

__global__ __launch_bounds__(256)
void gather_kernel(const int* __restrict__ ids, const float* __restrict__ embed,
                   float* __restrict__ h)
{
    int t = blockIdx.x;
    int row = ids[t];
    const f32x4* src = (const f32x4*)(embed + (size_t)row * 1024);
    f32x4* dst = (f32x4*)(h + (size_t)t * 1024);
    dst[threadIdx.x] = src[threadIdx.x];
}

__global__ __launch_bounds__(256)
void rmsnorm_split(const float* __restrict__ in, const float* __restrict__ w,
                   bf16_t* __restrict__ outh, bf16_t* __restrict__ outl)
{
    int row = blockIdx.x, tid = threadIdx.x;
    f32x4 v = *(const f32x4*)(in + (size_t)row * 1024 + tid * 4);
    float ss = v[0]*v[0] + v[1]*v[1] + v[2]*v[2] + v[3]*v[3];
    #pragma unroll
    for (int m = 1; m < 64; m <<= 1) ss += __shfl_xor(ss, m, 64);
    __shared__ float red[4];
    if ((tid & 63) == 0) red[tid >> 6] = ss;
    __syncthreads();
    float tot = red[0] + red[1] + red[2] + red[3];
    float inv = rsqrtf(tot * (1.0f / 1024.0f) + RMS_EPS);
    f32x4 wv = *(const f32x4*)(w + tid * 4);
    bf16x4 hv, lv;
    #pragma unroll
    for (int j = 0; j < 4; ++j) {
        float x = v[j] * inv * wv[j];
        bf16_t hb = (bf16_t)x;
        hv[j] = hb;
        lv[j] = (bf16_t)(x - (float)hb);
    }
    ((bf16x4*)outh)[(size_t)row * 256 + tid] = hv;
    ((bf16x4*)outl)[(size_t)row * 256 + tid] = lv;
}

// Per-(t,head) RMS over Dh=64 + RoPE on packed qkv [1024][3072].
// Reference quirk: rotation angle = head_index * freq (cos[:n], n = H).
__global__ __launch_bounds__(256)
void qknorm_rope(bf16_t* __restrict__ qkvh, bf16_t* __restrict__ qkvl,
                 const float* __restrict__ qn, const float* __restrict__ kn)
{
    int t = blockIdx.x, tid = threadIdx.x;
    int hh = tid >> 4;
    int i  = (tid & 15) * 4;
    size_t qb = ((size_t)t * 3072 + hh * 64 + i) >> 2;
    size_t kb = qb + (1024 >> 2);

    int p0 = i >> 1;
    float f0 = powf(10000.f, -(float)p0 / 32.f);
    float f1 = powf(10000.f, -(float)(p0 + 1) / 32.f);
    float a0 = (float)hh * f0, a1 = (float)hh * f1;
    float c0 = cosf(a0), s0 = sinf(a0);
    float c1 = cosf(a1), s1 = sinf(a1);

    f32x4 qw = *(const f32x4*)(qn + i);
    f32x4 kw = *(const f32x4*)(kn + i);

    {
        bf16x4 h4 = ((const bf16x4*)qkvh)[qb], l4 = ((const bf16x4*)qkvl)[qb];
        float x[4];
        #pragma unroll
        for (int j = 0; j < 4; ++j) x[j] = (float)h4[j] + (float)l4[j];
        float ss = x[0]*x[0] + x[1]*x[1] + x[2]*x[2] + x[3]*x[3];
        #pragma unroll
        for (int m = 1; m < 16; m <<= 1) ss += __shfl_xor(ss, m, 64);
        float inv = rsqrtf(ss * (1.0f / 64.0f) + RMS_EPS);
        float x0 = x[0]*inv*qw[0], x1 = x[1]*inv*qw[1];
        float x2 = x[2]*inv*qw[2], x3 = x[3]*inv*qw[3];
        bf16x4 o4;
        o4[0] = (bf16_t)(x0*c0 - x1*s0);  o4[1] = (bf16_t)(x0*s0 + x1*c0);
        o4[2] = (bf16_t)(x2*c1 - x3*s1);  o4[3] = (bf16_t)(x2*s1 + x3*c1);
        ((bf16x4*)qkvh)[qb] = o4;
    }
    {
        bf16x4 h4 = ((const bf16x4*)qkvh)[kb], l4 = ((const bf16x4*)qkvl)[kb];
        float x[4];
        #pragma unroll
        for (int j = 0; j < 4; ++j) x[j] = (float)h4[j] + (float)l4[j];
        float ss = x[0]*x[0] + x[1]*x[1] + x[2]*x[2] + x[3]*x[3];
        #pragma unroll
        for (int m = 1; m < 16; m <<= 1) ss += __shfl_xor(ss, m, 64);
        float inv = rsqrtf(ss * (1.0f / 64.0f) + RMS_EPS);
        float x0 = x[0]*inv*kw[0], x1 = x[1]*inv*kw[1];
        float x2 = x[2]*inv*kw[2], x3 = x[3]*inv*kw[3];
        bf16x4 o4;
        o4[0] = (bf16_t)(x0*c0 - x1*s0);  o4[1] = (bf16_t)(x0*s0 + x1*c0);
        o4[2] = (bf16_t)(x2*c1 - x3*s1);  o4[3] = (bf16_t)(x2*s1 + x3*c1);
        ((bf16x4*)qkvh)[kb] = o4;
    }
}

// v (cols 2048-3071 of qkv) -> vT [1024][1024]; z selects hi/lo plane.
__global__ __launch_bounds__(256)
void transpose_v(const bf16_t* __restrict__ inh, const bf16_t* __restrict__ inl,
                 bf16_t* __restrict__ outh, bf16_t* __restrict__ outl)
{
    __shared__ bf16_t tile[32][33];
    const bf16_t* in = blockIdx.z ? inl : inh;
    bf16_t* out      = blockIdx.z ? outl : outh;
    int bx = blockIdx.x * 32, by = blockIdx.y * 32;
    int r = threadIdx.x >> 5, c = threadIdx.x & 31;
    #pragma unroll
    for (int rr = r; rr < 32; rr += 8)
        tile[rr][c] = in[(size_t)(by + rr) * 3072 + 2048 + bx + c];
    __syncthreads();
    #pragma unroll
    for (int rr = r; rr < 32; rr += 8)
        out[(size_t)(bx + rr) * 1024 + by + c] = tile[c][rr];
}

// silu(g)*u over gu planes [1024][8192] -> sil planes [1024][4096] (hi+lo)
__global__ __launch_bounds__(256)
void silu_mul(const bf16_t* __restrict__ guh, const bf16_t* __restrict__ gul,
              bf16_t* __restrict__ sh, bf16_t* __restrict__ sl)
{
    size_t idx = (size_t)blockIdx.x * 1024 + threadIdx.x * 4;
    size_t rrow = idx >> 12, col = idx & 4095;
    size_t gb = (rrow * 8192 + col) >> 2;
    size_t ub = gb + (4096 >> 2);
    bf16x4 gh4 = ((const bf16x4*)guh)[gb], gl4 = ((const bf16x4*)gul)[gb];
    bf16x4 uh4 = ((const bf16x4*)guh)[ub], ul4 = ((const bf16x4*)gul)[ub];
    bf16x4 hv, lv;
    #pragma unroll
    for (int j = 0; j < 4; ++j) {
        float g = (float)gh4[j] + (float)gl4[j];
        float u = (float)uh4[j] + (float)ul4[j];
        float o = (g / (1.0f + expf(-g))) * u;
        bf16_t hb = (bf16_t)o;
        hv[j] = hb;
        lv[j] = (bf16_t)(o - (float)hb);
    }
    ((bf16x4*)sh)[idx >> 2] = hv;
    ((bf16x4*)sl)[idx >> 2] = lv;
}

extern "C" void kernel_launch(void* const* d_in, const int* in_sizes, int n_in,
                              void* d_out, int out_size, void* d_ws, size_t ws_size,
                              hipStream_t stream)
{
    (void)in_sizes; (void)n_in; (void)out_size; (void)ws_size;
    const int*   x_ids = (const int*)  d_in[0];
    const float* embed = (const float*)d_in[1];
    const float* ln1   = (const float*)d_in[2];
    const float* Wq    = (const float*)d_in[3];
    const float* Wk    = (const float*)d_in[4];
    const float* Wv    = (const float*)d_in[5];
    const float* Wo    = (const float*)d_in[6];
    const float* qn    = (const float*)d_in[7];
    const float* kn    = (const float*)d_in[8];
    const float* ln2   = (const float*)d_in[9];
    const float* Wg    = (const float*)d_in[10];
    const float* Wu    = (const float*)d_in[11];
    const float* Wd    = (const float*)d_in[12];
    const float* lnout = (const float*)d_in[13];
    float* out = (float*)d_out;

    char* ws = (char*)d_ws;
    const size_t MB = 1 << 20;
    float*  h    = (float*) (ws +   0 * MB);  // 4 MB fp32 residual
    bf16_t* hnh  = (bf16_t*)(ws +   4 * MB);
    bf16_t* hnl  = (bf16_t*)(ws +   6 * MB);
    bf16_t* qkvh = (bf16_t*)(ws +   8 * MB);  // 6 MB [1024][3072]
    bf16_t* qkvl = (bf16_t*)(ws +  14 * MB);
    bf16_t* vTh  = (bf16_t*)(ws +  20 * MB);
    bf16_t* vTl  = (bf16_t*)(ws +  22 * MB);
    bf16_t* oh   = (bf16_t*)(ws +  24 * MB);
    bf16_t* ol   = (bf16_t*)(ws +  26 * MB);
    bf16_t* wAh  = (bf16_t*)(ws +  28 * MB);  // 8 MB [4096][1024]
    bf16_t* wAl  = (bf16_t*)(ws +  36 * MB);
    bf16_t* wGUh = (bf16_t*)(ws +  44 * MB);  // 16 MB [8192][1024] hi-only
    bf16_t* wdh  = (bf16_t*)(ws +  60 * MB);  //  8 MB [1024][4096] hi-only
    bf16_t* guh  = (bf16_t*)(ws +  68 * MB);  // 16 MB [1024][8192]
    bf16_t* gul  = (bf16_t*)(ws +  84 * MB);
    bf16_t* silh = (bf16_t*)(ws + 100 * MB);  //  8 MB [1024][4096]
    bf16_t* sill = (bf16_t*)(ws + 108 * MB);
    bf16_t* eh   = (bf16_t*)(ws + 116 * MB);  // 62.5 MB embed hi (high-water ~179 MB)

    const long long M1 = 1024 * 1024;

    gather_kernel<<<1024, 256, 0, stream>>>(x_ids, embed, h);

    for (int l = 0; l < 6; ++l) {
        const float* wq = Wq + (size_t)l * M1;
        const float* wk = Wk + (size_t)l * M1;
        const float* wv = Wv + (size_t)l * M1;
        const float* wo = Wo + (size_t)l * M1;
        const float* wg = Wg + (size_t)l * 4 * M1;
        const float* wu = Wu + (size_t)l * 4 * M1;
        const float* wd = Wd + (size_t)l * 4 * M1;

        split_attn<<<4096, 256, 0, stream>>>(wq, wk, wv, wo, wAh, wAl);
        rmsnorm_split<<<1024, 256, 0, stream>>>(h, ln1 + l * 1024, hnh, hnl);

        // fused QKV: [1024][3072] = hn @ wA[0:3072]^T  (3-plane)
        gemm_bf16<64,128,3,EP_SPLIT><<<dim3(16,24),256,0,stream>>>(
            hnh, hnl, wAh, wAl, nullptr, qkvh, qkvl, 1024, 1024, 1024, 3072);

        qknorm_rope<<<1024, 256, 0, stream>>>(qkvh, qkvl, qn + l * 64, kn + l * 64);
        transpose_v<<<dim3(32,32,2), 256, 0, stream>>>(qkvh, qkvl, vTh, vTl);

        // fused scores+softcap+mask+softmax+PV
        flash_attn<<<dim3(32,16), 128, 0, stream>>>(qkvh, vTh, vTl, oh, ol);

        split_mlp<<<12288, 256, 0, stream>>>(wg, wu, wd, wGUh, wdh);

        gemm_bf16<64,64,3,EP_RESID><<<dim3(16,16),256,0,stream>>>(
            oh, ol, wAh + 3 * M1, wAl + 3 * M1, h, nullptr, nullptr,
            1024, 1024, 1024, 1024);

        rmsnorm_split<<<1024, 256, 0, stream>>>(h, ln2 + l * 1024, hnh, hnl);

        // fused gate+up: [1024][8192]  (2-plane: weight hi only)
        gemm_bf16<128,128,2,EP_SPLIT><<<dim3(8,64),256,0,stream>>>(
            hnh, hnl, wGUh, nullptr, nullptr, guh, gul, 1024, 1024, 1024, 8192);

        silu_mul<<<4096, 256, 0, stream>>>(guh, gul, silh, sill);

        // down-proj (2-plane)
        gemm_bf16<64,64,2,EP_RESID><<<dim3(16,16),256,0,stream>>>(
            silh, sill, wdh, nullptr, h, nullptr, nullptr, 4096, 4096, 4096, 1024);
    }

    rmsnorm_split<<<1024, 256, 0, stream>>>(h, lnout, hnh, hnl);
    split_kernel<<<32000, 256, 0, stream>>>(embed, eh, nullptr);
    gemm_bf16<128,128,1,EP_STORE><<<dim3(8,250),256,0,stream>>>(
        hnh, nullptr, eh, nullptr, out, nullptr, nullptr, 1024, 1024, 1024, 32000);
}

// Round 5
// 1612.791 us; speedup vs baseline: 4.8400x; 1.0623x over previous
//
#include <hip/hip_runtime.h>
#include <math.h>

typedef __bf16 bf16_t;
typedef bf16_t bf16x4 __attribute__((ext_vector_type(4)));
typedef bf16_t bf16x8 __attribute__((ext_vector_type(8)));
typedef float  f32x4  __attribute__((ext_vector_type(4)));

#define RMS_EPS 1e-6f

enum { EP_STORE = 0, EP_RESID = 1, EP_SPLIT = 2 };

static __device__ __forceinline__ f32x4 mfma16(bf16x8 a, bf16x8 b, f32x4 c) {
    return __builtin_amdgcn_mfma_f32_16x16x32_bf16(a, b, c, 0, 0, 0);
}

#define GLDS(gp, lp) __builtin_amdgcn_global_load_lds( \
    (const __attribute__((address_space(1))) void*)(gp), \
    (__attribute__((address_space(3))) void*)(lp), 16, 0, 0)

// C[M,N] = A[M,K]*B[N,K]^T.
// PLANES==3: full split-fp32 (ah·bh + al·bh + ah·bl).
// PLANES==2: A split, B hi-only.  PLANES==1: hi-only.
// blockIdx.z = K-chunk for split-K (A/B advance z*K columns; C advances z*sC).
// LDS [rows][32] bf16; 16B chunks XOR-swizzled via pre-swizzled global source.
template<int BM, int BN, int PLANES, int EPIL>
__global__ __launch_bounds__(256, 4)
void gemm_bf16(const bf16_t* __restrict__ Ah, const bf16_t* __restrict__ Al,
               const bf16_t* __restrict__ Bh, const bf16_t* __restrict__ Bl,
               float* __restrict__ Cf, bf16_t* __restrict__ Ch, bf16_t* __restrict__ Cl,
               int K, int lda, int ldb, int ldc, long long sC)
{
    __shared__ __align__(16) bf16_t sAh[BM*32], sBh[BN*32];
    __shared__ __align__(16) bf16_t sAl[PLANES >= 2 ? BM*32 : 8];
    __shared__ __align__(16) bf16_t sBl[PLANES >= 3 ? BN*32 : 8];

    const int gx = gridDim.x;
    int id = blockIdx.x + gx * blockIdx.y;
    if (gridDim.z == 1) {  // bijective XCD swizzle (m204)
        int nwg = gx * gridDim.y;
        int q = nwg >> 3, r = nwg & 7;
        int xcd = id & 7, ix = id >> 3;
        id = (xcd < r ? xcd * (q + 1) : r * (q + 1) + (xcd - r) * q) + ix;
    }
    const int bm = id % gx, bn = id / gx;
    const int row0 = bm * BM, col0 = bn * BN;

    const size_t kofs = (size_t)blockIdx.z * K;  // split-K column offset
    Ah += kofs;  Bh += kofs;
    if constexpr (PLANES >= 2) Al += kofs;
    if constexpr (PLANES >= 3) Bl += kofs;

    const int tid = threadIdx.x, lane = tid & 63, wave = tid >> 6;
    const int lr = lane & 15, lg = lane >> 4;
    constexpr int WM = BM / 2, WN = BN / 2, MF = WM / 16, NF = WN / 16;
    const int wm = wave >> 1, wn = wave & 1;

    f32x4 acc[MF][NF];
    #pragma unroll
    for (int m = 0; m < MF; ++m)
        #pragma unroll
        for (int n = 0; n < NF; ++n) acc[m][n] = (f32x4){0.f, 0.f, 0.f, 0.f};

    for (int k0 = 0; k0 < K; k0 += 32) {
        __syncthreads();
        #pragma unroll
        for (int i = wave; i < BM / 16; i += 4) {
            int s = i * 64 + lane, rr = s >> 2, c = s & 3;
            size_t go = (size_t)(row0 + rr) * lda + k0 + ((c ^ ((rr >> 1) & 3)) << 3);
            GLDS(Ah + go, sAh + i * 512);
            if constexpr (PLANES >= 2) GLDS(Al + go, sAl + i * 512);
        }
        #pragma unroll
        for (int i = wave; i < BN / 16; i += 4) {
            int s = i * 64 + lane, rr = s >> 2, c = s & 3;
            size_t go = (size_t)(col0 + rr) * ldb + k0 + ((c ^ ((rr >> 1) & 3)) << 3);
            GLDS(Bh + go, sBh + i * 512);
            if constexpr (PLANES >= 3) GLDS(Bl + go, sBl + i * 512);
        }
        __syncthreads();

        bf16x8 ah[MF], al[MF], bh[NF], bl[NF];
        #pragma unroll
        for (int m = 0; m < MF; ++m) {
            int rr = wm * WM + m * 16 + lr;
            int by = rr * 64 + ((lg ^ ((rr >> 1) & 3)) << 4);
            ah[m] = *(const bf16x8*)((const char*)sAh + by);
            if constexpr (PLANES >= 2) al[m] = *(const bf16x8*)((const char*)sAl + by);
        }
        #pragma unroll
        for (int n = 0; n < NF; ++n) {
            int rr = wn * WN + n * 16 + lr;
            int by = rr * 64 + ((lg ^ ((rr >> 1) & 3)) << 4);
            bh[n] = *(const bf16x8*)((const char*)sBh + by);
            if constexpr (PLANES >= 3) bl[n] = *(const bf16x8*)((const char*)sBl + by);
        }
        #pragma unroll
        for (int m = 0; m < MF; ++m)
            #pragma unroll
            for (int n = 0; n < NF; ++n) {
                acc[m][n] = mfma16(ah[m], bh[n], acc[m][n]);
                if constexpr (PLANES >= 2) acc[m][n] = mfma16(al[m], bh[n], acc[m][n]);
                if constexpr (PLANES >= 3) acc[m][n] = mfma16(ah[m], bl[n], acc[m][n]);
            }
    }

    #pragma unroll
    for (int m = 0; m < MF; ++m)
        #pragma unroll
        for (int n = 0; n < NF; ++n)
            #pragma unroll
            for (int r = 0; r < 4; ++r) {
                int grow = row0 + wm * WM + m * 16 + lg * 4 + r;
                int gcol = col0 + wn * WN + n * 16 + lr;
                size_t off = (size_t)blockIdx.z * sC + (size_t)grow * ldc + gcol;
                float v = acc[m][n][r];
                if constexpr (EPIL == EP_STORE) {
                    Cf[off] = v;
                } else if constexpr (EPIL == EP_RESID) {
                    Cf[off] += v;
                } else {  // EP_SPLIT
                    bf16_t hb = (bf16_t)v;
                    Ch[off] = hb;
                    Cl[off] = (bf16_t)(v - (float)hb);
                }
            }
}

// h += p0+p1+p2+p3 (split-K reduce, deterministic order). 1M floats.
__global__ __launch_bounds__(256)
void reduce4_kernel(const float* __restrict__ p, float* __restrict__ h)
{
    size_t i = (size_t)blockIdx.x * 256 + threadIdx.x;
    const size_t S = (1024 * 1024) / 4;
    f32x4 a = ((const f32x4*)p)[i];
    f32x4 b = ((const f32x4*)p)[i + S];
    f32x4 c = ((const f32x4*)p)[i + 2 * S];
    f32x4 d = ((const f32x4*)p)[i + 3 * S];
    f32x4 hv = ((const f32x4*)h)[i];
    #pragma unroll
    for (int j = 0; j < 4; ++j) hv[j] += (a[j] + b[j]) + (c[j] + d[j]);
    ((f32x4*)h)[i] = hv;
}

// Flash attention, triangular-balanced: block (px,hh) handles q-chunks
// {px, 31-px} (QBLK=32 rows each), KB=64 keys/tile -> every block does
// 17-18 tile-iters. 2 waves (16 q-rows each). Q,K hi-only; V hi+lo;
// softcap+causal+online softmax fp32; P hi/lo via per-wave LDS; 3-term P.V.
__global__ __launch_bounds__(128, 2)
void flash_attn(const bf16_t* __restrict__ qkvh,
                const bf16_t* __restrict__ vTh, const bf16_t* __restrict__ vTl,
                bf16_t* __restrict__ oh, bf16_t* __restrict__ ol)
{
    __shared__ __align__(16) bf16_t sQ[32*64], sK[64*64], sVh[64*64], sVl[64*64];
    __shared__ __align__(16) bf16_t sPh[32*64], sPl[32*64];

    const int px = blockIdx.x;
    const int hh = blockIdx.y;
    const int tid = threadIdx.x, lane = tid & 63, w = tid >> 6;
    const int lr = lane & 15, lg = lane >> 4;

    for (int cc = 0; cc < 2; ++cc) {
        const int qb = cc ? 31 - px : px;
        const int q0 = qb * 32;

        // stage Q rows q0..q0+31 (wave w: rows w*16..+15)
        #pragma unroll
        for (int ii = 0; ii < 2; ++ii) {
            int r0 = w * 16 + ii * 8;
            int r  = r0 + (lane >> 3);
            int i  = lane & 7;
            GLDS(qkvh + (size_t)(q0 + r) * 3072 + hh * 64 + ((i ^ (r & 7)) << 3),
                 sQ + r0 * 64);
        }
        __syncthreads();

        bf16x8 qa[2];
        #pragma unroll
        for (int ks = 0; ks < 2; ++ks) {
            int r = w * 16 + lr;
            qa[ks] = *(const bf16x8*)((const char*)sQ + r * 128 +
                                      ((((ks << 2) | lg) ^ (r & 7)) << 4));
        }

        f32x4 o_acc[4];
        #pragma unroll
        for (int n = 0; n < 4; ++n) o_acc[n] = (f32x4){0.f, 0.f, 0.f, 0.f};
        float m_run[4] = {-1e30f, -1e30f, -1e30f, -1e30f};
        float l_run[4] = {0.f, 0.f, 0.f, 0.f};

        const int ntiles = ((q0 + 31) >> 6) + 1;
        for (int t = 0; t < ntiles; ++t) {
            const int kv0 = t * 64;
            #pragma unroll
            for (int ii = 0; ii < 4; ++ii) {
                int r0 = w * 32 + ii * 8;
                int r  = r0 + (lane >> 3);
                int i  = lane & 7;
                GLDS(qkvh + (size_t)(kv0 + r) * 3072 + 1024 + hh * 64 + ((i ^ (r & 7)) << 3),
                     sK + r0 * 64);
                GLDS(vTh + (size_t)(hh * 64 + r) * 1024 + kv0 + ((i ^ (r & 7)) << 3),
                     sVh + r0 * 64);
                GLDS(vTl + (size_t)(hh * 64 + r) * 1024 + kv0 + ((i ^ (r & 7)) << 3),
                     sVl + r0 * 64);
            }
            __syncthreads();

            // S = Q.K^T  (rows: q = lg*4+j, cols: key = n*16+lr)
            f32x4 s_acc[4];
            #pragma unroll
            for (int n = 0; n < 4; ++n) s_acc[n] = (f32x4){0.f, 0.f, 0.f, 0.f};
            #pragma unroll
            for (int ks = 0; ks < 2; ++ks)
                #pragma unroll
                for (int n = 0; n < 4; ++n) {
                    int r = n * 16 + lr;
                    bf16x8 kb = *(const bf16x8*)((const char*)sK + r * 128 +
                                                 ((((ks << 2) | lg) ^ (r & 7)) << 4));
                    s_acc[n] = mfma16(qa[ks], kb, s_acc[n]);
                }

            // softcap + mask + online softmax + P write
            #pragma unroll
            for (int j = 0; j < 4; ++j) {
                int qr = q0 + w * 16 + lg * 4 + j;
                float p[4];
                float mx = -1e30f;
                #pragma unroll
                for (int n = 0; n < 4; ++n) {
                    float v = s_acc[n][j] * 0.125f;
                    v = 50.f * tanhf(v * 0.02f);
                    int key = kv0 + n * 16 + lr;
                    if (key > qr) v = -1e30f;
                    p[n] = v;
                    mx = fmaxf(mx, v);
                }
                #pragma unroll
                for (int m = 1; m < 16; m <<= 1) mx = fmaxf(mx, __shfl_xor(mx, m, 64));
                float mn = fmaxf(m_run[j], mx);
                float ef = __expf(m_run[j] - mn);
                m_run[j] = mn;
                float rs = 0.f;
                #pragma unroll
                for (int n = 0; n < 4; ++n) {
                    float e = expf(p[n] - mn);
                    p[n] = e;
                    rs += e;
                }
                #pragma unroll
                for (int m = 1; m < 16; m <<= 1) rs += __shfl_xor(rs, m, 64);
                l_run[j] = l_run[j] * ef + rs;
                #pragma unroll
                for (int n = 0; n < 4; ++n) o_acc[n][j] *= ef;
                int r = w * 16 + lg * 4 + j;
                #pragma unroll
                for (int n = 0; n < 4; ++n) {
                    int c = n * 16 + lr;
                    int byo = r * 128 + ((((c >> 3) ^ (r & 7)) << 4)) + ((c & 7) << 1);
                    bf16_t hb = (bf16_t)p[n];
                    *(bf16_t*)((char*)sPh + byo) = hb;
                    *(bf16_t*)((char*)sPl + byo) = (bf16_t)(p[n] - (float)hb);
                }
            }

            // O += P.V (Ph.Vh + Pl.Vh + Ph.Vl); P read within-wave (no barrier)
            #pragma unroll
            for (int ks = 0; ks < 2; ++ks) {
                int pr = w * 16 + lr;
                int pby = pr * 128 + ((((ks << 2) | lg) ^ (pr & 7)) << 4);
                bf16x8 pa  = *(const bf16x8*)((const char*)sPh + pby);
                bf16x8 pl_ = *(const bf16x8*)((const char*)sPl + pby);
                #pragma unroll
                for (int n = 0; n < 4; ++n) {
                    int vr = n * 16 + lr;
                    int vby = vr * 128 + ((((ks << 2) | lg) ^ (vr & 7)) << 4);
                    bf16x8 vhf = *(const bf16x8*)((const char*)sVh + vby);
                    bf16x8 vlf = *(const bf16x8*)((const char*)sVl + vby);
                    o_acc[n] = mfma16(pa,  vhf, o_acc[n]);
                    o_acc[n] = mfma16(pl_, vhf, o_acc[n]);
                    o_acc[n] = mfma16(pa,  vlf, o_acc[n]);
                }
            }
            __syncthreads();
        }

        #pragma unroll
        for (int j = 0; j < 4; ++j) {
            float inv = 1.0f / l_run[j];
            int qr = q0 + w * 16 + lg * 4 + j;
            #pragma unroll
            for (int n = 0; n < 4; ++n) {
                float v = o_acc[n][j] * inv;
                size_t off = (size_t)qr * 1024 + hh * 64 + n * 16 + lr;
                bf16_t hb = (bf16_t)v;
                oh[off] = hb;
                ol[off] = (bf16_t)(v - (float)hb);
            }
        }
    }
}

__global__ __launch_bounds__(256)
void split_kernel(const float* __restrict__ src, bf16_t* __restrict__ hi,
                  bf16_t* __restrict__ lo)
{
    size_t i = (size_t)blockIdx.x * 256 + threadIdx.x;
    f32x4 v = ((const f32x4*)src)[i];
    bf16x4 hv, lv;
    #pragma unroll
    for (int j = 0; j < 4; ++j) {
        bf16_t hb = (bf16_t)v[j];
        hv[j] = hb;
        lv[j] = (bf16_t)(v[j] - (float)hb);
    }
    ((bf16x4*)hi)[i] = hv;
    if (lo) ((bf16x4*)lo)[i] = lv;
}

// merged weight split: wq|wk|wv|wo -> wA hi+lo [4096x1024];
// wg|wu -> wGU hi [8192x1024]; wd -> wd hi [1024x4096]. 16384 blocks.
__global__ __launch_bounds__(256)
void wsplit_kernel(const float* __restrict__ wq, const float* __restrict__ wk,
                   const float* __restrict__ wv, const float* __restrict__ wo,
                   const float* __restrict__ wg, const float* __restrict__ wu,
                   const float* __restrict__ wd,
                   bf16_t* __restrict__ wAh, bf16_t* __restrict__ wAl,
                   bf16_t* __restrict__ wGUh, bf16_t* __restrict__ wdh)
{
    int b = blockIdx.x;
    if (b < 4096) {
        const float* src = b < 1024 ? wq : b < 2048 ? wk : b < 3072 ? wv : wo;
        size_t so = (size_t)(b & 1023) * 256 + threadIdx.x;
        size_t doff = (size_t)b * 256 + threadIdx.x;
        f32x4 v = ((const f32x4*)src)[so];
        bf16x4 hv, lv;
        #pragma unroll
        for (int j = 0; j < 4; ++j) {
            bf16_t hb = (bf16_t)v[j];
            hv[j] = hb;
            lv[j] = (bf16_t)(v[j] - (float)hb);
        }
        ((bf16x4*)wAh)[doff] = hv;
        ((bf16x4*)wAl)[doff] = lv;
    } else if (b < 12288) {
        int bb = b - 4096;
        const float* src = bb < 4096 ? wg : wu;
        size_t so = (size_t)(bb & 4095) * 256 + threadIdx.x;
        size_t doff = (size_t)bb * 256 + threadIdx.x;
        f32x4 v = ((const f32x4*)src)[so];
        bf16x4 hv;
        #pragma unroll
        for (int j = 0; j < 4; ++j) hv[j] = (bf16_t)v[j];
        ((bf16x4*)wGUh)[doff] = hv;
    } else {
        size_t so = (size_t)(b - 12288) * 256 + threadIdx.x;
        f32x4 v = ((const f32x4*)wd)[so];
        bf16x4 hv;
        #pragma unroll
        for (int j = 0; j < 4; ++j) hv[j] = (bf16_t)v[j];
        ((bf16x4*)wdh)[so] = hv;
    }
}

__global__ __launch_bounds__(256)
void gather_kernel(const int* __restrict__ ids, const float* __restrict__ embed,
                   float* __restrict__ h)
{
    int t = blockIdx.x;
    int row = ids[t];
    const f32x4* src = (const f32x4*)(embed + (size_t)row * 1024);
    f32x4* dst = (f32x4*)(h + (size_t)t * 1024);
    dst[threadIdx.x] = src[threadIdx.x];
}

__global__ __launch_bounds__(256)
void rmsnorm_split(const float* __restrict__ in, const float* __restrict__ w,
                   bf16_t* __restrict__ outh, bf16_t* __restrict__ outl)
{
    int row = blockIdx.x, tid = threadIdx.x;
    f32x4 v = *(const f32x4*)(in + (size_t)row * 1024 + tid * 4);
    float ss = v[0]*v[0] + v[1]*v[1] + v[2]*v[2] + v[3]*v[3];
    #pragma unroll
    for (int m = 1; m < 64; m <<= 1) ss += __shfl_xor(ss, m, 64);
    __shared__ float red[4];
    if ((tid & 63) == 0) red[tid >> 6] = ss;
    __syncthreads();
    float tot = red[0] + red[1] + red[2] + red[3];
    float inv = rsqrtf(tot * (1.0f / 1024.0f) + RMS_EPS);
    f32x4 wv = *(const f32x4*)(w + tid * 4);
    bf16x4 hv, lv;
    #pragma unroll
    for (int j = 0; j < 4; ++j) {
        float x = v[j] * inv * wv[j];
        bf16_t hb = (bf16_t)x;
        hv[j] = hb;
        lv[j] = (bf16_t)(x - (float)hb);
    }
    ((bf16x4*)outh)[(size_t)row * 256 + tid] = hv;
    ((bf16x4*)outl)[(size_t)row * 256 + tid] = lv;
}

// Per-(t,head) RMS over Dh=64 + RoPE on packed qkv [1024][3072].
// Reference quirk: rotation angle = head_index * freq (cos[:n], n = H).
__global__ __launch_bounds__(256)
void qknorm_rope(bf16_t* __restrict__ qkvh, bf16_t* __restrict__ qkvl,
                 const float* __restrict__ qn, const float* __restrict__ kn)
{
    int t = blockIdx.x, tid = threadIdx.x;
    int hh = tid >> 4;
    int i  = (tid & 15) * 4;
    size_t qb = ((size_t)t * 3072 + hh * 64 + i) >> 2;
    size_t kb = qb + (1024 >> 2);

    int p0 = i >> 1;
    float f0 = powf(10000.f, -(float)p0 / 32.f);
    float f1 = powf(10000.f, -(float)(p0 + 1) / 32.f);
    float a0 = (float)hh * f0, a1 = (float)hh * f1;
    float c0 = cosf(a0), s0 = sinf(a0);
    float c1 = cosf(a1), s1 = sinf(a1);

    f32x4 qw = *(const f32x4*)(qn + i);
    f32x4 kw = *(const f32x4*)(kn + i);

    {
        bf16x4 h4 = ((const bf16x4*)qkvh)[qb], l4 = ((const bf16x4*)qkvl)[qb];
        float x[4];
        #pragma unroll
        for (int j = 0; j < 4; ++j) x[j] = (float)h4[j] + (float)l4[j];
        float ss = x[0]*x[0] + x[1]*x[1] + x[2]*x[2] + x[3]*x[3];
        #pragma unroll
        for (int m = 1; m < 16; m <<= 1) ss += __shfl_xor(ss, m, 64);
        float inv = rsqrtf(ss * (1.0f / 64.0f) + RMS_EPS);
        float x0 = x[0]*inv*qw[0], x1 = x[1]*inv*qw[1];
        float x2 = x[2]*inv*qw[2], x3 = x[3]*inv*qw[3];
        bf16x4 o4;
        o4[0] = (bf16_t)(x0*c0 - x1*s0);  o4[1] = (bf16_t)(x0*s0 + x1*c0);
        o4[2] = (bf16_t)(x2*c1 - x3*s1);  o4[3] = (bf16_t)(x2*s1 + x3*c1);
        ((bf16x4*)qkvh)[qb] = o4;
    }
    {
        bf16x4 h4 = ((const bf16x4*)qkvh)[kb], l4 = ((const bf16x4*)qkvl)[kb];
        float x[4];
        #pragma unroll
        for (int j = 0; j < 4; ++j) x[j] = (float)h4[j] + (float)l4[j];
        float ss = x[0]*x[0] + x[1]*x[1] + x[2]*x[2] + x[3]*x[3];
        #pragma unroll
        for (int m = 1; m < 16; m <<= 1) ss += __shfl_xor(ss, m, 64);
        float inv = rsqrtf(ss * (1.0f / 64.0f) + RMS_EPS);
        float x0 = x[0]*inv*kw[0], x1 = x[1]*inv*kw[1];
        float x2 = x[2]*inv*kw[2], x3 = x[3]*inv*kw[3];
        bf16x4 o4;
        o4[0] = (bf16_t)(x0*c0 - x1*s0);  o4[1] = (bf16_t)(x0*s0 + x1*c0);
        o4[2] = (bf16_t)(x2*c1 - x3*s1);  o4[3] = (bf16_t)(x2*s1 + x3*c1);
        ((bf16x4*)qkvh)[kb] = o4;
    }
}

// v (cols 2048-3071 of qkv) -> vT [1024][1024]; z selects hi/lo plane.
__global__ __launch_bounds__(256)
void transpose_v(const bf16_t* __restrict__ inh, const bf16_t* __restrict__ inl,
                 bf16_t* __restrict__ outh, bf16_t* __restrict__ outl)
{
    __shared__ bf16_t tile[32][33];
    const bf16_t* in = blockIdx.z ? inl : inh;
    bf16_t* out      = blockIdx.z ? outl : outh;
    int bx = blockIdx.x * 32, by = blockIdx.y * 32;
    int r = threadIdx.x >> 5, c = threadIdx.x & 31;
    #pragma unroll
    for (int rr = r; rr < 32; rr += 8)
        tile[rr][c] = in[(size_t)(by + rr) * 3072 + 2048 + bx + c];
    __syncthreads();
    #pragma unroll
    for (int rr = r; rr < 32; rr += 8)
        out[(size_t)(bx + rr) * 1024 + by + c] = tile[c][rr];
}

// silu(g)*u over gu planes [1024][8192] -> sil planes [1024][4096] (hi+lo)
__global__ __launch_bounds__(256)
void silu_mul(const bf16_t* __restrict__ guh, const bf16_t* __restrict__ gul,
              bf16_t* __restrict__ sh, bf16_t* __restrict__ sl)
{
    size_t idx = (size_t)blockIdx.x * 1024 + threadIdx.x * 4;
    size_t rrow = idx >> 12, col = idx & 4095;
    size_t gb = (rrow * 8192 + col) >> 2;
    size_t ub = gb + (4096 >> 2);
    bf16x4 gh4 = ((const bf16x4*)guh)[gb], gl4 = ((const bf16x4*)gul)[gb];
    bf16x4 uh4 = ((const bf16x4*)guh)[ub], ul4 = ((const bf16x4*)gul)[ub];
    bf16x4 hv, lv;
    #pragma unroll
    for (int j = 0; j < 4; ++j) {
        float g = (float)gh4[j] + (float)gl4[j];
        float u = (float)uh4[j] + (float)ul4[j];
        float o = (g / (1.0f + expf(-g))) * u;
        bf16_t hb = (bf16_t)o;
        hv[j] = hb;
        lv[j] = (bf16_t)(o - (float)hb);
    }
    ((bf16x4*)sh)[idx >> 2] = hv;
    ((bf16x4*)sl)[idx >> 2] = lv;
}

extern "C" void kernel_launch(void* const* d_in, const int* in_sizes, int n_in,
                              void* d_out, int out_size, void* d_ws, size_t ws_size,
                              hipStream_t stream)
{
    (void)in_sizes; (void)n_in; (void)out_size; (void)ws_size;
    const int*   x_ids = (const int*)  d_in[0];
    const float* embed = (const float*)d_in[1];
    const float* ln1   = (const float*)d_in[2];
    const float* Wq    = (const float*)d_in[3];
    const float* Wk    = (const float*)d_in[4];
    const float* Wv    = (const float*)d_in[5];
    const float* Wo    = (const float*)d_in[6];
    const float* qn    = (const float*)d_in[7];
    const float* kn    = (const float*)d_in[8];
    const float* ln2   = (const float*)d_in[9];
    const float* Wg    = (const float*)d_in[10];
    const float* Wu    = (const float*)d_in[11];
    const float* Wd    = (const float*)d_in[12];
    const float* lnout = (const float*)d_in[13];
    float* out = (float*)d_out;

    char* ws = (char*)d_ws;
    const size_t MB = 1 << 20;
    float*  h    = (float*) (ws +   0 * MB);  // 4 MB fp32 residual
    bf16_t* hnh  = (bf16_t*)(ws +   4 * MB);
    bf16_t* hnl  = (bf16_t*)(ws +   6 * MB);
    bf16_t* qkvh = (bf16_t*)(ws +   8 * MB);  // 6 MB [1024][3072]
    bf16_t* qkvl = (bf16_t*)(ws +  14 * MB);
    bf16_t* vTh  = (bf16_t*)(ws +  20 * MB);
    bf16_t* vTl  = (bf16_t*)(ws +  22 * MB);
    bf16_t* oh   = (bf16_t*)(ws +  24 * MB);
    bf16_t* ol   = (bf16_t*)(ws +  26 * MB);
    bf16_t* wAh  = (bf16_t*)(ws +  28 * MB);  // 8 MB [4096][1024]
    bf16_t* wAl  = (bf16_t*)(ws +  36 * MB);
    bf16_t* wGUh = (bf16_t*)(ws +  44 * MB);  // 16 MB [8192][1024] hi-only
    bf16_t* wdh  = (bf16_t*)(ws +  60 * MB);  //  8 MB [1024][4096] hi-only
    bf16_t* guh  = (bf16_t*)(ws +  68 * MB);  // 16 MB [1024][8192]
    bf16_t* gul  = (bf16_t*)(ws +  84 * MB);
    bf16_t* silh = (bf16_t*)(ws + 100 * MB);  //  8 MB [1024][4096]
    bf16_t* sill = (bf16_t*)(ws + 108 * MB);
    float*  wdp  = (float*) (ws + 116 * MB);  // 16 MB split-K partials [4][1024][1024]
    bf16_t* eh   = (bf16_t*)(ws + 132 * MB);  // 62.5 MB embed hi (high-water ~195 MB)

    const long long M1 = 1024 * 1024;

    gather_kernel<<<1024, 256, 0, stream>>>(x_ids, embed, h);

    for (int l = 0; l < 6; ++l) {
        const float* wq = Wq + (size_t)l * M1;
        const float* wk = Wk + (size_t)l * M1;
        const float* wv = Wv + (size_t)l * M1;
        const float* wo = Wo + (size_t)l * M1;
        const float* wg = Wg + (size_t)l * 4 * M1;
        const float* wu = Wu + (size_t)l * 4 * M1;
        const float* wd = Wd + (size_t)l * 4 * M1;

        wsplit_kernel<<<16384, 256, 0, stream>>>(wq, wk, wv, wo, wg, wu, wd,
                                                 wAh, wAl, wGUh, wdh);
        rmsnorm_split<<<1024, 256, 0, stream>>>(h, ln1 + l * 1024, hnh, hnl);

        // fused QKV: [1024][3072] = hn @ wA[0:3072]^T  (3-plane, 128^2 tiles)
        gemm_bf16<128,128,3,EP_SPLIT><<<dim3(8,24),256,0,stream>>>(
            hnh, hnl, wAh, wAl, nullptr, qkvh, qkvl, 1024, 1024, 1024, 3072, 0);

        qknorm_rope<<<1024, 256, 0, stream>>>(qkvh, qkvl, qn + l * 64, kn + l * 64);
        transpose_v<<<dim3(32,32,2), 256, 0, stream>>>(qkvh, qkvl, vTh, vTl);

        // fused scores+softcap+mask+softmax+PV (triangular-balanced)
        flash_attn<<<dim3(16,16), 128, 0, stream>>>(qkvh, vTh, vTl, oh, ol);

        gemm_bf16<64,64,3,EP_RESID><<<dim3(16,16),256,0,stream>>>(
            oh, ol, wAh + 3 * M1, wAl + 3 * M1, h, nullptr, nullptr,
            1024, 1024, 1024, 1024, 0);

        rmsnorm_split<<<1024, 256, 0, stream>>>(h, ln2 + l * 1024, hnh, hnl);

        // fused gate+up: [1024][8192]  (2-plane)
        gemm_bf16<128,128,2,EP_SPLIT><<<dim3(8,64),256,0,stream>>>(
            hnh, hnl, wGUh, nullptr, nullptr, guh, gul, 1024, 1024, 1024, 8192, 0);

        silu_mul<<<4096, 256, 0, stream>>>(guh, gul, silh, sill);

        // down-proj: split-K x4 (2-plane, 128^2 tiles) -> partials, then reduce
        gemm_bf16<128,128,2,EP_STORE><<<dim3(8,8,4),256,0,stream>>>(
            silh, sill, wdh, nullptr, wdp, nullptr, nullptr,
            1024, 4096, 4096, 1024, M1);
        reduce4_kernel<<<1024, 256, 0, stream>>>(wdp, h);
    }

    rmsnorm_split<<<1024, 256, 0, stream>>>(h, lnout, hnh, hnl);
    split_kernel<<<32000, 256, 0, stream>>>(embed, eh, nullptr);
    gemm_bf16<128,128,1,EP_STORE><<<dim3(8,250),256,0,stream>>>(
        hnh, nullptr, eh, nullptr, out, nullptr, nullptr, 1024, 1024, 1024, 32000, 0);
}

// Round 6
// 1523.985 us; speedup vs baseline: 5.1220x; 1.0583x over previous
//
#include <hip/hip_runtime.h>
#include <math.h>
#include <type_traits>

typedef __bf16 bf16_t;
typedef bf16_t bf16x4 __attribute__((ext_vector_type(4)));
typedef bf16_t bf16x8 __attribute__((ext_vector_type(8)));
typedef float  f32x4  __attribute__((ext_vector_type(4)));

#define RMS_EPS 1e-6f

enum { EP_STORE = 0, EP_RESID = 1, EP_SPLIT = 2 };

template<int V> using IC = std::integral_constant<int, V>;

static __device__ __forceinline__ f32x4 mfma16(bf16x8 a, bf16x8 b, f32x4 c) {
    return __builtin_amdgcn_mfma_f32_16x16x32_bf16(a, b, c, 0, 0, 0);
}

#define GLDS(gp, lp) __builtin_amdgcn_global_load_lds( \
    (const __attribute__((address_space(1))) void*)(gp), \
    (__attribute__((address_space(3))) void*)(lp), 16, 0, 0)

// C[M,N] = A[M,K]*B[N,K]^T.
// PLANES==2: A split hi/lo, B hi-only (2 MFMAs).  PLANES==1: hi-only.
// Double-buffered LDS with single-barrier prefetch K-loop (T3-minimum):
//   STAGE(next buf) -> compute(cur) -> __syncthreads() [vmcnt0 drains prefetch,
//   which flew during compute].  Static buffer indices (unrolled pairs) so the
//   compiler proves no LDS aliasing between in-flight stage and ds_reads.
// Requires K % 64 == 0 (all call sites use K = 1024).
// blockIdx.z = K-chunk for split-K (A/B advance z*K cols; C advances z*sC).
template<int BM, int BN, int PLANES, int EPIL>
__global__ __launch_bounds__(256, 3)
void gemm_bf16(const bf16_t* __restrict__ Ah, const bf16_t* __restrict__ Al,
               const bf16_t* __restrict__ Bh,
               float* __restrict__ Cf, bf16_t* __restrict__ Ch, bf16_t* __restrict__ Cl,
               int K, int lda, int ldb, int ldc, long long sC)
{
    constexpr int ASZ = BM * 32, BSZ = BN * 32;
    __shared__ __align__(16) bf16_t sAh[2][ASZ], sBh[2][BSZ];
    __shared__ __align__(16) bf16_t sAl[PLANES >= 2 ? 2 : 1][PLANES >= 2 ? ASZ : 8];

    const int gx = gridDim.x;
    int id = blockIdx.x + gx * blockIdx.y;
    if (gridDim.z == 1) {  // bijective XCD swizzle (m204)
        int nwg = gx * gridDim.y;
        int q = nwg >> 3, r = nwg & 7;
        int xcd = id & 7, ix = id >> 3;
        id = (xcd < r ? xcd * (q + 1) : r * (q + 1) + (xcd - r) * q) + ix;
    }
    const int bm = id % gx, bn = id / gx;
    const int row0 = bm * BM, col0 = bn * BN;

    const size_t kofs = (size_t)blockIdx.z * K;
    Ah += kofs;  Bh += kofs;
    if constexpr (PLANES >= 2) Al += kofs;

    const int tid = threadIdx.x, lane = tid & 63, wave = tid >> 6;
    const int lr = lane & 15, lg = lane >> 4;
    constexpr int WM = BM / 2, WN = BN / 2, MF = WM / 16, NF = WN / 16;
    const int wm = wave >> 1, wn = wave & 1;

    f32x4 acc[MF][NF];
    #pragma unroll
    for (int m = 0; m < MF; ++m)
        #pragma unroll
        for (int n = 0; n < NF; ++n) acc[m][n] = (f32x4){0.f, 0.f, 0.f, 0.f};

    auto stage = [&](int k0, auto pc) {
        constexpr int p = decltype(pc)::value;
        #pragma unroll
        for (int i = wave; i < BM / 16; i += 4) {
            int s = i * 64 + lane, rr = s >> 2, c = s & 3;
            size_t go = (size_t)(row0 + rr) * lda + k0 + ((c ^ ((rr >> 1) & 3)) << 3);
            GLDS(Ah + go, &sAh[p][i * 512]);
            if constexpr (PLANES >= 2) GLDS(Al + go, &sAl[p][i * 512]);
        }
        #pragma unroll
        for (int i = wave; i < BN / 16; i += 4) {
            int s = i * 64 + lane, rr = s >> 2, c = s & 3;
            size_t go = (size_t)(col0 + rr) * ldb + k0 + ((c ^ ((rr >> 1) & 3)) << 3);
            GLDS(Bh + go, &sBh[p][i * 512]);
        }
    };

    auto compute = [&](auto pc) {
        constexpr int p = decltype(pc)::value;
        bf16x8 ahf[MF], alf[MF], bhf[NF];
        #pragma unroll
        for (int m = 0; m < MF; ++m) {
            int rr = wm * WM + m * 16 + lr;
            int by = rr * 64 + ((lg ^ ((rr >> 1) & 3)) << 4);
            ahf[m] = *(const bf16x8*)((const char*)&sAh[p][0] + by);
            if constexpr (PLANES >= 2)
                alf[m] = *(const bf16x8*)((const char*)&sAl[p][0] + by);
        }
        #pragma unroll
        for (int n = 0; n < NF; ++n) {
            int rr = wn * WN + n * 16 + lr;
            int by = rr * 64 + ((lg ^ ((rr >> 1) & 3)) << 4);
            bhf[n] = *(const bf16x8*)((const char*)&sBh[p][0] + by);
        }
        #pragma unroll
        for (int m = 0; m < MF; ++m)
            #pragma unroll
            for (int n = 0; n < NF; ++n) {
                acc[m][n] = mfma16(ahf[m], bhf[n], acc[m][n]);
                if constexpr (PLANES >= 2)
                    acc[m][n] = mfma16(alf[m], bhf[n], acc[m][n]);
            }
    };

    stage(0, IC<0>{});
    __syncthreads();
    int k0 = 32;
    for (; k0 + 32 < K; k0 += 64) {
        stage(k0, IC<1>{});      compute(IC<0>{}); __syncthreads();
        stage(k0 + 32, IC<0>{}); compute(IC<1>{}); __syncthreads();
    }
    stage(k0, IC<1>{}); compute(IC<0>{}); __syncthreads();
    compute(IC<1>{});

    #pragma unroll
    for (int m = 0; m < MF; ++m)
        #pragma unroll
        for (int n = 0; n < NF; ++n)
            #pragma unroll
            for (int r = 0; r < 4; ++r) {
                int grow = row0 + wm * WM + m * 16 + lg * 4 + r;
                int gcol = col0 + wn * WN + n * 16 + lr;
                size_t off = (size_t)blockIdx.z * sC + (size_t)grow * ldc + gcol;
                float v = acc[m][n][r];
                if constexpr (EPIL == EP_STORE) {
                    Cf[off] = v;
                } else if constexpr (EPIL == EP_RESID) {
                    Cf[off] += v;
                } else {  // EP_SPLIT
                    bf16_t hb = (bf16_t)v;
                    Ch[off] = hb;
                    Cl[off] = (bf16_t)(v - (float)hb);
                }
            }
}

// h += sum of 4 split-K partials (one row per block), then RMS-norm the new
// row with weight w -> hi/lo planes. Fuses reduce4 + next rmsnorm_split.
__global__ __launch_bounds__(256)
void reduce4_rms(const float* __restrict__ p, float* __restrict__ h,
                 const float* __restrict__ w,
                 bf16_t* __restrict__ outh, bf16_t* __restrict__ outl)
{
    int row = blockIdx.x, tid = threadIdx.x;
    size_t i = (size_t)row * 256 + tid;
    const size_t S = (1024 * 1024) / 4;
    f32x4 a = ((const f32x4*)p)[i];
    f32x4 b = ((const f32x4*)p)[i + S];
    f32x4 c = ((const f32x4*)p)[i + 2 * S];
    f32x4 d = ((const f32x4*)p)[i + 3 * S];
    f32x4 hv = ((const f32x4*)h)[i];
    #pragma unroll
    for (int j = 0; j < 4; ++j) hv[j] += (a[j] + b[j]) + (c[j] + d[j]);
    ((f32x4*)h)[i] = hv;

    float ss = hv[0]*hv[0] + hv[1]*hv[1] + hv[2]*hv[2] + hv[3]*hv[3];
    #pragma unroll
    for (int m = 1; m < 64; m <<= 1) ss += __shfl_xor(ss, m, 64);
    __shared__ float red[4];
    if ((tid & 63) == 0) red[tid >> 6] = ss;
    __syncthreads();
    float tot = red[0] + red[1] + red[2] + red[3];
    float inv = rsqrtf(tot * (1.0f / 1024.0f) + RMS_EPS);
    f32x4 wv = *(const f32x4*)(w + tid * 4);
    bf16x4 hv4, lv4;
    #pragma unroll
    for (int j = 0; j < 4; ++j) {
        float x = hv[j] * inv * wv[j];
        bf16_t hb = (bf16_t)x;
        hv4[j] = hb;
        lv4[j] = (bf16_t)(x - (float)hb);
    }
    ((bf16x4*)outh)[i] = hv4;
    ((bf16x4*)outl)[i] = lv4;
}

// Flash attention, triangular-balanced: block (px,hh) handles q-chunks
// {px, 31-px} (QBLK=32 rows each), KB=64 keys/tile -> every block does
// 17-18 tile-iters. 2 waves (16 q-rows each). Q,K hi-only; V hi+lo;
// softcap+causal+online softmax fp32; P hi/lo via per-wave LDS; 3-term P.V.
__global__ __launch_bounds__(128, 2)
void flash_attn(const bf16_t* __restrict__ qkvh,
                const bf16_t* __restrict__ vTh, const bf16_t* __restrict__ vTl,
                bf16_t* __restrict__ oh, bf16_t* __restrict__ ol)
{
    __shared__ __align__(16) bf16_t sQ[32*64], sK[64*64], sVh[64*64], sVl[64*64];
    __shared__ __align__(16) bf16_t sPh[32*64], sPl[32*64];

    const int px = blockIdx.x;
    const int hh = blockIdx.y;
    const int tid = threadIdx.x, lane = tid & 63, w = tid >> 6;
    const int lr = lane & 15, lg = lane >> 4;

    for (int cc = 0; cc < 2; ++cc) {
        const int qb = cc ? 31 - px : px;
        const int q0 = qb * 32;

        #pragma unroll
        for (int ii = 0; ii < 2; ++ii) {
            int r0 = w * 16 + ii * 8;
            int r  = r0 + (lane >> 3);
            int i  = lane & 7;
            GLDS(qkvh + (size_t)(q0 + r) * 3072 + hh * 64 + ((i ^ (r & 7)) << 3),
                 sQ + r0 * 64);
        }
        __syncthreads();

        bf16x8 qa[2];
        #pragma unroll
        for (int ks = 0; ks < 2; ++ks) {
            int r = w * 16 + lr;
            qa[ks] = *(const bf16x8*)((const char*)sQ + r * 128 +
                                      ((((ks << 2) | lg) ^ (r & 7)) << 4));
        }

        f32x4 o_acc[4];
        #pragma unroll
        for (int n = 0; n < 4; ++n) o_acc[n] = (f32x4){0.f, 0.f, 0.f, 0.f};
        float m_run[4] = {-1e30f, -1e30f, -1e30f, -1e30f};
        float l_run[4] = {0.f, 0.f, 0.f, 0.f};

        const int ntiles = ((q0 + 31) >> 6) + 1;
        for (int t = 0; t < ntiles; ++t) {
            const int kv0 = t * 64;
            #pragma unroll
            for (int ii = 0; ii < 4; ++ii) {
                int r0 = w * 32 + ii * 8;
                int r  = r0 + (lane >> 3);
                int i  = lane & 7;
                GLDS(qkvh + (size_t)(kv0 + r) * 3072 + 1024 + hh * 64 + ((i ^ (r & 7)) << 3),
                     sK + r0 * 64);
                GLDS(vTh + (size_t)(hh * 64 + r) * 1024 + kv0 + ((i ^ (r & 7)) << 3),
                     sVh + r0 * 64);
                GLDS(vTl + (size_t)(hh * 64 + r) * 1024 + kv0 + ((i ^ (r & 7)) << 3),
                     sVl + r0 * 64);
            }
            __syncthreads();

            f32x4 s_acc[4];
            #pragma unroll
            for (int n = 0; n < 4; ++n) s_acc[n] = (f32x4){0.f, 0.f, 0.f, 0.f};
            #pragma unroll
            for (int ks = 0; ks < 2; ++ks)
                #pragma unroll
                for (int n = 0; n < 4; ++n) {
                    int r = n * 16 + lr;
                    bf16x8 kb = *(const bf16x8*)((const char*)sK + r * 128 +
                                                 ((((ks << 2) | lg) ^ (r & 7)) << 4));
                    s_acc[n] = mfma16(qa[ks], kb, s_acc[n]);
                }

            #pragma unroll
            for (int j = 0; j < 4; ++j) {
                int qr = q0 + w * 16 + lg * 4 + j;
                float p[4];
                float mx = -1e30f;
                #pragma unroll
                for (int n = 0; n < 4; ++n) {
                    float v = s_acc[n][j] * 0.125f;
                    v = 50.f * tanhf(v * 0.02f);
                    int key = kv0 + n * 16 + lr;
                    if (key > qr) v = -1e30f;
                    p[n] = v;
                    mx = fmaxf(mx, v);
                }
                #pragma unroll
                for (int m = 1; m < 16; m <<= 1) mx = fmaxf(mx, __shfl_xor(mx, m, 64));
                float mn = fmaxf(m_run[j], mx);
                float ef = __expf(m_run[j] - mn);
                m_run[j] = mn;
                float rs = 0.f;
                #pragma unroll
                for (int n = 0; n < 4; ++n) {
                    float e = expf(p[n] - mn);
                    p[n] = e;
                    rs += e;
                }
                #pragma unroll
                for (int m = 1; m < 16; m <<= 1) rs += __shfl_xor(rs, m, 64);
                l_run[j] = l_run[j] * ef + rs;
                #pragma unroll
                for (int n = 0; n < 4; ++n) o_acc[n][j] *= ef;
                int r = w * 16 + lg * 4 + j;
                #pragma unroll
                for (int n = 0; n < 4; ++n) {
                    int c = n * 16 + lr;
                    int byo = r * 128 + ((((c >> 3) ^ (r & 7)) << 4)) + ((c & 7) << 1);
                    bf16_t hb = (bf16_t)p[n];
                    *(bf16_t*)((char*)sPh + byo) = hb;
                    *(bf16_t*)((char*)sPl + byo) = (bf16_t)(p[n] - (float)hb);
                }
            }

            #pragma unroll
            for (int ks = 0; ks < 2; ++ks) {
                int pr = w * 16 + lr;
                int pby = pr * 128 + ((((ks << 2) | lg) ^ (pr & 7)) << 4);
                bf16x8 pa  = *(const bf16x8*)((const char*)sPh + pby);
                bf16x8 pl_ = *(const bf16x8*)((const char*)sPl + pby);
                #pragma unroll
                for (int n = 0; n < 4; ++n) {
                    int vr = n * 16 + lr;
                    int vby = vr * 128 + ((((ks << 2) | lg) ^ (vr & 7)) << 4);
                    bf16x8 vhf = *(const bf16x8*)((const char*)sVh + vby);
                    bf16x8 vlf = *(const bf16x8*)((const char*)sVl + vby);
                    o_acc[n] = mfma16(pa,  vhf, o_acc[n]);
                    o_acc[n] = mfma16(pl_, vhf, o_acc[n]);
                    o_acc[n] = mfma16(pa,  vlf, o_acc[n]);
                }
            }
            __syncthreads();
        }

        #pragma unroll
        for (int j = 0; j < 4; ++j) {
            float inv = 1.0f / l_run[j];
            int qr = q0 + w * 16 + lg * 4 + j;
            #pragma unroll
            for (int n = 0; n < 4; ++n) {
                float v = o_acc[n][j] * inv;
                size_t off = (size_t)qr * 1024 + hh * 64 + n * 16 + lr;
                bf16_t hb = (bf16_t)v;
                oh[off] = hb;
                ol[off] = (bf16_t)(v - (float)hb);
            }
        }
    }
}

__global__ __launch_bounds__(256)
void split_kernel(const float* __restrict__ src, bf16_t* __restrict__ hi,
                  bf16_t* __restrict__ lo)
{
    size_t i = (size_t)blockIdx.x * 256 + threadIdx.x;
    f32x4 v = ((const f32x4*)src)[i];
    bf16x4 hv, lv;
    #pragma unroll
    for (int j = 0; j < 4; ++j) {
        bf16_t hb = (bf16_t)v[j];
        hv[j] = hb;
        lv[j] = (bf16_t)(v[j] - (float)hb);
    }
    ((bf16x4*)hi)[i] = hv;
    if (lo) ((bf16x4*)lo)[i] = lv;
}

// hi-only weight pack: wq|wk|wv|wo -> wAh [4096x1024];
// wg|wu -> wGUh [8192x1024]; wd -> wdh [1024x4096]. 16384 blocks.
__global__ __launch_bounds__(256)
void wsplit_kernel(const float* __restrict__ wq, const float* __restrict__ wk,
                   const float* __restrict__ wv, const float* __restrict__ wo,
                   const float* __restrict__ wg, const float* __restrict__ wu,
                   const float* __restrict__ wd,
                   bf16_t* __restrict__ wAh, bf16_t* __restrict__ wGUh,
                   bf16_t* __restrict__ wdh)
{
    int b = blockIdx.x;
    const float* src;
    bf16_t* dst;
    size_t so, doff;
    if (b < 4096) {
        src = b < 1024 ? wq : b < 2048 ? wk : b < 3072 ? wv : wo;
        so = (size_t)(b & 1023) * 256 + threadIdx.x;
        doff = (size_t)b * 256 + threadIdx.x;
        dst = wAh;
    } else if (b < 12288) {
        int bb = b - 4096;
        src = bb < 4096 ? wg : wu;
        so = (size_t)(bb & 4095) * 256 + threadIdx.x;
        doff = (size_t)bb * 256 + threadIdx.x;
        dst = wGUh;
    } else {
        src = wd;
        so = (size_t)(b - 12288) * 256 + threadIdx.x;
        doff = so;
        dst = wdh;
    }
    f32x4 v = ((const f32x4*)src)[so];
    bf16x4 hv;
    #pragma unroll
    for (int j = 0; j < 4; ++j) hv[j] = (bf16_t)v[j];
    ((bf16x4*)dst)[doff] = hv;
}

__global__ __launch_bounds__(256)
void gather_kernel(const int* __restrict__ ids, const float* __restrict__ embed,
                   float* __restrict__ h)
{
    int t = blockIdx.x;
    int row = ids[t];
    const f32x4* src = (const f32x4*)(embed + (size_t)row * 1024);
    f32x4* dst = (f32x4*)(h + (size_t)t * 1024);
    dst[threadIdx.x] = src[threadIdx.x];
}

__global__ __launch_bounds__(256)
void rmsnorm_split(const float* __restrict__ in, const float* __restrict__ w,
                   bf16_t* __restrict__ outh, bf16_t* __restrict__ outl)
{
    int row = blockIdx.x, tid = threadIdx.x;
    f32x4 v = *(const f32x4*)(in + (size_t)row * 1024 + tid * 4);
    float ss = v[0]*v[0] + v[1]*v[1] + v[2]*v[2] + v[3]*v[3];
    #pragma unroll
    for (int m = 1; m < 64; m <<= 1) ss += __shfl_xor(ss, m, 64);
    __shared__ float red[4];
    if ((tid & 63) == 0) red[tid >> 6] = ss;
    __syncthreads();
    float tot = red[0] + red[1] + red[2] + red[3];
    float inv = rsqrtf(tot * (1.0f / 1024.0f) + RMS_EPS);
    f32x4 wv = *(const f32x4*)(w + tid * 4);
    bf16x4 hv, lv;
    #pragma unroll
    for (int j = 0; j < 4; ++j) {
        float x = v[j] * inv * wv[j];
        bf16_t hb = (bf16_t)x;
        hv[j] = hb;
        lv[j] = (bf16_t)(x - (float)hb);
    }
    ((bf16x4*)outh)[(size_t)row * 256 + tid] = hv;
    ((bf16x4*)outl)[(size_t)row * 256 + tid] = lv;
}

// Merged: blocks 0-1023  = per-(t,head) RMS(Dh=64)+RoPE on packed qkv [1024][3072]
//         blocks 1024-3071 = v (cols 2048-3071) -> vT [1024][1024], hi/lo planes.
// Reference quirk: rotation angle = head_index * freq (cos[:n], n = H).
__global__ __launch_bounds__(256)
void rope_transpose(bf16_t* __restrict__ qkvh, bf16_t* __restrict__ qkvl,
                    const float* __restrict__ qn, const float* __restrict__ kn,
                    bf16_t* __restrict__ vTh, bf16_t* __restrict__ vTl)
{
    __shared__ bf16_t tile[32][33];
    int b = blockIdx.x;
    if (b >= 1024) {
        int t2 = b - 1024;
        int z = t2 >> 10, rem = t2 & 1023;
        const bf16_t* in = z ? qkvl : qkvh;
        bf16_t* out      = z ? vTl : vTh;
        int bx = (rem & 31) * 32, by = (rem >> 5) * 32;
        int r = threadIdx.x >> 5, c = threadIdx.x & 31;
        #pragma unroll
        for (int rr = r; rr < 32; rr += 8)
            tile[rr][c] = in[(size_t)(by + rr) * 3072 + 2048 + bx + c];
        __syncthreads();
        #pragma unroll
        for (int rr = r; rr < 32; rr += 8)
            out[(size_t)(bx + rr) * 1024 + by + c] = tile[c][rr];
        return;
    }

    int t = b, tid = threadIdx.x;
    int hh = tid >> 4;
    int i  = (tid & 15) * 4;
    size_t qb = ((size_t)t * 3072 + hh * 64 + i) >> 2;
    size_t kb = qb + (1024 >> 2);

    int p0 = i >> 1;
    float f0 = powf(10000.f, -(float)p0 / 32.f);
    float f1 = powf(10000.f, -(float)(p0 + 1) / 32.f);
    float a0 = (float)hh * f0, a1 = (float)hh * f1;
    float c0 = cosf(a0), s0 = sinf(a0);
    float c1 = cosf(a1), s1 = sinf(a1);

    f32x4 qw = *(const f32x4*)(qn + i);
    f32x4 kw = *(const f32x4*)(kn + i);

    {
        bf16x4 h4 = ((const bf16x4*)qkvh)[qb], l4 = ((const bf16x4*)qkvl)[qb];
        float x[4];
        #pragma unroll
        for (int j = 0; j < 4; ++j) x[j] = (float)h4[j] + (float)l4[j];
        float ss = x[0]*x[0] + x[1]*x[1] + x[2]*x[2] + x[3]*x[3];
        #pragma unroll
        for (int m = 1; m < 16; m <<= 1) ss += __shfl_xor(ss, m, 64);
        float inv = rsqrtf(ss * (1.0f / 64.0f) + RMS_EPS);
        float x0 = x[0]*inv*qw[0], x1 = x[1]*inv*qw[1];
        float x2 = x[2]*inv*qw[2], x3 = x[3]*inv*qw[3];
        bf16x4 o4;
        o4[0] = (bf16_t)(x0*c0 - x1*s0);  o4[1] = (bf16_t)(x0*s0 + x1*c0);
        o4[2] = (bf16_t)(x2*c1 - x3*s1);  o4[3] = (bf16_t)(x2*s1 + x3*c1);
        ((bf16x4*)qkvh)[qb] = o4;
    }
    {
        bf16x4 h4 = ((const bf16x4*)qkvh)[kb], l4 = ((const bf16x4*)qkvl)[kb];
        float x[4];
        #pragma unroll
        for (int j = 0; j < 4; ++j) x[j] = (float)h4[j] + (float)l4[j];
        float ss = x[0]*x[0] + x[1]*x[1] + x[2]*x[2] + x[3]*x[3];
        #pragma unroll
        for (int m = 1; m < 16; m <<= 1) ss += __shfl_xor(ss, m, 64);
        float inv = rsqrtf(ss * (1.0f / 64.0f) + RMS_EPS);
        float x0 = x[0]*inv*kw[0], x1 = x[1]*inv*kw[1];
        float x2 = x[2]*inv*kw[2], x3 = x[3]*inv*kw[3];
        bf16x4 o4;
        o4[0] = (bf16_t)(x0*c0 - x1*s0);  o4[1] = (bf16_t)(x0*s0 + x1*c0);
        o4[2] = (bf16_t)(x2*c1 - x3*s1);  o4[3] = (bf16_t)(x2*s1 + x3*c1);
        ((bf16x4*)qkvh)[kb] = o4;
    }
}

// silu(g)*u over gu planes [1024][8192] -> sil planes [1024][4096] (hi+lo)
__global__ __launch_bounds__(256)
void silu_mul(const bf16_t* __restrict__ guh, const bf16_t* __restrict__ gul,
              bf16_t* __restrict__ sh, bf16_t* __restrict__ sl)
{
    size_t idx = (size_t)blockIdx.x * 1024 + threadIdx.x * 4;
    size_t rrow = idx >> 12, col = idx & 4095;
    size_t gb = (rrow * 8192 + col) >> 2;
    size_t ub = gb + (4096 >> 2);
    bf16x4 gh4 = ((const bf16x4*)guh)[gb], gl4 = ((const bf16x4*)gul)[gb];
    bf16x4 uh4 = ((const bf16x4*)guh)[ub], ul4 = ((const bf16x4*)gul)[ub];
    bf16x4 hv, lv;
    #pragma unroll
    for (int j = 0; j < 4; ++j) {
        float g = (float)gh4[j] + (float)gl4[j];
        float u = (float)uh4[j] + (float)ul4[j];
        float o = (g / (1.0f + expf(-g))) * u;
        bf16_t hb = (bf16_t)o;
        hv[j] = hb;
        lv[j] = (bf16_t)(o - (float)hb);
    }
    ((bf16x4*)sh)[idx >> 2] = hv;
    ((bf16x4*)sl)[idx >> 2] = lv;
}

extern "C" void kernel_launch(void* const* d_in, const int* in_sizes, int n_in,
                              void* d_out, int out_size, void* d_ws, size_t ws_size,
                              hipStream_t stream)
{
    (void)in_sizes; (void)n_in; (void)out_size; (void)ws_size;
    const int*   x_ids = (const int*)  d_in[0];
    const float* embed = (const float*)d_in[1];
    const float* ln1   = (const float*)d_in[2];
    const float* Wq    = (const float*)d_in[3];
    const float* Wk    = (const float*)d_in[4];
    const float* Wv    = (const float*)d_in[5];
    const float* Wo    = (const float*)d_in[6];
    const float* qn    = (const float*)d_in[7];
    const float* kn    = (const float*)d_in[8];
    const float* ln2   = (const float*)d_in[9];
    const float* Wg    = (const float*)d_in[10];
    const float* Wu    = (const float*)d_in[11];
    const float* Wd    = (const float*)d_in[12];
    const float* lnout = (const float*)d_in[13];
    float* out = (float*)d_out;

    char* ws = (char*)d_ws;
    const size_t MB = 1 << 20;
    float*  h    = (float*) (ws +   0 * MB);  // 4 MB fp32 residual
    bf16_t* hnh  = (bf16_t*)(ws +   4 * MB);
    bf16_t* hnl  = (bf16_t*)(ws +   6 * MB);
    bf16_t* qkvh = (bf16_t*)(ws +   8 * MB);  // 6 MB [1024][3072]
    bf16_t* qkvl = (bf16_t*)(ws +  14 * MB);
    bf16_t* vTh  = (bf16_t*)(ws +  20 * MB);
    bf16_t* vTl  = (bf16_t*)(ws +  22 * MB);
    bf16_t* oh   = (bf16_t*)(ws +  24 * MB);
    bf16_t* ol   = (bf16_t*)(ws +  26 * MB);
    bf16_t* wAh  = (bf16_t*)(ws +  28 * MB);  //  8 MB [4096][1024] hi-only
    bf16_t* wGUh = (bf16_t*)(ws +  36 * MB);  // 16 MB [8192][1024] hi-only
    bf16_t* wdh  = (bf16_t*)(ws +  52 * MB);  //  8 MB [1024][4096] hi-only
    bf16_t* guh  = (bf16_t*)(ws +  60 * MB);  // 16 MB [1024][8192]
    bf16_t* gul  = (bf16_t*)(ws +  76 * MB);
    bf16_t* silh = (bf16_t*)(ws +  92 * MB);  //  8 MB [1024][4096]
    bf16_t* sill = (bf16_t*)(ws + 100 * MB);
    float*  wdp  = (float*) (ws + 108 * MB);  // 16 MB split-K partials [4][1024][1024]
    bf16_t* eh   = (bf16_t*)(ws + 124 * MB);  // 62.5 MB embed hi (high-water ~187 MB)

    const long long M1 = 1024 * 1024;

    gather_kernel<<<1024, 256, 0, stream>>>(x_ids, embed, h);
    rmsnorm_split<<<1024, 256, 0, stream>>>(h, ln1, hnh, hnl);  // layer 0 pre-norm

    for (int l = 0; l < 6; ++l) {
        const float* wq = Wq + (size_t)l * M1;
        const float* wk = Wk + (size_t)l * M1;
        const float* wv = Wv + (size_t)l * M1;
        const float* wo = Wo + (size_t)l * M1;
        const float* wg = Wg + (size_t)l * 4 * M1;
        const float* wu = Wu + (size_t)l * 4 * M1;
        const float* wd = Wd + (size_t)l * 4 * M1;

        wsplit_kernel<<<16384, 256, 0, stream>>>(wq, wk, wv, wo, wg, wu, wd,
                                                 wAh, wGUh, wdh);

        // fused QKV: [1024][3072] = hn @ wA[0:3072]^T  (2-plane, 128^2)
        gemm_bf16<128,128,2,EP_SPLIT><<<dim3(8,24),256,0,stream>>>(
            hnh, hnl, wAh, nullptr, qkvh, qkvl, 1024, 1024, 1024, 3072, 0);

        rope_transpose<<<3072, 256, 0, stream>>>(qkvh, qkvl, qn + l * 64, kn + l * 64,
                                                 vTh, vTl);

        // fused scores+softcap+mask+softmax+PV (triangular-balanced)
        flash_attn<<<dim3(16,16), 128, 0, stream>>>(qkvh, vTh, vTl, oh, ol);

        // Wo residual (2-plane, 64^2 tiles)
        gemm_bf16<64,64,2,EP_RESID><<<dim3(16,16),256,0,stream>>>(
            oh, ol, wAh + 3 * M1, h, nullptr, nullptr, 1024, 1024, 1024, 1024, 0);

        rmsnorm_split<<<1024, 256, 0, stream>>>(h, ln2 + l * 1024, hnh, hnl);

        // fused gate+up: [1024][8192]  (2-plane)
        gemm_bf16<128,128,2,EP_SPLIT><<<dim3(8,64),256,0,stream>>>(
            hnh, hnl, wGUh, nullptr, guh, gul, 1024, 1024, 1024, 8192, 0);

        silu_mul<<<4096, 256, 0, stream>>>(guh, gul, silh, sill);

        // down-proj: split-K x4 (2-plane) -> partials
        gemm_bf16<128,128,2,EP_STORE><<<dim3(8,8,4),256,0,stream>>>(
            silh, sill, wdh, wdp, nullptr, nullptr, 1024, 4096, 4096, 1024, M1);

        // reduce partials into h + next pre-norm (ln1[l+1], or ln_out after last)
        const float* wnext = (l < 5) ? (ln1 + (l + 1) * 1024) : lnout;
        reduce4_rms<<<1024, 256, 0, stream>>>(wdp, h, wnext, hnh, hnl);
    }

    split_kernel<<<32000, 256, 0, stream>>>(embed, eh, nullptr);
    // logits (1-plane): [1024][32000]
    gemm_bf16<128,128,1,EP_STORE><<<dim3(8,250),256,0,stream>>>(
        hnh, nullptr, eh, out, nullptr, nullptr, 1024, 1024, 1024, 32000, 0);
}

// Round 7
// 1480.407 us; speedup vs baseline: 5.2728x; 1.0294x over previous
//
#include <hip/hip_runtime.h>
#include <math.h>
#include <type_traits>

typedef __bf16 bf16_t;
typedef bf16_t bf16x4 __attribute__((ext_vector_type(4)));
typedef bf16_t bf16x8 __attribute__((ext_vector_type(8)));
typedef float  f32x4  __attribute__((ext_vector_type(4)));

#define RMS_EPS 1e-6f

enum { EP_STORE = 0, EP_RESID = 1, EP_SPLIT = 2, EP_SILU = 3 };

template<int V> using IC = std::integral_constant<int, V>;

static __device__ __forceinline__ f32x4 mfma16(bf16x8 a, bf16x8 b, f32x4 c) {
    return __builtin_amdgcn_mfma_f32_16x16x32_bf16(a, b, c, 0, 0, 0);
}

#define GLDS(gp, lp) __builtin_amdgcn_global_load_lds( \
    (const __attribute__((address_space(1))) void*)(gp), \
    (__attribute__((address_space(3))) void*)(lp), 16, 0, 0)

// C[M,N] = A[M,K]*B[N,K]^T.
// PLANES==2: A split hi/lo, B hi-only (2 MFMAs).  PLANES==1: hi-only.
// DBUF==1: double-buffered LDS, single-barrier prefetch loop (T3-minimum).
// DBUF==0: single buffer, 2 barriers/K-step, (256,4) occupancy — measured
//          faster for the 1-plane logits GEMM (occupancy > overlap there).
// EP_SILU: B is wGU interleaved (row 2i=wg_i, row 2i+1=wu_i); adjacent lanes
//          hold (g,u); even lanes write silu(g)*u as hi/lo bf16 planes at
//          col>>1, row stride ldc.
// blockIdx.z = K-chunk for split-K (A/B advance z*K cols; C advances z*sC).
template<int BM, int BN, int PLANES, int EPIL, int DBUF>
__global__ __launch_bounds__(256, DBUF ? 3 : 4)
void gemm_bf16(const bf16_t* __restrict__ Ah, const bf16_t* __restrict__ Al,
               const bf16_t* __restrict__ Bh,
               float* __restrict__ Cf, bf16_t* __restrict__ Ch, bf16_t* __restrict__ Cl,
               int K, int lda, int ldb, int ldc, long long sC)
{
    constexpr int ASZ = BM * 32, BSZ = BN * 32;
    constexpr int NB = DBUF ? 2 : 1;
    __shared__ __align__(16) bf16_t sAh[NB][ASZ], sBh[NB][BSZ];
    __shared__ __align__(16) bf16_t sAl[PLANES >= 2 ? NB : 1][PLANES >= 2 ? ASZ : 8];

    const int gx = gridDim.x;
    int id = blockIdx.x + gx * blockIdx.y;
    if (gridDim.z == 1) {  // bijective XCD swizzle (m204)
        int nwg = gx * gridDim.y;
        int q = nwg >> 3, r = nwg & 7;
        int xcd = id & 7, ix = id >> 3;
        id = (xcd < r ? xcd * (q + 1) : r * (q + 1) + (xcd - r) * q) + ix;
    }
    const int bm = id % gx, bn = id / gx;
    const int row0 = bm * BM, col0 = bn * BN;

    const size_t kofs = (size_t)blockIdx.z * K;
    Ah += kofs;  Bh += kofs;
    if constexpr (PLANES >= 2) Al += kofs;

    const int tid = threadIdx.x, lane = tid & 63, wave = tid >> 6;
    const int lr = lane & 15, lg = lane >> 4;
    constexpr int WM = BM / 2, WN = BN / 2, MF = WM / 16, NF = WN / 16;
    const int wm = wave >> 1, wn = wave & 1;

    f32x4 acc[MF][NF];
    #pragma unroll
    for (int m = 0; m < MF; ++m)
        #pragma unroll
        for (int n = 0; n < NF; ++n) acc[m][n] = (f32x4){0.f, 0.f, 0.f, 0.f};

    auto stage = [&](int k0, auto pc) {
        constexpr int p = decltype(pc)::value;
        #pragma unroll
        for (int i = wave; i < BM / 16; i += 4) {
            int s = i * 64 + lane, rr = s >> 2, c = s & 3;
            size_t go = (size_t)(row0 + rr) * lda + k0 + ((c ^ ((rr >> 1) & 3)) << 3);
            GLDS(Ah + go, &sAh[p][i * 512]);
            if constexpr (PLANES >= 2) GLDS(Al + go, &sAl[p][i * 512]);
        }
        #pragma unroll
        for (int i = wave; i < BN / 16; i += 4) {
            int s = i * 64 + lane, rr = s >> 2, c = s & 3;
            size_t go = (size_t)(col0 + rr) * ldb + k0 + ((c ^ ((rr >> 1) & 3)) << 3);
            GLDS(Bh + go, &sBh[p][i * 512]);
        }
    };

    auto compute = [&](auto pc) {
        constexpr int p = decltype(pc)::value;
        bf16x8 ahf[MF], alf[MF], bhf[NF];
        #pragma unroll
        for (int m = 0; m < MF; ++m) {
            int rr = wm * WM + m * 16 + lr;
            int by = rr * 64 + ((lg ^ ((rr >> 1) & 3)) << 4);
            ahf[m] = *(const bf16x8*)((const char*)&sAh[p][0] + by);
            if constexpr (PLANES >= 2)
                alf[m] = *(const bf16x8*)((const char*)&sAl[p][0] + by);
        }
        #pragma unroll
        for (int n = 0; n < NF; ++n) {
            int rr = wn * WN + n * 16 + lr;
            int by = rr * 64 + ((lg ^ ((rr >> 1) & 3)) << 4);
            bhf[n] = *(const bf16x8*)((const char*)&sBh[p][0] + by);
        }
        #pragma unroll
        for (int m = 0; m < MF; ++m)
            #pragma unroll
            for (int n = 0; n < NF; ++n) {
                acc[m][n] = mfma16(ahf[m], bhf[n], acc[m][n]);
                if constexpr (PLANES >= 2)
                    acc[m][n] = mfma16(alf[m], bhf[n], acc[m][n]);
            }
    };

    if constexpr (DBUF) {
        stage(0, IC<0>{});
        __syncthreads();
        int k0 = 32;
        for (; k0 + 32 < K; k0 += 64) {
            stage(k0, IC<1>{});      compute(IC<0>{}); __syncthreads();
            stage(k0 + 32, IC<0>{}); compute(IC<1>{}); __syncthreads();
        }
        stage(k0, IC<1>{}); compute(IC<0>{}); __syncthreads();
        compute(IC<1>{});
    } else {
        for (int k0 = 0; k0 < K; k0 += 32) {
            __syncthreads();
            stage(k0, IC<0>{});
            __syncthreads();
            compute(IC<0>{});
        }
    }

    #pragma unroll
    for (int m = 0; m < MF; ++m)
        #pragma unroll
        for (int n = 0; n < NF; ++n)
            #pragma unroll
            for (int r = 0; r < 4; ++r) {
                int grow = row0 + wm * WM + m * 16 + lg * 4 + r;
                int gcol = col0 + wn * WN + n * 16 + lr;
                float v = acc[m][n][r];
                if constexpr (EPIL == EP_SILU) {
                    float pv = __shfl_xor(v, 1, 64);   // partner column (g,u pair)
                    if (!(lr & 1)) {
                        float s = (v / (1.0f + expf(-v))) * pv;
                        size_t off = (size_t)grow * ldc + (gcol >> 1);
                        bf16_t hb = (bf16_t)s;
                        Ch[off] = hb;
                        Cl[off] = (bf16_t)(s - (float)hb);
                    }
                } else {
                    size_t off = (size_t)blockIdx.z * sC + (size_t)grow * ldc + gcol;
                    if constexpr (EPIL == EP_STORE) {
                        Cf[off] = v;
                    } else if constexpr (EPIL == EP_RESID) {
                        Cf[off] += v;
                    } else {  // EP_SPLIT
                        bf16_t hb = (bf16_t)v;
                        Ch[off] = hb;
                        Cl[off] = (bf16_t)(v - (float)hb);
                    }
                }
            }
}

// h += sum of 4 split-K partials (one row per block), then RMS-norm the new
// row with weight w -> hi/lo planes. Fuses reduce4 + next rmsnorm_split.
__global__ __launch_bounds__(256)
void reduce4_rms(const float* __restrict__ p, float* __restrict__ h,
                 const float* __restrict__ w,
                 bf16_t* __restrict__ outh, bf16_t* __restrict__ outl)
{
    int row = blockIdx.x, tid = threadIdx.x;
    size_t i = (size_t)row * 256 + tid;
    const size_t S = (1024 * 1024) / 4;
    f32x4 a = ((const f32x4*)p)[i];
    f32x4 b = ((const f32x4*)p)[i + S];
    f32x4 c = ((const f32x4*)p)[i + 2 * S];
    f32x4 d = ((const f32x4*)p)[i + 3 * S];
    f32x4 hv = ((const f32x4*)h)[i];
    #pragma unroll
    for (int j = 0; j < 4; ++j) hv[j] += (a[j] + b[j]) + (c[j] + d[j]);
    ((f32x4*)h)[i] = hv;

    float ss = hv[0]*hv[0] + hv[1]*hv[1] + hv[2]*hv[2] + hv[3]*hv[3];
    #pragma unroll
    for (int m = 1; m < 64; m <<= 1) ss += __shfl_xor(ss, m, 64);
    __shared__ float red[4];
    if ((tid & 63) == 0) red[tid >> 6] = ss;
    __syncthreads();
    float tot = red[0] + red[1] + red[2] + red[3];
    float inv = rsqrtf(tot * (1.0f / 1024.0f) + RMS_EPS);
    f32x4 wv = *(const f32x4*)(w + tid * 4);
    bf16x4 hv4, lv4;
    #pragma unroll
    for (int j = 0; j < 4; ++j) {
        float x = hv[j] * inv * wv[j];
        bf16_t hb = (bf16_t)x;
        hv4[j] = hb;
        lv4[j] = (bf16_t)(x - (float)hb);
    }
    ((bf16x4*)outh)[i] = hv4;
    ((bf16x4*)outl)[i] = lv4;
}

// Flash attention, triangular-balanced: block (px,hh) handles q-chunks
// {px, 31-px} (QBLK=32 rows each), KB=64 keys/tile. 2 waves (16 q-rows each).
// Q,K hi-only; V hi+lo; softcap+causal+online softmax fp32; P hi/lo via
// per-wave LDS; 3-term P.V.
__global__ __launch_bounds__(128, 2)
void flash_attn(const bf16_t* __restrict__ qkvh,
                const bf16_t* __restrict__ vTh, const bf16_t* __restrict__ vTl,
                bf16_t* __restrict__ oh, bf16_t* __restrict__ ol)
{
    __shared__ __align__(16) bf16_t sQ[32*64], sK[64*64], sVh[64*64], sVl[64*64];
    __shared__ __align__(16) bf16_t sPh[32*64], sPl[32*64];

    const int px = blockIdx.x;
    const int hh = blockIdx.y;
    const int tid = threadIdx.x, lane = tid & 63, w = tid >> 6;
    const int lr = lane & 15, lg = lane >> 4;

    for (int cc = 0; cc < 2; ++cc) {
        const int qb = cc ? 31 - px : px;
        const int q0 = qb * 32;

        #pragma unroll
        for (int ii = 0; ii < 2; ++ii) {
            int r0 = w * 16 + ii * 8;
            int r  = r0 + (lane >> 3);
            int i  = lane & 7;
            GLDS(qkvh + (size_t)(q0 + r) * 3072 + hh * 64 + ((i ^ (r & 7)) << 3),
                 sQ + r0 * 64);
        }
        __syncthreads();

        bf16x8 qa[2];
        #pragma unroll
        for (int ks = 0; ks < 2; ++ks) {
            int r = w * 16 + lr;
            qa[ks] = *(const bf16x8*)((const char*)sQ + r * 128 +
                                      ((((ks << 2) | lg) ^ (r & 7)) << 4));
        }

        f32x4 o_acc[4];
        #pragma unroll
        for (int n = 0; n < 4; ++n) o_acc[n] = (f32x4){0.f, 0.f, 0.f, 0.f};
        float m_run[4] = {-1e30f, -1e30f, -1e30f, -1e30f};
        float l_run[4] = {0.f, 0.f, 0.f, 0.f};

        const int ntiles = ((q0 + 31) >> 6) + 1;
        for (int t = 0; t < ntiles; ++t) {
            const int kv0 = t * 64;
            #pragma unroll
            for (int ii = 0; ii < 4; ++ii) {
                int r0 = w * 32 + ii * 8;
                int r  = r0 + (lane >> 3);
                int i  = lane & 7;
                GLDS(qkvh + (size_t)(kv0 + r) * 3072 + 1024 + hh * 64 + ((i ^ (r & 7)) << 3),
                     sK + r0 * 64);
                GLDS(vTh + (size_t)(hh * 64 + r) * 1024 + kv0 + ((i ^ (r & 7)) << 3),
                     sVh + r0 * 64);
                GLDS(vTl + (size_t)(hh * 64 + r) * 1024 + kv0 + ((i ^ (r & 7)) << 3),
                     sVl + r0 * 64);
            }
            __syncthreads();

            f32x4 s_acc[4];
            #pragma unroll
            for (int n = 0; n < 4; ++n) s_acc[n] = (f32x4){0.f, 0.f, 0.f, 0.f};
            #pragma unroll
            for (int ks = 0; ks < 2; ++ks)
                #pragma unroll
                for (int n = 0; n < 4; ++n) {
                    int r = n * 16 + lr;
                    bf16x8 kb = *(const bf16x8*)((const char*)sK + r * 128 +
                                                 ((((ks << 2) | lg) ^ (r & 7)) << 4));
                    s_acc[n] = mfma16(qa[ks], kb, s_acc[n]);
                }

            #pragma unroll
            for (int j = 0; j < 4; ++j) {
                int qr = q0 + w * 16 + lg * 4 + j;
                float p[4];
                float mx = -1e30f;
                #pragma unroll
                for (int n = 0; n < 4; ++n) {
                    float v = s_acc[n][j] * 0.125f;
                    v = 50.f * tanhf(v * 0.02f);
                    int key = kv0 + n * 16 + lr;
                    if (key > qr) v = -1e30f;
                    p[n] = v;
                    mx = fmaxf(mx, v);
                }
                #pragma unroll
                for (int m = 1; m < 16; m <<= 1) mx = fmaxf(mx, __shfl_xor(mx, m, 64));
                float mn = fmaxf(m_run[j], mx);
                float ef = __expf(m_run[j] - mn);
                m_run[j] = mn;
                float rs = 0.f;
                #pragma unroll
                for (int n = 0; n < 4; ++n) {
                    float e = expf(p[n] - mn);
                    p[n] = e;
                    rs += e;
                }
                #pragma unroll
                for (int m = 1; m < 16; m <<= 1) rs += __shfl_xor(rs, m, 64);
                l_run[j] = l_run[j] * ef + rs;
                #pragma unroll
                for (int n = 0; n < 4; ++n) o_acc[n][j] *= ef;
                int r = w * 16 + lg * 4 + j;
                #pragma unroll
                for (int n = 0; n < 4; ++n) {
                    int c = n * 16 + lr;
                    int byo = r * 128 + ((((c >> 3) ^ (r & 7)) << 4)) + ((c & 7) << 1);
                    bf16_t hb = (bf16_t)p[n];
                    *(bf16_t*)((char*)sPh + byo) = hb;
                    *(bf16_t*)((char*)sPl + byo) = (bf16_t)(p[n] - (float)hb);
                }
            }

            #pragma unroll
            for (int ks = 0; ks < 2; ++ks) {
                int pr = w * 16 + lr;
                int pby = pr * 128 + ((((ks << 2) | lg) ^ (pr & 7)) << 4);
                bf16x8 pa  = *(const bf16x8*)((const char*)sPh + pby);
                bf16x8 pl_ = *(const bf16x8*)((const char*)sPl + pby);
                #pragma unroll
                for (int n = 0; n < 4; ++n) {
                    int vr = n * 16 + lr;
                    int vby = vr * 128 + ((((ks << 2) | lg) ^ (vr & 7)) << 4);
                    bf16x8 vhf = *(const bf16x8*)((const char*)sVh + vby);
                    bf16x8 vlf = *(const bf16x8*)((const char*)sVl + vby);
                    o_acc[n] = mfma16(pa,  vhf, o_acc[n]);
                    o_acc[n] = mfma16(pl_, vhf, o_acc[n]);
                    o_acc[n] = mfma16(pa,  vlf, o_acc[n]);
                }
            }
            __syncthreads();
        }

        #pragma unroll
        for (int j = 0; j < 4; ++j) {
            float inv = 1.0f / l_run[j];
            int qr = q0 + w * 16 + lg * 4 + j;
            #pragma unroll
            for (int n = 0; n < 4; ++n) {
                float v = o_acc[n][j] * inv;
                size_t off = (size_t)qr * 1024 + hh * 64 + n * 16 + lr;
                bf16_t hb = (bf16_t)v;
                oh[off] = hb;
                ol[off] = (bf16_t)(v - (float)hb);
            }
        }
    }
}

__global__ __launch_bounds__(256)
void split_kernel(const float* __restrict__ src, bf16_t* __restrict__ hi,
                  bf16_t* __restrict__ lo)
{
    size_t i = (size_t)blockIdx.x * 256 + threadIdx.x;
    f32x4 v = ((const f32x4*)src)[i];
    bf16x4 hv, lv;
    #pragma unroll
    for (int j = 0; j < 4; ++j) {
        bf16_t hb = (bf16_t)v[j];
        hv[j] = hb;
        lv[j] = (bf16_t)(v[j] - (float)hb);
    }
    ((bf16x4*)hi)[i] = hv;
    if (lo) ((bf16x4*)lo)[i] = lv;
}

// hi-only weight pack, grid-strided (4 chunks/block, 4096 blocks):
// wq|wk|wv|wo -> wAh [4096x1024]; wg|wu -> wGUh INTERLEAVED [8192x1024]
// (row 2i = wg_i, row 2i+1 = wu_i, for the fused-silu GEMM); wd -> wdh.
__global__ __launch_bounds__(256)
void wsplit_kernel(const float* __restrict__ wq, const float* __restrict__ wk,
                   const float* __restrict__ wv, const float* __restrict__ wo,
                   const float* __restrict__ wg, const float* __restrict__ wu,
                   const float* __restrict__ wd,
                   bf16_t* __restrict__ wAh, bf16_t* __restrict__ wGUh,
                   bf16_t* __restrict__ wdh)
{
    #pragma unroll
    for (int k = 0; k < 4; ++k) {
        int b = blockIdx.x * 4 + k;
        const float* src;
        bf16_t* dst;
        size_t so, doff;
        if (b < 4096) {
            src = b < 1024 ? wq : b < 2048 ? wk : b < 3072 ? wv : wo;
            so = (size_t)(b & 1023) * 256 + threadIdx.x;
            doff = (size_t)b * 256 + threadIdx.x;
            dst = wAh;
        } else if (b < 12288) {
            int bb = b - 4096;
            int row = bb < 4096 ? 2 * bb : 2 * (bb - 4096) + 1;
            src = bb < 4096 ? wg : wu;
            so = (size_t)(bb & 4095) * 256 + threadIdx.x;
            doff = (size_t)row * 256 + threadIdx.x;
            dst = wGUh;
        } else {
            src = wd;
            so = (size_t)(b - 12288) * 256 + threadIdx.x;
            doff = so;
            dst = wdh;
        }
        f32x4 v = ((const f32x4*)src)[so];
        bf16x4 hv;
        #pragma unroll
        for (int j = 0; j < 4; ++j) hv[j] = (bf16_t)v[j];
        ((bf16x4*)dst)[doff] = hv;
    }
}

__global__ __launch_bounds__(256)
void gather_kernel(const int* __restrict__ ids, const float* __restrict__ embed,
                   float* __restrict__ h)
{
    int t = blockIdx.x;
    int row = ids[t];
    const f32x4* src = (const f32x4*)(embed + (size_t)row * 1024);
    f32x4* dst = (f32x4*)(h + (size_t)t * 1024);
    dst[threadIdx.x] = src[threadIdx.x];
}

__global__ __launch_bounds__(256)
void rmsnorm_split(const float* __restrict__ in, const float* __restrict__ w,
                   bf16_t* __restrict__ outh, bf16_t* __restrict__ outl)
{
    int row = blockIdx.x, tid = threadIdx.x;
    f32x4 v = *(const f32x4*)(in + (size_t)row * 1024 + tid * 4);
    float ss = v[0]*v[0] + v[1]*v[1] + v[2]*v[2] + v[3]*v[3];
    #pragma unroll
    for (int m = 1; m < 64; m <<= 1) ss += __shfl_xor(ss, m, 64);
    __shared__ float red[4];
    if ((tid & 63) == 0) red[tid >> 6] = ss;
    __syncthreads();
    float tot = red[0] + red[1] + red[2] + red[3];
    float inv = rsqrtf(tot * (1.0f / 1024.0f) + RMS_EPS);
    f32x4 wv = *(const f32x4*)(w + tid * 4);
    bf16x4 hv, lv;
    #pragma unroll
    for (int j = 0; j < 4; ++j) {
        float x = v[j] * inv * wv[j];
        bf16_t hb = (bf16_t)x;
        hv[j] = hb;
        lv[j] = (bf16_t)(x - (float)hb);
    }
    ((bf16x4*)outh)[(size_t)row * 256 + tid] = hv;
    ((bf16x4*)outl)[(size_t)row * 256 + tid] = lv;
}

// Merged: blocks 0-1023  = per-(t,head) RMS(Dh=64)+RoPE on packed qkv [1024][3072]
//         blocks 1024-3071 = v (cols 2048-3071) -> vT [1024][1024], hi/lo planes.
// Reference quirk: rotation angle = head_index * freq (cos[:n], n = H).
__global__ __launch_bounds__(256)
void rope_transpose(bf16_t* __restrict__ qkvh, bf16_t* __restrict__ qkvl,
                    const float* __restrict__ qn, const float* __restrict__ kn,
                    bf16_t* __restrict__ vTh, bf16_t* __restrict__ vTl)
{
    __shared__ bf16_t tile[32][33];
    int b = blockIdx.x;
    if (b >= 1024) {
        int t2 = b - 1024;
        int z = t2 >> 10, rem = t2 & 1023;
        const bf16_t* in = z ? qkvl : qkvh;
        bf16_t* out      = z ? vTl : vTh;
        int bx = (rem & 31) * 32, by = (rem >> 5) * 32;
        int r = threadIdx.x >> 5, c = threadIdx.x & 31;
        #pragma unroll
        for (int rr = r; rr < 32; rr += 8)
            tile[rr][c] = in[(size_t)(by + rr) * 3072 + 2048 + bx + c];
        __syncthreads();
        #pragma unroll
        for (int rr = r; rr < 32; rr += 8)
            out[(size_t)(bx + rr) * 1024 + by + c] = tile[c][rr];
        return;
    }

    int t = b, tid = threadIdx.x;
    int hh = tid >> 4;
    int i  = (tid & 15) * 4;
    size_t qb = ((size_t)t * 3072 + hh * 64 + i) >> 2;
    size_t kb = qb + (1024 >> 2);

    int p0 = i >> 1;
    float f0 = powf(10000.f, -(float)p0 / 32.f);
    float f1 = powf(10000.f, -(float)(p0 + 1) / 32.f);
    float a0 = (float)hh * f0, a1 = (float)hh * f1;
    float c0 = cosf(a0), s0 = sinf(a0);
    float c1 = cosf(a1), s1 = sinf(a1);

    f32x4 qw = *(const f32x4*)(qn + i);
    f32x4 kw = *(const f32x4*)(kn + i);

    {
        bf16x4 h4 = ((const bf16x4*)qkvh)[qb], l4 = ((const bf16x4*)qkvl)[qb];
        float x[4];
        #pragma unroll
        for (int j = 0; j < 4; ++j) x[j] = (float)h4[j] + (float)l4[j];
        float ss = x[0]*x[0] + x[1]*x[1] + x[2]*x[2] + x[3]*x[3];
        #pragma unroll
        for (int m = 1; m < 16; m <<= 1) ss += __shfl_xor(ss, m, 64);
        float inv = rsqrtf(ss * (1.0f / 64.0f) + RMS_EPS);
        float x0 = x[0]*inv*qw[0], x1 = x[1]*inv*qw[1];
        float x2 = x[2]*inv*qw[2], x3 = x[3]*inv*qw[3];
        bf16x4 o4;
        o4[0] = (bf16_t)(x0*c0 - x1*s0);  o4[1] = (bf16_t)(x0*s0 + x1*c0);
        o4[2] = (bf16_t)(x2*c1 - x3*s1);  o4[3] = (bf16_t)(x2*s1 + x3*c1);
        ((bf16x4*)qkvh)[qb] = o4;
    }
    {
        bf16x4 h4 = ((const bf16x4*)qkvh)[kb], l4 = ((const bf16x4*)qkvl)[kb];
        float x[4];
        #pragma unroll
        for (int j = 0; j < 4; ++j) x[j] = (float)h4[j] + (float)l4[j];
        float ss = x[0]*x[0] + x[1]*x[1] + x[2]*x[2] + x[3]*x[3];
        #pragma unroll
        for (int m = 1; m < 16; m <<= 1) ss += __shfl_xor(ss, m, 64);
        float inv = rsqrtf(ss * (1.0f / 64.0f) + RMS_EPS);
        float x0 = x[0]*inv*kw[0], x1 = x[1]*inv*kw[1];
        float x2 = x[2]*inv*kw[2], x3 = x[3]*inv*kw[3];
        bf16x4 o4;
        o4[0] = (bf16_t)(x0*c0 - x1*s0);  o4[1] = (bf16_t)(x0*s0 + x1*c0);
        o4[2] = (bf16_t)(x2*c1 - x3*s1);  o4[3] = (bf16_t)(x2*s1 + x3*c1);
        ((bf16x4*)qkvh)[kb] = o4;
    }
}

extern "C" void kernel_launch(void* const* d_in, const int* in_sizes, int n_in,
                              void* d_out, int out_size, void* d_ws, size_t ws_size,
                              hipStream_t stream)
{
    (void)in_sizes; (void)n_in; (void)out_size; (void)ws_size;
    const int*   x_ids = (const int*)  d_in[0];
    const float* embed = (const float*)d_in[1];
    const float* ln1   = (const float*)d_in[2];
    const float* Wq    = (const float*)d_in[3];
    const float* Wk    = (const float*)d_in[4];
    const float* Wv    = (const float*)d_in[5];
    const float* Wo    = (const float*)d_in[6];
    const float* qn    = (const float*)d_in[7];
    const float* kn    = (const float*)d_in[8];
    const float* ln2   = (const float*)d_in[9];
    const float* Wg    = (const float*)d_in[10];
    const float* Wu    = (const float*)d_in[11];
    const float* Wd    = (const float*)d_in[12];
    const float* lnout = (const float*)d_in[13];
    float* out = (float*)d_out;

    char* ws = (char*)d_ws;
    const size_t MB = 1 << 20;
    float*  h    = (float*) (ws +   0 * MB);  // 4 MB fp32 residual
    bf16_t* hnh  = (bf16_t*)(ws +   4 * MB);
    bf16_t* hnl  = (bf16_t*)(ws +   6 * MB);
    bf16_t* qkvh = (bf16_t*)(ws +   8 * MB);  // 6 MB [1024][3072]
    bf16_t* qkvl = (bf16_t*)(ws +  14 * MB);
    bf16_t* vTh  = (bf16_t*)(ws +  20 * MB);
    bf16_t* vTl  = (bf16_t*)(ws +  22 * MB);
    bf16_t* oh   = (bf16_t*)(ws +  24 * MB);
    bf16_t* ol   = (bf16_t*)(ws +  26 * MB);
    bf16_t* wAh  = (bf16_t*)(ws +  28 * MB);  //  8 MB [4096][1024] hi-only
    bf16_t* wGUh = (bf16_t*)(ws +  36 * MB);  // 16 MB [8192][1024] interleaved hi
    bf16_t* wdh  = (bf16_t*)(ws +  52 * MB);  //  8 MB [1024][4096] hi-only
    bf16_t* silh = (bf16_t*)(ws +  60 * MB);  //  8 MB [1024][4096]
    bf16_t* sill = (bf16_t*)(ws +  68 * MB);
    float*  wdp  = (float*) (ws +  76 * MB);  // 16 MB split-K partials [4][1024][1024]
    bf16_t* eh   = (bf16_t*)(ws +  92 * MB);  // 62.5 MB embed hi (high-water ~155 MB)

    const long long M1 = 1024 * 1024;

    gather_kernel<<<1024, 256, 0, stream>>>(x_ids, embed, h);
    rmsnorm_split<<<1024, 256, 0, stream>>>(h, ln1, hnh, hnl);  // layer 0 pre-norm

    for (int l = 0; l < 6; ++l) {
        const float* wq = Wq + (size_t)l * M1;
        const float* wk = Wk + (size_t)l * M1;
        const float* wv = Wv + (size_t)l * M1;
        const float* wo = Wo + (size_t)l * M1;
        const float* wg = Wg + (size_t)l * 4 * M1;
        const float* wu = Wu + (size_t)l * 4 * M1;
        const float* wd = Wd + (size_t)l * 4 * M1;

        wsplit_kernel<<<4096, 256, 0, stream>>>(wq, wk, wv, wo, wg, wu, wd,
                                                wAh, wGUh, wdh);

        // fused QKV: [1024][3072] = hn @ wA[0:3072]^T  (2-plane, 128^2, dbuf)
        gemm_bf16<128,128,2,EP_SPLIT,1><<<dim3(8,24),256,0,stream>>>(
            hnh, hnl, wAh, nullptr, qkvh, qkvl, 1024, 1024, 1024, 3072, 0);

        rope_transpose<<<3072, 256, 0, stream>>>(qkvh, qkvl, qn + l * 64, kn + l * 64,
                                                 vTh, vTl);

        // fused scores+softcap+mask+softmax+PV (triangular-balanced)
        flash_attn<<<dim3(16,16), 128, 0, stream>>>(qkvh, vTh, vTl, oh, ol);

        // Wo residual (2-plane, 64^2 tiles)
        gemm_bf16<64,64,2,EP_RESID,1><<<dim3(16,16),256,0,stream>>>(
            oh, ol, wAh + 3 * M1, h, nullptr, nullptr, 1024, 1024, 1024, 1024, 0);

        rmsnorm_split<<<1024, 256, 0, stream>>>(h, ln2 + l * 1024, hnh, hnl);

        // fused gate+up+silu: logical [1024][8192] gu, writes sil [1024][4096]
        gemm_bf16<128,128,2,EP_SILU,1><<<dim3(8,64),256,0,stream>>>(
            hnh, hnl, wGUh, nullptr, silh, sill, 1024, 1024, 1024, 4096, 0);

        // down-proj: split-K x4 (2-plane) -> partials
        gemm_bf16<128,128,2,EP_STORE,1><<<dim3(8,8,4),256,0,stream>>>(
            silh, sill, wdh, wdp, nullptr, nullptr, 1024, 4096, 4096, 1024, M1);

        // reduce partials into h + next pre-norm (ln1[l+1], or ln_out after last)
        const float* wnext = (l < 5) ? (ln1 + (l + 1) * 1024) : lnout;
        reduce4_rms<<<1024, 256, 0, stream>>>(wdp, h, wnext, hnh, hnl);
    }

    split_kernel<<<32000, 256, 0, stream>>>(embed, eh, nullptr);
    // logits (1-plane, single-buffer): [1024][32000]
    gemm_bf16<128,128,1,EP_STORE,0><<<dim3(8,250),256,0,stream>>>(
        hnh, nullptr, eh, out, nullptr, nullptr, 1024, 1024, 1024, 32000, 0);
}

// Round 8
// 1465.351 us; speedup vs baseline: 5.3270x; 1.0103x over previous
//
#include <hip/hip_runtime.h>
#include <math.h>
#include <type_traits>

typedef __bf16 bf16_t;
typedef bf16_t bf16x4 __attribute__((ext_vector_type(4)));
typedef bf16_t bf16x8 __attribute__((ext_vector_type(8)));
typedef float  f32x4  __attribute__((ext_vector_type(4)));

#define RMS_EPS 1e-6f

enum { EP_STORE = 0, EP_RESID = 1, EP_SPLIT = 2, EP_SILU = 3 };

template<int V> using IC = std::integral_constant<int, V>;

static __device__ __forceinline__ f32x4 mfma16(bf16x8 a, bf16x8 b, f32x4 c) {
    return __builtin_amdgcn_mfma_f32_16x16x32_bf16(a, b, c, 0, 0, 0);
}

#define GLDS(gp, lp) __builtin_amdgcn_global_load_lds( \
    (const __attribute__((address_space(1))) void*)(gp), \
    (__attribute__((address_space(3))) void*)(lp), 16, 0, 0)

// counted vector-memory wait (T4): leave N newest loads in flight.
template<int N> static __device__ __forceinline__ void vmwait() {
    if constexpr (N == 0)      asm volatile("s_waitcnt vmcnt(0)" ::: "memory");
    else if constexpr (N == 2) asm volatile("s_waitcnt vmcnt(2)" ::: "memory");
    else if constexpr (N == 3) asm volatile("s_waitcnt vmcnt(3)" ::: "memory");
    else if constexpr (N == 4) asm volatile("s_waitcnt vmcnt(4)" ::: "memory");
    else if constexpr (N == 6) asm volatile("s_waitcnt vmcnt(6)" ::: "memory");
    else if constexpr (N == 8) asm volatile("s_waitcnt vmcnt(8)" ::: "memory");
    __builtin_amdgcn_sched_barrier(0);
}
static __device__ __forceinline__ void bar() { __builtin_amdgcn_s_barrier(); }

// C[M,N] = A[M,K]*B[N,K]^T.
// PLANES==2: A split hi/lo, B hi-only (2 MFMAs).  PLANES==1: hi-only.
// K-loop: counted-vmcnt double-buffered pipeline (T3+T4 minimum):
//   phase j: stage(chunk j, b[j%2]); vmcnt(NLD); s_barrier;
//            compute(chunk j-1);     s_barrier;
// The vmcnt(NLD) only waits for the PREVIOUS stage's loads (NLD newest stay
// in flight across the barrier) — no vmcnt(0) drain in the main loop.
// Requires K/32 even (all call sites use K=1024 or 256).
// blockIdx.z = K-chunk for split-K (A/B advance z*K cols; C advances z*sC).
template<int BM, int BN, int PLANES, int EPIL>
__global__ __launch_bounds__(256, (PLANES >= 2 && BM == 128) ? 3 : 4)
void gemm_bf16(const bf16_t* __restrict__ Ah, const bf16_t* __restrict__ Al,
               const bf16_t* __restrict__ Bh,
               float* __restrict__ Cf, bf16_t* __restrict__ Ch, bf16_t* __restrict__ Cl,
               int K, int lda, int ldb, int ldc, long long sC)
{
    constexpr int ASZ = BM * 32, BSZ = BN * 32;
    constexpr int NLD = (BM / 64) * (PLANES >= 2 ? 2 : 1) + (BN / 64);
    __shared__ __align__(16) bf16_t sAh[2][ASZ], sBh[2][BSZ];
    __shared__ __align__(16) bf16_t sAl[PLANES >= 2 ? 2 : 1][PLANES >= 2 ? ASZ : 8];

    const int gx = gridDim.x;
    int id = blockIdx.x + gx * blockIdx.y;
    if (gridDim.z == 1) {  // bijective XCD swizzle (m204)
        int nwg = gx * gridDim.y;
        int q = nwg >> 3, r = nwg & 7;
        int xcd = id & 7, ix = id >> 3;
        id = (xcd < r ? xcd * (q + 1) : r * (q + 1) + (xcd - r) * q) + ix;
    }
    const int bm = id % gx, bn = id / gx;
    const int row0 = bm * BM, col0 = bn * BN;

    const size_t kofs = (size_t)blockIdx.z * K;
    Ah += kofs;  Bh += kofs;
    if constexpr (PLANES >= 2) Al += kofs;

    const int tid = threadIdx.x, lane = tid & 63, wave = tid >> 6;
    const int lr = lane & 15, lg = lane >> 4;
    constexpr int WM = BM / 2, WN = BN / 2, MF = WM / 16, NF = WN / 16;
    const int wm = wave >> 1, wn = wave & 1;

    f32x4 acc[MF][NF];
    #pragma unroll
    for (int m = 0; m < MF; ++m)
        #pragma unroll
        for (int n = 0; n < NF; ++n) acc[m][n] = (f32x4){0.f, 0.f, 0.f, 0.f};

    auto stage = [&](int k0, auto pc) {
        constexpr int p = decltype(pc)::value;
        #pragma unroll
        for (int i = wave; i < BM / 16; i += 4) {
            int s = i * 64 + lane, rr = s >> 2, c = s & 3;
            size_t go = (size_t)(row0 + rr) * lda + k0 + ((c ^ ((rr >> 1) & 3)) << 3);
            GLDS(Ah + go, &sAh[p][i * 512]);
            if constexpr (PLANES >= 2) GLDS(Al + go, &sAl[p][i * 512]);
        }
        #pragma unroll
        for (int i = wave; i < BN / 16; i += 4) {
            int s = i * 64 + lane, rr = s >> 2, c = s & 3;
            size_t go = (size_t)(col0 + rr) * ldb + k0 + ((c ^ ((rr >> 1) & 3)) << 3);
            GLDS(Bh + go, &sBh[p][i * 512]);
        }
    };

    auto compute = [&](auto pc) {
        constexpr int p = decltype(pc)::value;
        bf16x8 ahf[MF], alf[MF], bhf[NF];
        #pragma unroll
        for (int m = 0; m < MF; ++m) {
            int rr = wm * WM + m * 16 + lr;
            int by = rr * 64 + ((lg ^ ((rr >> 1) & 3)) << 4);
            ahf[m] = *(const bf16x8*)((const char*)&sAh[p][0] + by);
            if constexpr (PLANES >= 2)
                alf[m] = *(const bf16x8*)((const char*)&sAl[p][0] + by);
        }
        #pragma unroll
        for (int n = 0; n < NF; ++n) {
            int rr = wn * WN + n * 16 + lr;
            int by = rr * 64 + ((lg ^ ((rr >> 1) & 3)) << 4);
            bhf[n] = *(const bf16x8*)((const char*)&sBh[p][0] + by);
        }
        #pragma unroll
        for (int m = 0; m < MF; ++m)
            #pragma unroll
            for (int n = 0; n < NF; ++n) {
                acc[m][n] = mfma16(ahf[m], bhf[n], acc[m][n]);
                if constexpr (PLANES >= 2)
                    acc[m][n] = mfma16(alf[m], bhf[n], acc[m][n]);
            }
    };

    // pipeline: chunk 0 staged; each loop iter stages 2 ahead, computes 2 behind
    stage(0, IC<0>{});
    int k0 = 32;
    for (; k0 + 32 < K; k0 += 64) {
        stage(k0, IC<1>{});
        vmwait<NLD>(); bar();          // prev stage landed; this one stays in flight
        compute(IC<0>{});
        bar();                          // protect b0 before overwrite next phase
        stage(k0 + 32, IC<0>{});
        vmwait<NLD>(); bar();
        compute(IC<1>{});
        bar();
    }
    stage(k0, IC<1>{});
    vmwait<NLD>(); bar();
    compute(IC<0>{});
    bar();
    vmwait<0>(); bar();                 // drain final stage
    compute(IC<1>{});

    #pragma unroll
    for (int m = 0; m < MF; ++m)
        #pragma unroll
        for (int n = 0; n < NF; ++n)
            #pragma unroll
            for (int r = 0; r < 4; ++r) {
                int grow = row0 + wm * WM + m * 16 + lg * 4 + r;
                int gcol = col0 + wn * WN + n * 16 + lr;
                float v = acc[m][n][r];
                if constexpr (EPIL == EP_SILU) {
                    float pv = __shfl_xor(v, 1, 64);   // partner column (g,u pair)
                    if (!(lr & 1)) {
                        float s = (v / (1.0f + expf(-v))) * pv;
                        size_t off = (size_t)grow * ldc + (gcol >> 1);
                        bf16_t hb = (bf16_t)s;
                        Ch[off] = hb;
                        Cl[off] = (bf16_t)(s - (float)hb);
                    }
                } else {
                    size_t off = (size_t)blockIdx.z * sC + (size_t)grow * ldc + gcol;
                    if constexpr (EPIL == EP_STORE) {
                        Cf[off] = v;
                    } else if constexpr (EPIL == EP_RESID) {
                        Cf[off] += v;
                    } else {  // EP_SPLIT
                        bf16_t hb = (bf16_t)v;
                        Ch[off] = hb;
                        Cl[off] = (bf16_t)(v - (float)hb);
                    }
                }
            }
}

// h += sum of 4 split-K partials (one row per block), then RMS-norm the new
// row with weight w -> hi/lo planes. Fuses reduce4 + next rmsnorm_split.
__global__ __launch_bounds__(256)
void reduce4_rms(const float* __restrict__ p, float* __restrict__ h,
                 const float* __restrict__ w,
                 bf16_t* __restrict__ outh, bf16_t* __restrict__ outl)
{
    int row = blockIdx.x, tid = threadIdx.x;
    size_t i = (size_t)row * 256 + tid;
    const size_t S = (1024 * 1024) / 4;
    f32x4 a = ((const f32x4*)p)[i];
    f32x4 b = ((const f32x4*)p)[i + S];
    f32x4 c = ((const f32x4*)p)[i + 2 * S];
    f32x4 d = ((const f32x4*)p)[i + 3 * S];
    f32x4 hv = ((const f32x4*)h)[i];
    #pragma unroll
    for (int j = 0; j < 4; ++j) hv[j] += (a[j] + b[j]) + (c[j] + d[j]);
    ((f32x4*)h)[i] = hv;

    float ss = hv[0]*hv[0] + hv[1]*hv[1] + hv[2]*hv[2] + hv[3]*hv[3];
    #pragma unroll
    for (int m = 1; m < 64; m <<= 1) ss += __shfl_xor(ss, m, 64);
    __shared__ float red[4];
    if ((tid & 63) == 0) red[tid >> 6] = ss;
    __syncthreads();
    float tot = red[0] + red[1] + red[2] + red[3];
    float inv = rsqrtf(tot * (1.0f / 1024.0f) + RMS_EPS);
    f32x4 wv = *(const f32x4*)(w + tid * 4);
    bf16x4 hv4, lv4;
    #pragma unroll
    for (int j = 0; j < 4; ++j) {
        float x = hv[j] * inv * wv[j];
        bf16_t hb = (bf16_t)x;
        hv4[j] = hb;
        lv4[j] = (bf16_t)(x - (float)hb);
    }
    ((bf16x4*)outh)[i] = hv4;
    ((bf16x4*)outl)[i] = lv4;
}

// Flash attention, triangular-balanced: block (px,hh) handles q-chunks
// {px, 31-px} (QBLK=32 rows each), KB=64 keys/tile. 2 waves (16 q-rows each).
// Q,K hi-only; V hi+lo; softcap+causal+online softmax fp32; P hi/lo via
// per-wave LDS; 3-term P.V.
__global__ __launch_bounds__(128, 2)
void flash_attn(const bf16_t* __restrict__ qkvh,
                const bf16_t* __restrict__ vTh, const bf16_t* __restrict__ vTl,
                bf16_t* __restrict__ oh, bf16_t* __restrict__ ol)
{
    __shared__ __align__(16) bf16_t sQ[32*64], sK[64*64], sVh[64*64], sVl[64*64];
    __shared__ __align__(16) bf16_t sPh[32*64], sPl[32*64];

    const int px = blockIdx.x;
    const int hh = blockIdx.y;
    const int tid = threadIdx.x, lane = tid & 63, w = tid >> 6;
    const int lr = lane & 15, lg = lane >> 4;

    for (int cc = 0; cc < 2; ++cc) {
        const int qb = cc ? 31 - px : px;
        const int q0 = qb * 32;

        #pragma unroll
        for (int ii = 0; ii < 2; ++ii) {
            int r0 = w * 16 + ii * 8;
            int r  = r0 + (lane >> 3);
            int i  = lane & 7;
            GLDS(qkvh + (size_t)(q0 + r) * 3072 + hh * 64 + ((i ^ (r & 7)) << 3),
                 sQ + r0 * 64);
        }
        __syncthreads();

        bf16x8 qa[2];
        #pragma unroll
        for (int ks = 0; ks < 2; ++ks) {
            int r = w * 16 + lr;
            qa[ks] = *(const bf16x8*)((const char*)sQ + r * 128 +
                                      ((((ks << 2) | lg) ^ (r & 7)) << 4));
        }

        f32x4 o_acc[4];
        #pragma unroll
        for (int n = 0; n < 4; ++n) o_acc[n] = (f32x4){0.f, 0.f, 0.f, 0.f};
        float m_run[4] = {-1e30f, -1e30f, -1e30f, -1e30f};
        float l_run[4] = {0.f, 0.f, 0.f, 0.f};

        const int ntiles = ((q0 + 31) >> 6) + 1;
        for (int t = 0; t < ntiles; ++t) {
            const int kv0 = t * 64;
            #pragma unroll
            for (int ii = 0; ii < 4; ++ii) {
                int r0 = w * 32 + ii * 8;
                int r  = r0 + (lane >> 3);
                int i  = lane & 7;
                GLDS(qkvh + (size_t)(kv0 + r) * 3072 + 1024 + hh * 64 + ((i ^ (r & 7)) << 3),
                     sK + r0 * 64);
                GLDS(vTh + (size_t)(hh * 64 + r) * 1024 + kv0 + ((i ^ (r & 7)) << 3),
                     sVh + r0 * 64);
                GLDS(vTl + (size_t)(hh * 64 + r) * 1024 + kv0 + ((i ^ (r & 7)) << 3),
                     sVl + r0 * 64);
            }
            __syncthreads();

            f32x4 s_acc[4];
            #pragma unroll
            for (int n = 0; n < 4; ++n) s_acc[n] = (f32x4){0.f, 0.f, 0.f, 0.f};
            #pragma unroll
            for (int ks = 0; ks < 2; ++ks)
                #pragma unroll
                for (int n = 0; n < 4; ++n) {
                    int r = n * 16 + lr;
                    bf16x8 kb = *(const bf16x8*)((const char*)sK + r * 128 +
                                                 ((((ks << 2) | lg) ^ (r & 7)) << 4));
                    s_acc[n] = mfma16(qa[ks], kb, s_acc[n]);
                }

            #pragma unroll
            for (int j = 0; j < 4; ++j) {
                int qr = q0 + w * 16 + lg * 4 + j;
                float p[4];
                float mx = -1e30f;
                #pragma unroll
                for (int n = 0; n < 4; ++n) {
                    float v = s_acc[n][j] * 0.125f;
                    v = 50.f * tanhf(v * 0.02f);
                    int key = kv0 + n * 16 + lr;
                    if (key > qr) v = -1e30f;
                    p[n] = v;
                    mx = fmaxf(mx, v);
                }
                #pragma unroll
                for (int m = 1; m < 16; m <<= 1) mx = fmaxf(mx, __shfl_xor(mx, m, 64));
                float mn = fmaxf(m_run[j], mx);
                float ef = __expf(m_run[j] - mn);
                m_run[j] = mn;
                float rs = 0.f;
                #pragma unroll
                for (int n = 0; n < 4; ++n) {
                    float e = expf(p[n] - mn);
                    p[n] = e;
                    rs += e;
                }
                #pragma unroll
                for (int m = 1; m < 16; m <<= 1) rs += __shfl_xor(rs, m, 64);
                l_run[j] = l_run[j] * ef + rs;
                #pragma unroll
                for (int n = 0; n < 4; ++n) o_acc[n][j] *= ef;
                int r = w * 16 + lg * 4 + j;
                #pragma unroll
                for (int n = 0; n < 4; ++n) {
                    int c = n * 16 + lr;
                    int byo = r * 128 + ((((c >> 3) ^ (r & 7)) << 4)) + ((c & 7) << 1);
                    bf16_t hb = (bf16_t)p[n];
                    *(bf16_t*)((char*)sPh + byo) = hb;
                    *(bf16_t*)((char*)sPl + byo) = (bf16_t)(p[n] - (float)hb);
                }
            }

            #pragma unroll
            for (int ks = 0; ks < 2; ++ks) {
                int pr = w * 16 + lr;
                int pby = pr * 128 + ((((ks << 2) | lg) ^ (pr & 7)) << 4);
                bf16x8 pa  = *(const bf16x8*)((const char*)sPh + pby);
                bf16x8 pl_ = *(const bf16x8*)((const char*)sPl + pby);
                #pragma unroll
                for (int n = 0; n < 4; ++n) {
                    int vr = n * 16 + lr;
                    int vby = vr * 128 + ((((ks << 2) | lg) ^ (vr & 7)) << 4);
                    bf16x8 vhf = *(const bf16x8*)((const char*)sVh + vby);
                    bf16x8 vlf = *(const bf16x8*)((const char*)sVl + vby);
                    o_acc[n] = mfma16(pa,  vhf, o_acc[n]);
                    o_acc[n] = mfma16(pl_, vhf, o_acc[n]);
                    o_acc[n] = mfma16(pa,  vlf, o_acc[n]);
                }
            }
            __syncthreads();
        }

        #pragma unroll
        for (int j = 0; j < 4; ++j) {
            float inv = 1.0f / l_run[j];
            int qr = q0 + w * 16 + lg * 4 + j;
            #pragma unroll
            for (int n = 0; n < 4; ++n) {
                float v = o_acc[n][j] * inv;
                size_t off = (size_t)qr * 1024 + hh * 64 + n * 16 + lr;
                bf16_t hb = (bf16_t)v;
                oh[off] = hb;
                ol[off] = (bf16_t)(v - (float)hb);
            }
        }
    }
}

__global__ __launch_bounds__(256)
void split_kernel(const float* __restrict__ src, bf16_t* __restrict__ hi,
                  bf16_t* __restrict__ lo)
{
    size_t i = (size_t)blockIdx.x * 256 + threadIdx.x;
    f32x4 v = ((const f32x4*)src)[i];
    bf16x4 hv, lv;
    #pragma unroll
    for (int j = 0; j < 4; ++j) {
        bf16_t hb = (bf16_t)v[j];
        hv[j] = hb;
        lv[j] = (bf16_t)(v[j] - (float)hb);
    }
    ((bf16x4*)hi)[i] = hv;
    if (lo) ((bf16x4*)lo)[i] = lv;
}

// hi-only weight pack, grid-strided (4 chunks/block, 4096 blocks):
// wq|wk|wv|wo -> wAh [4096x1024]; wg|wu -> wGUh INTERLEAVED [8192x1024]
// (row 2i = wg_i, row 2i+1 = wu_i, for the fused-silu GEMM); wd -> wdh.
__global__ __launch_bounds__(256)
void wsplit_kernel(const float* __restrict__ wq, const float* __restrict__ wk,
                   const float* __restrict__ wv, const float* __restrict__ wo,
                   const float* __restrict__ wg, const float* __restrict__ wu,
                   const float* __restrict__ wd,
                   bf16_t* __restrict__ wAh, bf16_t* __restrict__ wGUh,
                   bf16_t* __restrict__ wdh)
{
    #pragma unroll
    for (int k = 0; k < 4; ++k) {
        int b = blockIdx.x * 4 + k;
        const float* src;
        bf16_t* dst;
        size_t so, doff;
        if (b < 4096) {
            src = b < 1024 ? wq : b < 2048 ? wk : b < 3072 ? wv : wo;
            so = (size_t)(b & 1023) * 256 + threadIdx.x;
            doff = (size_t)b * 256 + threadIdx.x;
            dst = wAh;
        } else if (b < 12288) {
            int bb = b - 4096;
            int row = bb < 4096 ? 2 * bb : 2 * (bb - 4096) + 1;
            src = bb < 4096 ? wg : wu;
            so = (size_t)(bb & 4095) * 256 + threadIdx.x;
            doff = (size_t)row * 256 + threadIdx.x;
            dst = wGUh;
        } else {
            src = wd;
            so = (size_t)(b - 12288) * 256 + threadIdx.x;
            doff = so;
            dst = wdh;
        }
        f32x4 v = ((const f32x4*)src)[so];
        bf16x4 hv;
        #pragma unroll
        for (int j = 0; j < 4; ++j) hv[j] = (bf16_t)v[j];
        ((bf16x4*)dst)[doff] = hv;
    }
}

__global__ __launch_bounds__(256)
void gather_kernel(const int* __restrict__ ids, const float* __restrict__ embed,
                   float* __restrict__ h)
{
    int t = blockIdx.x;
    int row = ids[t];
    const f32x4* src = (const f32x4*)(embed + (size_t)row * 1024);
    f32x4* dst = (f32x4*)(h + (size_t)t * 1024);
    dst[threadIdx.x] = src[threadIdx.x];
}

__global__ __launch_bounds__(256)
void rmsnorm_split(const float* __restrict__ in, const float* __restrict__ w,
                   bf16_t* __restrict__ outh, bf16_t* __restrict__ outl)
{
    int row = blockIdx.x, tid = threadIdx.x;
    f32x4 v = *(const f32x4*)(in + (size_t)row * 1024 + tid * 4);
    float ss = v[0]*v[0] + v[1]*v[1] + v[2]*v[2] + v[3]*v[3];
    #pragma unroll
    for (int m = 1; m < 64; m <<= 1) ss += __shfl_xor(ss, m, 64);
    __shared__ float red[4];
    if ((tid & 63) == 0) red[tid >> 6] = ss;
    __syncthreads();
    float tot = red[0] + red[1] + red[2] + red[3];
    float inv = rsqrtf(tot * (1.0f / 1024.0f) + RMS_EPS);
    f32x4 wv = *(const f32x4*)(w + tid * 4);
    bf16x4 hv, lv;
    #pragma unroll
    for (int j = 0; j < 4; ++j) {
        float x = v[j] * inv * wv[j];
        bf16_t hb = (bf16_t)x;
        hv[j] = hb;
        lv[j] = (bf16_t)(x - (float)hb);
    }
    ((bf16x4*)outh)[(size_t)row * 256 + tid] = hv;
    ((bf16x4*)outl)[(size_t)row * 256 + tid] = lv;
}

// Merged: blocks 0-1023  = per-(t,head) RMS(Dh=64)+RoPE on packed qkv [1024][3072]
//         blocks 1024-3071 = v (cols 2048-3071) -> vT [1024][1024], hi/lo planes.
// Reference quirk: rotation angle = head_index * freq (cos[:n], n = H).
__global__ __launch_bounds__(256)
void rope_transpose(bf16_t* __restrict__ qkvh, bf16_t* __restrict__ qkvl,
                    const float* __restrict__ qn, const float* __restrict__ kn,
                    bf16_t* __restrict__ vTh, bf16_t* __restrict__ vTl)
{
    __shared__ bf16_t tile[32][33];
    int b = blockIdx.x;
    if (b >= 1024) {
        int t2 = b - 1024;
        int z = t2 >> 10, rem = t2 & 1023;
        const bf16_t* in = z ? qkvl : qkvh;
        bf16_t* out      = z ? vTl : vTh;
        int bx = (rem & 31) * 32, by = (rem >> 5) * 32;
        int r = threadIdx.x >> 5, c = threadIdx.x & 31;
        #pragma unroll
        for (int rr = r; rr < 32; rr += 8)
            tile[rr][c] = in[(size_t)(by + rr) * 3072 + 2048 + bx + c];
        __syncthreads();
        #pragma unroll
        for (int rr = r; rr < 32; rr += 8)
            out[(size_t)(bx + rr) * 1024 + by + c] = tile[c][rr];
        return;
    }

    int t = b, tid = threadIdx.x;
    int hh = tid >> 4;
    int i  = (tid & 15) * 4;
    size_t qb = ((size_t)t * 3072 + hh * 64 + i) >> 2;
    size_t kb = qb + (1024 >> 2);

    int p0 = i >> 1;
    float f0 = powf(10000.f, -(float)p0 / 32.f);
    float f1 = powf(10000.f, -(float)(p0 + 1) / 32.f);
    float a0 = (float)hh * f0, a1 = (float)hh * f1;
    float c0 = cosf(a0), s0 = sinf(a0);
    float c1 = cosf(a1), s1 = sinf(a1);

    f32x4 qw = *(const f32x4*)(qn + i);
    f32x4 kw = *(const f32x4*)(kn + i);

    {
        bf16x4 h4 = ((const bf16x4*)qkvh)[qb], l4 = ((const bf16x4*)qkvl)[qb];
        float x[4];
        #pragma unroll
        for (int j = 0; j < 4; ++j) x[j] = (float)h4[j] + (float)l4[j];
        float ss = x[0]*x[0] + x[1]*x[1] + x[2]*x[2] + x[3]*x[3];
        #pragma unroll
        for (int m = 1; m < 16; m <<= 1) ss += __shfl_xor(ss, m, 64);
        float inv = rsqrtf(ss * (1.0f / 64.0f) + RMS_EPS);
        float x0 = x[0]*inv*qw[0], x1 = x[1]*inv*qw[1];
        float x2 = x[2]*inv*qw[2], x3 = x[3]*inv*qw[3];
        bf16x4 o4;
        o4[0] = (bf16_t)(x0*c0 - x1*s0);  o4[1] = (bf16_t)(x0*s0 + x1*c0);
        o4[2] = (bf16_t)(x2*c1 - x3*s1);  o4[3] = (bf16_t)(x2*s1 + x3*c1);
        ((bf16x4*)qkvh)[qb] = o4;
    }
    {
        bf16x4 h4 = ((const bf16x4*)qkvh)[kb], l4 = ((const bf16x4*)qkvl)[kb];
        float x[4];
        #pragma unroll
        for (int j = 0; j < 4; ++j) x[j] = (float)h4[j] + (float)l4[j];
        float ss = x[0]*x[0] + x[1]*x[1] + x[2]*x[2] + x[3]*x[3];
        #pragma unroll
        for (int m = 1; m < 16; m <<= 1) ss += __shfl_xor(ss, m, 64);
        float inv = rsqrtf(ss * (1.0f / 64.0f) + RMS_EPS);
        float x0 = x[0]*inv*kw[0], x1 = x[1]*inv*kw[1];
        float x2 = x[2]*inv*kw[2], x3 = x[3]*inv*kw[3];
        bf16x4 o4;
        o4[0] = (bf16_t)(x0*c0 - x1*s0);  o4[1] = (bf16_t)(x0*s0 + x1*c0);
        o4[2] = (bf16_t)(x2*c1 - x3*s1);  o4[3] = (bf16_t)(x2*s1 + x3*c1);
        ((bf16x4*)qkvh)[kb] = o4;
    }
}

extern "C" void kernel_launch(void* const* d_in, const int* in_sizes, int n_in,
                              void* d_out, int out_size, void* d_ws, size_t ws_size,
                              hipStream_t stream)
{
    (void)in_sizes; (void)n_in; (void)out_size; (void)ws_size;
    const int*   x_ids = (const int*)  d_in[0];
    const float* embed = (const float*)d_in[1];
    const float* ln1   = (const float*)d_in[2];
    const float* Wq    = (const float*)d_in[3];
    const float* Wk    = (const float*)d_in[4];
    const float* Wv    = (const float*)d_in[5];
    const float* Wo    = (const float*)d_in[6];
    const float* qn    = (const float*)d_in[7];
    const float* kn    = (const float*)d_in[8];
    const float* ln2   = (const float*)d_in[9];
    const float* Wg    = (const float*)d_in[10];
    const float* Wu    = (const float*)d_in[11];
    const float* Wd    = (const float*)d_in[12];
    const float* lnout = (const float*)d_in[13];
    float* out = (float*)d_out;

    char* ws = (char*)d_ws;
    const size_t MB = 1 << 20;
    float*  h    = (float*) (ws +   0 * MB);  // 4 MB fp32 residual
    bf16_t* hnh  = (bf16_t*)(ws +   4 * MB);
    bf16_t* hnl  = (bf16_t*)(ws +   6 * MB);
    bf16_t* qkvh = (bf16_t*)(ws +   8 * MB);  // 6 MB [1024][3072]
    bf16_t* qkvl = (bf16_t*)(ws +  14 * MB);
    bf16_t* vTh  = (bf16_t*)(ws +  20 * MB);
    bf16_t* vTl  = (bf16_t*)(ws +  22 * MB);
    bf16_t* oh   = (bf16_t*)(ws +  24 * MB);
    bf16_t* ol   = (bf16_t*)(ws +  26 * MB);
    bf16_t* wAh  = (bf16_t*)(ws +  28 * MB);  //  8 MB [4096][1024] hi-only
    bf16_t* wGUh = (bf16_t*)(ws +  36 * MB);  // 16 MB [8192][1024] interleaved hi
    bf16_t* wdh  = (bf16_t*)(ws +  52 * MB);  //  8 MB [1024][4096] hi-only
    bf16_t* silh = (bf16_t*)(ws +  60 * MB);  //  8 MB [1024][4096]
    bf16_t* sill = (bf16_t*)(ws +  68 * MB);
    float*  wdp  = (float*) (ws +  76 * MB);  // 16 MB split-K partials [4][1024][1024]
    bf16_t* eh   = (bf16_t*)(ws +  92 * MB);  // 62.5 MB embed hi (high-water ~155 MB)

    const long long M1 = 1024 * 1024;

    gather_kernel<<<1024, 256, 0, stream>>>(x_ids, embed, h);
    rmsnorm_split<<<1024, 256, 0, stream>>>(h, ln1, hnh, hnl);  // layer 0 pre-norm

    for (int l = 0; l < 6; ++l) {
        const float* wq = Wq + (size_t)l * M1;
        const float* wk = Wk + (size_t)l * M1;
        const float* wv = Wv + (size_t)l * M1;
        const float* wo = Wo + (size_t)l * M1;
        const float* wg = Wg + (size_t)l * 4 * M1;
        const float* wu = Wu + (size_t)l * 4 * M1;
        const float* wd = Wd + (size_t)l * 4 * M1;

        wsplit_kernel<<<4096, 256, 0, stream>>>(wq, wk, wv, wo, wg, wu, wd,
                                                wAh, wGUh, wdh);

        // fused QKV: [1024][3072] = hn @ wA[0:3072]^T  (2-plane, 128^2)
        gemm_bf16<128,128,2,EP_SPLIT><<<dim3(8,24),256,0,stream>>>(
            hnh, hnl, wAh, nullptr, qkvh, qkvl, 1024, 1024, 1024, 3072, 0);

        rope_transpose<<<3072, 256, 0, stream>>>(qkvh, qkvl, qn + l * 64, kn + l * 64,
                                                 vTh, vTl);

        // fused scores+softcap+mask+softmax+PV (triangular-balanced)
        flash_attn<<<dim3(16,16), 128, 0, stream>>>(qkvh, vTh, vTl, oh, ol);

        // Wo residual (2-plane, 64^2 tiles)
        gemm_bf16<64,64,2,EP_RESID><<<dim3(16,16),256,0,stream>>>(
            oh, ol, wAh + 3 * M1, h, nullptr, nullptr, 1024, 1024, 1024, 1024, 0);

        rmsnorm_split<<<1024, 256, 0, stream>>>(h, ln2 + l * 1024, hnh, hnl);

        // fused gate+up+silu: logical [1024][8192] gu, writes sil [1024][4096]
        gemm_bf16<128,128,2,EP_SILU><<<dim3(8,64),256,0,stream>>>(
            hnh, hnl, wGUh, nullptr, silh, sill, 1024, 1024, 1024, 4096, 0);

        // down-proj: split-K x4 (2-plane) -> partials
        gemm_bf16<128,128,2,EP_STORE><<<dim3(8,8,4),256,0,stream>>>(
            silh, sill, wdh, wdp, nullptr, nullptr, 1024, 4096, 4096, 1024, M1);

        // reduce partials into h + next pre-norm (ln1[l+1], or ln_out after last)
        const float* wnext = (l < 5) ? (ln1 + (l + 1) * 1024) : lnout;
        reduce4_rms<<<1024, 256, 0, stream>>>(wdp, h, wnext, hnh, hnl);
    }

    split_kernel<<<32000, 256, 0, stream>>>(embed, eh, nullptr);
    // logits (1-plane): [1024][32000]
    gemm_bf16<128,128,1,EP_STORE><<<dim3(8,250),256,0,stream>>>(
        hnh, nullptr, eh, out, nullptr, nullptr, 1024, 1024, 1024, 32000, 0);
}

// Round 9
// 1403.809 us; speedup vs baseline: 5.5605x; 1.0438x over previous
//
#include <hip/hip_runtime.h>
#include <math.h>
#include <type_traits>

typedef __bf16 bf16_t;
typedef bf16_t bf16x4 __attribute__((ext_vector_type(4)));
typedef bf16_t bf16x8 __attribute__((ext_vector_type(8)));
typedef float  f32x4  __attribute__((ext_vector_type(4)));

#define RMS_EPS 1e-6f

enum { EP_STORE = 0, EP_RESID = 1, EP_SPLIT = 2, EP_SILU = 3 };

template<int V> using IC = std::integral_constant<int, V>;

static __device__ __forceinline__ f32x4 mfma16(bf16x8 a, bf16x8 b, f32x4 c) {
    return __builtin_amdgcn_mfma_f32_16x16x32_bf16(a, b, c, 0, 0, 0);
}

#define GLDS(gp, lp) __builtin_amdgcn_global_load_lds( \
    (const __attribute__((address_space(1))) void*)(gp), \
    (__attribute__((address_space(3))) void*)(lp), 16, 0, 0)

// counted vector-memory wait (T4): leave N newest loads in flight.
template<int N> static __device__ __forceinline__ void vmwait() {
    if constexpr (N == 0)      asm volatile("s_waitcnt vmcnt(0)" ::: "memory");
    else if constexpr (N == 2) asm volatile("s_waitcnt vmcnt(2)" ::: "memory");
    else if constexpr (N == 3) asm volatile("s_waitcnt vmcnt(3)" ::: "memory");
    else if constexpr (N == 4) asm volatile("s_waitcnt vmcnt(4)" ::: "memory");
    else if constexpr (N == 6) asm volatile("s_waitcnt vmcnt(6)" ::: "memory");
    else if constexpr (N == 8) asm volatile("s_waitcnt vmcnt(8)" ::: "memory");
    __builtin_amdgcn_sched_barrier(0);
}
static __device__ __forceinline__ void bar() { __builtin_amdgcn_s_barrier(); }

// C[M,N] = A[M,K]*B[N,K]^T.
// PLANES==2: A split hi/lo, B hi-only (2 MFMAs).  PLANES==1: hi-only.
// K-loop: counted-vmcnt double-buffered pipeline (1-phase cover).
// blockIdx.z = K-chunk for split-K (A/B advance z*K cols; C advances z*sC).
template<int BM, int BN, int PLANES, int EPIL>
__global__ __launch_bounds__(256, (PLANES >= 2 && BM == 128) ? 3 : 4)
void gemm_bf16(const bf16_t* __restrict__ Ah, const bf16_t* __restrict__ Al,
               const bf16_t* __restrict__ Bh,
               float* __restrict__ Cf, bf16_t* __restrict__ Ch, bf16_t* __restrict__ Cl,
               int K, int lda, int ldb, int ldc, long long sC)
{
    constexpr int ASZ = BM * 32, BSZ = BN * 32;
    constexpr int NLD = (BM / 64) * (PLANES >= 2 ? 2 : 1) + (BN / 64);
    __shared__ __align__(16) bf16_t sAh[2][ASZ], sBh[2][BSZ];
    __shared__ __align__(16) bf16_t sAl[PLANES >= 2 ? 2 : 1][PLANES >= 2 ? ASZ : 8];

    const int gx = gridDim.x;
    int id = blockIdx.x + gx * blockIdx.y;
    if (gridDim.z == 1) {  // bijective XCD swizzle (m204)
        int nwg = gx * gridDim.y;
        int q = nwg >> 3, r = nwg & 7;
        int xcd = id & 7, ix = id >> 3;
        id = (xcd < r ? xcd * (q + 1) : r * (q + 1) + (xcd - r) * q) + ix;
    }
    const int bm = id % gx, bn = id / gx;
    const int row0 = bm * BM, col0 = bn * BN;

    const size_t kofs = (size_t)blockIdx.z * K;
    Ah += kofs;  Bh += kofs;
    if constexpr (PLANES >= 2) Al += kofs;

    const int tid = threadIdx.x, lane = tid & 63, wave = tid >> 6;
    const int lr = lane & 15, lg = lane >> 4;
    constexpr int WM = BM / 2, WN = BN / 2, MF = WM / 16, NF = WN / 16;
    const int wm = wave >> 1, wn = wave & 1;

    f32x4 acc[MF][NF];
    #pragma unroll
    for (int m = 0; m < MF; ++m)
        #pragma unroll
        for (int n = 0; n < NF; ++n) acc[m][n] = (f32x4){0.f, 0.f, 0.f, 0.f};

    auto stage = [&](int k0, auto pc) {
        constexpr int p = decltype(pc)::value;
        #pragma unroll
        for (int i = wave; i < BM / 16; i += 4) {
            int s = i * 64 + lane, rr = s >> 2, c = s & 3;
            size_t go = (size_t)(row0 + rr) * lda + k0 + ((c ^ ((rr >> 1) & 3)) << 3);
            GLDS(Ah + go, &sAh[p][i * 512]);
            if constexpr (PLANES >= 2) GLDS(Al + go, &sAl[p][i * 512]);
        }
        #pragma unroll
        for (int i = wave; i < BN / 16; i += 4) {
            int s = i * 64 + lane, rr = s >> 2, c = s & 3;
            size_t go = (size_t)(col0 + rr) * ldb + k0 + ((c ^ ((rr >> 1) & 3)) << 3);
            GLDS(Bh + go, &sBh[p][i * 512]);
        }
    };

    auto compute = [&](auto pc) {
        constexpr int p = decltype(pc)::value;
        bf16x8 ahf[MF], alf[MF], bhf[NF];
        #pragma unroll
        for (int m = 0; m < MF; ++m) {
            int rr = wm * WM + m * 16 + lr;
            int by = rr * 64 + ((lg ^ ((rr >> 1) & 3)) << 4);
            ahf[m] = *(const bf16x8*)((const char*)&sAh[p][0] + by);
            if constexpr (PLANES >= 2)
                alf[m] = *(const bf16x8*)((const char*)&sAl[p][0] + by);
        }
        #pragma unroll
        for (int n = 0; n < NF; ++n) {
            int rr = wn * WN + n * 16 + lr;
            int by = rr * 64 + ((lg ^ ((rr >> 1) & 3)) << 4);
            bhf[n] = *(const bf16x8*)((const char*)&sBh[p][0] + by);
        }
        #pragma unroll
        for (int m = 0; m < MF; ++m)
            #pragma unroll
            for (int n = 0; n < NF; ++n) {
                acc[m][n] = mfma16(ahf[m], bhf[n], acc[m][n]);
                if constexpr (PLANES >= 2)
                    acc[m][n] = mfma16(alf[m], bhf[n], acc[m][n]);
            }
    };

    stage(0, IC<0>{});
    int k0 = 32;
    for (; k0 + 32 < K; k0 += 64) {
        stage(k0, IC<1>{});
        vmwait<NLD>(); bar();
        compute(IC<0>{});
        bar();
        stage(k0 + 32, IC<0>{});
        vmwait<NLD>(); bar();
        compute(IC<1>{});
        bar();
    }
    stage(k0, IC<1>{});
    vmwait<NLD>(); bar();
    compute(IC<0>{});
    bar();
    vmwait<0>(); bar();
    compute(IC<1>{});

    #pragma unroll
    for (int m = 0; m < MF; ++m)
        #pragma unroll
        for (int n = 0; n < NF; ++n)
            #pragma unroll
            for (int r = 0; r < 4; ++r) {
                int grow = row0 + wm * WM + m * 16 + lg * 4 + r;
                int gcol = col0 + wn * WN + n * 16 + lr;
                float v = acc[m][n][r];
                if constexpr (EPIL == EP_SILU) {
                    float pv = __shfl_xor(v, 1, 64);   // partner column (g,u pair)
                    if (!(lr & 1)) {
                        float s = (v / (1.0f + expf(-v))) * pv;
                        size_t off = (size_t)grow * ldc + (gcol >> 1);
                        bf16_t hb = (bf16_t)s;
                        Ch[off] = hb;
                        Cl[off] = (bf16_t)(s - (float)hb);
                    }
                } else {
                    size_t off = (size_t)blockIdx.z * sC + (size_t)grow * ldc + gcol;
                    if constexpr (EPIL == EP_STORE) {
                        Cf[off] = v;
                    } else if constexpr (EPIL == EP_RESID) {
                        Cf[off] += v;
                    } else {  // EP_SPLIT
                        bf16_t hb = (bf16_t)v;
                        Ch[off] = hb;
                        Cl[off] = (bf16_t)(v - (float)hb);
                    }
                }
            }
}

// Logits GEMM, specialized: C[1024,32000] = A[1024,1024] * B[32000,1024]^T,
// hi-only (1 MFMA). TRIPLE-buffered LDS: stage chunk j+2 while computing j ->
// 2-phase (~600 cyc) load-latency cover; vmcnt(8) leaves 2 stages in flight.
__global__ __launch_bounds__(256, 3)
void gemm_logits(const bf16_t* __restrict__ Ah, const bf16_t* __restrict__ Bh,
                 float* __restrict__ Cf)
{
    constexpr int lda = 1024, ldb = 1024, ldc = 32000;
    __shared__ __align__(16) bf16_t sA[3][128 * 32], sB[3][128 * 32];

    const int gx = gridDim.x;
    int id = blockIdx.x + gx * blockIdx.y;
    {   // bijective XCD swizzle
        int nwg = gx * gridDim.y;
        int q = nwg >> 3, r = nwg & 7;
        int xcd = id & 7, ix = id >> 3;
        id = (xcd < r ? xcd * (q + 1) : r * (q + 1) + (xcd - r) * q) + ix;
    }
    const int bm = id % gx, bn = id / gx;
    const int row0 = bm * 128, col0 = bn * 128;

    const int tid = threadIdx.x, lane = tid & 63, wave = tid >> 6;
    const int lr = lane & 15, lg = lane >> 4;
    const int wm = wave >> 1, wn = wave & 1;

    f32x4 acc[4][4];
    #pragma unroll
    for (int m = 0; m < 4; ++m)
        #pragma unroll
        for (int n = 0; n < 4; ++n) acc[m][n] = (f32x4){0.f, 0.f, 0.f, 0.f};

    auto stage = [&](int k0, int p) {
        #pragma unroll
        for (int i = wave; i < 8; i += 4) {
            int s = i * 64 + lane, rr = s >> 2, c = s & 3;
            size_t go = (size_t)(row0 + rr) * lda + k0 + ((c ^ ((rr >> 1) & 3)) << 3);
            GLDS(Ah + go, &sA[p][i * 512]);
        }
        #pragma unroll
        for (int i = wave; i < 8; i += 4) {
            int s = i * 64 + lane, rr = s >> 2, c = s & 3;
            size_t go = (size_t)(col0 + rr) * ldb + k0 + ((c ^ ((rr >> 1) & 3)) << 3);
            GLDS(Bh + go, &sB[p][i * 512]);
        }
    };

    auto compute = [&](int p) {
        bf16x8 af[4], bf[4];
        #pragma unroll
        for (int m = 0; m < 4; ++m) {
            int rr = wm * 64 + m * 16 + lr;
            int by = rr * 64 + ((lg ^ ((rr >> 1) & 3)) << 4);
            af[m] = *(const bf16x8*)((const char*)&sA[p][0] + by);
        }
        #pragma unroll
        for (int n = 0; n < 4; ++n) {
            int rr = wn * 64 + n * 16 + lr;
            int by = rr * 64 + ((lg ^ ((rr >> 1) & 3)) << 4);
            bf[n] = *(const bf16x8*)((const char*)&sB[p][0] + by);
        }
        #pragma unroll
        for (int m = 0; m < 4; ++m)
            #pragma unroll
            for (int n = 0; n < 4; ++n)
                acc[m][n] = mfma16(af[m], bf[n], acc[m][n]);
    };

    stage(0, 0);
    stage(32, 1);
    // 32 chunks total; loop computes 0..29, stages 2..31
    for (int j = 0; j < 30; ++j) {
        stage(32 * (j + 2), (j + 2) % 3);
        vmwait<8>(); bar();     // ensure stage j landed; j+1, j+2 stay in flight
        compute(j % 3);
        bar();                  // protect buf[(j+3)%3] before next phase's stage
    }
    vmwait<4>(); bar();
    compute(0);                 // chunk 30
    vmwait<0>(); bar();
    compute(1);                 // chunk 31

    #pragma unroll
    for (int m = 0; m < 4; ++m)
        #pragma unroll
        for (int n = 0; n < 4; ++n)
            #pragma unroll
            for (int r = 0; r < 4; ++r) {
                int grow = row0 + wm * 64 + m * 16 + lg * 4 + r;
                int gcol = col0 + wn * 64 + n * 16 + lr;
                Cf[(size_t)grow * ldc + gcol] = acc[m][n][r];
            }
}

// h += sum of 4 split-K partials (one row per block), then RMS-norm the new
// row with weight w -> hi/lo planes. Fuses reduce4 + next rmsnorm_split.
__global__ __launch_bounds__(256)
void reduce4_rms(const float* __restrict__ p, float* __restrict__ h,
                 const float* __restrict__ w,
                 bf16_t* __restrict__ outh, bf16_t* __restrict__ outl)
{
    int row = blockIdx.x, tid = threadIdx.x;
    size_t i = (size_t)row * 256 + tid;
    const size_t S = (1024 * 1024) / 4;
    f32x4 a = ((const f32x4*)p)[i];
    f32x4 b = ((const f32x4*)p)[i + S];
    f32x4 c = ((const f32x4*)p)[i + 2 * S];
    f32x4 d = ((const f32x4*)p)[i + 3 * S];
    f32x4 hv = ((const f32x4*)h)[i];
    #pragma unroll
    for (int j = 0; j < 4; ++j) hv[j] += (a[j] + b[j]) + (c[j] + d[j]);
    ((f32x4*)h)[i] = hv;

    float ss = hv[0]*hv[0] + hv[1]*hv[1] + hv[2]*hv[2] + hv[3]*hv[3];
    #pragma unroll
    for (int m = 1; m < 64; m <<= 1) ss += __shfl_xor(ss, m, 64);
    __shared__ float red[4];
    if ((tid & 63) == 0) red[tid >> 6] = ss;
    __syncthreads();
    float tot = red[0] + red[1] + red[2] + red[3];
    float inv = rsqrtf(tot * (1.0f / 1024.0f) + RMS_EPS);
    f32x4 wv = *(const f32x4*)(w + tid * 4);
    bf16x4 hv4, lv4;
    #pragma unroll
    for (int j = 0; j < 4; ++j) {
        float x = hv[j] * inv * wv[j];
        bf16_t hb = (bf16_t)x;
        hv4[j] = hb;
        lv4[j] = (bf16_t)(x - (float)hb);
    }
    ((bf16x4*)outh)[i] = hv4;
    ((bf16x4*)outl)[i] = lv4;
}

// Flash attention, triangular-balanced: block (px,hh) handles q-chunks
// {px, 31-px} (QBLK=32 rows each), KB=64 keys/tile. 2 waves (16 q-rows each).
// Q,K hi-only; V hi+lo; softcap+causal+online softmax fp32; P hi/lo via
// per-wave LDS; 3-term P.V.
__global__ __launch_bounds__(128, 2)
void flash_attn(const bf16_t* __restrict__ qkvh,
                const bf16_t* __restrict__ vTh, const bf16_t* __restrict__ vTl,
                bf16_t* __restrict__ oh, bf16_t* __restrict__ ol)
{
    __shared__ __align__(16) bf16_t sQ[32*64], sK[64*64], sVh[64*64], sVl[64*64];
    __shared__ __align__(16) bf16_t sPh[32*64], sPl[32*64];

    const int px = blockIdx.x;
    const int hh = blockIdx.y;
    const int tid = threadIdx.x, lane = tid & 63, w = tid >> 6;
    const int lr = lane & 15, lg = lane >> 4;

    for (int cc = 0; cc < 2; ++cc) {
        const int qb = cc ? 31 - px : px;
        const int q0 = qb * 32;

        #pragma unroll
        for (int ii = 0; ii < 2; ++ii) {
            int r0 = w * 16 + ii * 8;
            int r  = r0 + (lane >> 3);
            int i  = lane & 7;
            GLDS(qkvh + (size_t)(q0 + r) * 3072 + hh * 64 + ((i ^ (r & 7)) << 3),
                 sQ + r0 * 64);
        }
        __syncthreads();

        bf16x8 qa[2];
        #pragma unroll
        for (int ks = 0; ks < 2; ++ks) {
            int r = w * 16 + lr;
            qa[ks] = *(const bf16x8*)((const char*)sQ + r * 128 +
                                      ((((ks << 2) | lg) ^ (r & 7)) << 4));
        }

        f32x4 o_acc[4];
        #pragma unroll
        for (int n = 0; n < 4; ++n) o_acc[n] = (f32x4){0.f, 0.f, 0.f, 0.f};
        float m_run[4] = {-1e30f, -1e30f, -1e30f, -1e30f};
        float l_run[4] = {0.f, 0.f, 0.f, 0.f};

        const int ntiles = ((q0 + 31) >> 6) + 1;
        for (int t = 0; t < ntiles; ++t) {
            const int kv0 = t * 64;
            #pragma unroll
            for (int ii = 0; ii < 4; ++ii) {
                int r0 = w * 32 + ii * 8;
                int r  = r0 + (lane >> 3);
                int i  = lane & 7;
                GLDS(qkvh + (size_t)(kv0 + r) * 3072 + 1024 + hh * 64 + ((i ^ (r & 7)) << 3),
                     sK + r0 * 64);
                GLDS(vTh + (size_t)(hh * 64 + r) * 1024 + kv0 + ((i ^ (r & 7)) << 3),
                     sVh + r0 * 64);
                GLDS(vTl + (size_t)(hh * 64 + r) * 1024 + kv0 + ((i ^ (r & 7)) << 3),
                     sVl + r0 * 64);
            }
            __syncthreads();

            f32x4 s_acc[4];
            #pragma unroll
            for (int n = 0; n < 4; ++n) s_acc[n] = (f32x4){0.f, 0.f, 0.f, 0.f};
            #pragma unroll
            for (int ks = 0; ks < 2; ++ks)
                #pragma unroll
                for (int n = 0; n < 4; ++n) {
                    int r = n * 16 + lr;
                    bf16x8 kb = *(const bf16x8*)((const char*)sK + r * 128 +
                                                 ((((ks << 2) | lg) ^ (r & 7)) << 4));
                    s_acc[n] = mfma16(qa[ks], kb, s_acc[n]);
                }

            #pragma unroll
            for (int j = 0; j < 4; ++j) {
                int qr = q0 + w * 16 + lg * 4 + j;
                float p[4];
                float mx = -1e30f;
                #pragma unroll
                for (int n = 0; n < 4; ++n) {
                    float v = s_acc[n][j] * 0.125f;
                    v = 50.f * tanhf(v * 0.02f);
                    int key = kv0 + n * 16 + lr;
                    if (key > qr) v = -1e30f;
                    p[n] = v;
                    mx = fmaxf(mx, v);
                }
                #pragma unroll
                for (int m = 1; m < 16; m <<= 1) mx = fmaxf(mx, __shfl_xor(mx, m, 64));
                float mn = fmaxf(m_run[j], mx);
                float ef = __expf(m_run[j] - mn);
                m_run[j] = mn;
                float rs = 0.f;
                #pragma unroll
                for (int n = 0; n < 4; ++n) {
                    float e = expf(p[n] - mn);
                    p[n] = e;
                    rs += e;
                }
                #pragma unroll
                for (int m = 1; m < 16; m <<= 1) rs += __shfl_xor(rs, m, 64);
                l_run[j] = l_run[j] * ef + rs;
                #pragma unroll
                for (int n = 0; n < 4; ++n) o_acc[n][j] *= ef;
                int r = w * 16 + lg * 4 + j;
                #pragma unroll
                for (int n = 0; n < 4; ++n) {
                    int c = n * 16 + lr;
                    int byo = r * 128 + ((((c >> 3) ^ (r & 7)) << 4)) + ((c & 7) << 1);
                    bf16_t hb = (bf16_t)p[n];
                    *(bf16_t*)((char*)sPh + byo) = hb;
                    *(bf16_t*)((char*)sPl + byo) = (bf16_t)(p[n] - (float)hb);
                }
            }

            #pragma unroll
            for (int ks = 0; ks < 2; ++ks) {
                int pr = w * 16 + lr;
                int pby = pr * 128 + ((((ks << 2) | lg) ^ (pr & 7)) << 4);
                bf16x8 pa  = *(const bf16x8*)((const char*)sPh + pby);
                bf16x8 pl_ = *(const bf16x8*)((const char*)sPl + pby);
                #pragma unroll
                for (int n = 0; n < 4; ++n) {
                    int vr = n * 16 + lr;
                    int vby = vr * 128 + ((((ks << 2) | lg) ^ (vr & 7)) << 4);
                    bf16x8 vhf = *(const bf16x8*)((const char*)sVh + vby);
                    bf16x8 vlf = *(const bf16x8*)((const char*)sVl + vby);
                    o_acc[n] = mfma16(pa,  vhf, o_acc[n]);
                    o_acc[n] = mfma16(pl_, vhf, o_acc[n]);
                    o_acc[n] = mfma16(pa,  vlf, o_acc[n]);
                }
            }
            __syncthreads();
        }

        #pragma unroll
        for (int j = 0; j < 4; ++j) {
            float inv = 1.0f / l_run[j];
            int qr = q0 + w * 16 + lg * 4 + j;
            #pragma unroll
            for (int n = 0; n < 4; ++n) {
                float v = o_acc[n][j] * inv;
                size_t off = (size_t)qr * 1024 + hh * 64 + n * 16 + lr;
                bf16_t hb = (bf16_t)v;
                oh[off] = hb;
                ol[off] = (bf16_t)(v - (float)hb);
            }
        }
    }
}

__global__ __launch_bounds__(256)
void split_kernel(const float* __restrict__ src, bf16_t* __restrict__ hi,
                  bf16_t* __restrict__ lo)
{
    size_t i = (size_t)blockIdx.x * 256 + threadIdx.x;
    f32x4 v = ((const f32x4*)src)[i];
    bf16x4 hv, lv;
    #pragma unroll
    for (int j = 0; j < 4; ++j) {
        bf16_t hb = (bf16_t)v[j];
        hv[j] = hb;
        lv[j] = (bf16_t)(v[j] - (float)hb);
    }
    ((bf16x4*)hi)[i] = hv;
    if (lo) ((bf16x4*)lo)[i] = lv;
}

// hi-only weight pack, grid-strided (4 chunks/block, 4096 blocks):
// wq|wk|wv|wo -> wAh [4096x1024]; wg|wu -> wGUh INTERLEAVED [8192x1024]
// (row 2i = wg_i, row 2i+1 = wu_i, for the fused-silu GEMM); wd -> wdh.
__global__ __launch_bounds__(256)
void wsplit_kernel(const float* __restrict__ wq, const float* __restrict__ wk,
                   const float* __restrict__ wv, const float* __restrict__ wo,
                   const float* __restrict__ wg, const float* __restrict__ wu,
                   const float* __restrict__ wd,
                   bf16_t* __restrict__ wAh, bf16_t* __restrict__ wGUh,
                   bf16_t* __restrict__ wdh)
{
    #pragma unroll
    for (int k = 0; k < 4; ++k) {
        int b = blockIdx.x * 4 + k;
        const float* src;
        bf16_t* dst;
        size_t so, doff;
        if (b < 4096) {
            src = b < 1024 ? wq : b < 2048 ? wk : b < 3072 ? wv : wo;
            so = (size_t)(b & 1023) * 256 + threadIdx.x;
            doff = (size_t)b * 256 + threadIdx.x;
            dst = wAh;
        } else if (b < 12288) {
            int bb = b - 4096;
            int row = bb < 4096 ? 2 * bb : 2 * (bb - 4096) + 1;
            src = bb < 4096 ? wg : wu;
            so = (size_t)(bb & 4095) * 256 + threadIdx.x;
            doff = (size_t)row * 256 + threadIdx.x;
            dst = wGUh;
        } else {
            src = wd;
            so = (size_t)(b - 12288) * 256 + threadIdx.x;
            doff = so;
            dst = wdh;
        }
        f32x4 v = ((const f32x4*)src)[so];
        bf16x4 hv;
        #pragma unroll
        for (int j = 0; j < 4; ++j) hv[j] = (bf16_t)v[j];
        ((bf16x4*)dst)[doff] = hv;
    }
}

// Fused: gather embed row by token id, write fp32 residual h, and RMS-norm
// (weight w = ln1 layer 0) -> hi/lo planes.
__global__ __launch_bounds__(256)
void gather_rms(const int* __restrict__ ids, const float* __restrict__ embed,
                const float* __restrict__ w, float* __restrict__ h,
                bf16_t* __restrict__ outh, bf16_t* __restrict__ outl)
{
    int t = blockIdx.x, tid = threadIdx.x;
    int row = ids[t];
    f32x4 v = ((const f32x4*)(embed + (size_t)row * 1024))[tid];
    ((f32x4*)(h + (size_t)t * 1024))[tid] = v;

    float ss = v[0]*v[0] + v[1]*v[1] + v[2]*v[2] + v[3]*v[3];
    #pragma unroll
    for (int m = 1; m < 64; m <<= 1) ss += __shfl_xor(ss, m, 64);
    __shared__ float red[4];
    if ((tid & 63) == 0) red[tid >> 6] = ss;
    __syncthreads();
    float tot = red[0] + red[1] + red[2] + red[3];
    float inv = rsqrtf(tot * (1.0f / 1024.0f) + RMS_EPS);
    f32x4 wv = *(const f32x4*)(w + tid * 4);
    bf16x4 hv, lv;
    #pragma unroll
    for (int j = 0; j < 4; ++j) {
        float x = v[j] * inv * wv[j];
        bf16_t hb = (bf16_t)x;
        hv[j] = hb;
        lv[j] = (bf16_t)(x - (float)hb);
    }
    ((bf16x4*)outh)[(size_t)t * 256 + tid] = hv;
    ((bf16x4*)outl)[(size_t)t * 256 + tid] = lv;
}

__global__ __launch_bounds__(256)
void rmsnorm_split(const float* __restrict__ in, const float* __restrict__ w,
                   bf16_t* __restrict__ outh, bf16_t* __restrict__ outl)
{
    int row = blockIdx.x, tid = threadIdx.x;
    f32x4 v = *(const f32x4*)(in + (size_t)row * 1024 + tid * 4);
    float ss = v[0]*v[0] + v[1]*v[1] + v[2]*v[2] + v[3]*v[3];
    #pragma unroll
    for (int m = 1; m < 64; m <<= 1) ss += __shfl_xor(ss, m, 64);
    __shared__ float red[4];
    if ((tid & 63) == 0) red[tid >> 6] = ss;
    __syncthreads();
    float tot = red[0] + red[1] + red[2] + red[3];
    float inv = rsqrtf(tot * (1.0f / 1024.0f) + RMS_EPS);
    f32x4 wv = *(const f32x4*)(w + tid * 4);
    bf16x4 hv, lv;
    #pragma unroll
    for (int j = 0; j < 4; ++j) {
        float x = v[j] * inv * wv[j];
        bf16_t hb = (bf16_t)x;
        hv[j] = hb;
        lv[j] = (bf16_t)(x - (float)hb);
    }
    ((bf16x4*)outh)[(size_t)row * 256 + tid] = hv;
    ((bf16x4*)outl)[(size_t)row * 256 + tid] = lv;
}

// Merged: blocks 0-1023  = per-(t,head) RMS(Dh=64)+RoPE on packed qkv [1024][3072]
//         blocks 1024-3071 = v (cols 2048-3071) -> vT [1024][1024], hi/lo planes.
// Reference quirk: rotation angle = head_index * freq (cos[:n], n = H).
__global__ __launch_bounds__(256)
void rope_transpose(bf16_t* __restrict__ qkvh, bf16_t* __restrict__ qkvl,
                    const float* __restrict__ qn, const float* __restrict__ kn,
                    bf16_t* __restrict__ vTh, bf16_t* __restrict__ vTl)
{
    __shared__ bf16_t tile[32][33];
    int b = blockIdx.x;
    if (b >= 1024) {
        int t2 = b - 1024;
        int z = t2 >> 10, rem = t2 & 1023;
        const bf16_t* in = z ? qkvl : qkvh;
        bf16_t* out      = z ? vTl : vTh;
        int bx = (rem & 31) * 32, by = (rem >> 5) * 32;
        int r = threadIdx.x >> 5, c = threadIdx.x & 31;
        #pragma unroll
        for (int rr = r; rr < 32; rr += 8)
            tile[rr][c] = in[(size_t)(by + rr) * 3072 + 2048 + bx + c];
        __syncthreads();
        #pragma unroll
        for (int rr = r; rr < 32; rr += 8)
            out[(size_t)(bx + rr) * 1024 + by + c] = tile[c][rr];
        return;
    }

    int t = b, tid = threadIdx.x;
    int hh = tid >> 4;
    int i  = (tid & 15) * 4;
    size_t qb = ((size_t)t * 3072 + hh * 64 + i) >> 2;
    size_t kb = qb + (1024 >> 2);

    int p0 = i >> 1;
    float f0 = powf(10000.f, -(float)p0 / 32.f);
    float f1 = powf(10000.f, -(float)(p0 + 1) / 32.f);
    float a0 = (float)hh * f0, a1 = (float)hh * f1;
    float c0 = cosf(a0), s0 = sinf(a0);
    float c1 = cosf(a1), s1 = sinf(a1);

    f32x4 qw = *(const f32x4*)(qn + i);
    f32x4 kw = *(const f32x4*)(kn + i);

    {
        bf16x4 h4 = ((const bf16x4*)qkvh)[qb], l4 = ((const bf16x4*)qkvl)[qb];
        float x[4];
        #pragma unroll
        for (int j = 0; j < 4; ++j) x[j] = (float)h4[j] + (float)l4[j];
        float ss = x[0]*x[0] + x[1]*x[1] + x[2]*x[2] + x[3]*x[3];
        #pragma unroll
        for (int m = 1; m < 16; m <<= 1) ss += __shfl_xor(ss, m, 64);
        float inv = rsqrtf(ss * (1.0f / 64.0f) + RMS_EPS);
        float x0 = x[0]*inv*qw[0], x1 = x[1]*inv*qw[1];
        float x2 = x[2]*inv*qw[2], x3 = x[3]*inv*qw[3];
        bf16x4 o4;
        o4[0] = (bf16_t)(x0*c0 - x1*s0);  o4[1] = (bf16_t)(x0*s0 + x1*c0);
        o4[2] = (bf16_t)(x2*c1 - x3*s1);  o4[3] = (bf16_t)(x2*s1 + x3*c1);
        ((bf16x4*)qkvh)[qb] = o4;
    }
    {
        bf16x4 h4 = ((const bf16x4*)qkvh)[kb], l4 = ((const bf16x4*)qkvl)[kb];
        float x[4];
        #pragma unroll
        for (int j = 0; j < 4; ++j) x[j] = (float)h4[j] + (float)l4[j];
        float ss = x[0]*x[0] + x[1]*x[1] + x[2]*x[2] + x[3]*x[3];
        #pragma unroll
        for (int m = 1; m < 16; m <<= 1) ss += __shfl_xor(ss, m, 64);
        float inv = rsqrtf(ss * (1.0f / 64.0f) + RMS_EPS);
        float x0 = x[0]*inv*kw[0], x1 = x[1]*inv*kw[1];
        float x2 = x[2]*inv*kw[2], x3 = x[3]*inv*kw[3];
        bf16x4 o4;
        o4[0] = (bf16_t)(x0*c0 - x1*s0);  o4[1] = (bf16_t)(x0*s0 + x1*c0);
        o4[2] = (bf16_t)(x2*c1 - x3*s1);  o4[3] = (bf16_t)(x2*s1 + x3*c1);
        ((bf16x4*)qkvh)[kb] = o4;
    }
}

extern "C" void kernel_launch(void* const* d_in, const int* in_sizes, int n_in,
                              void* d_out, int out_size, void* d_ws, size_t ws_size,
                              hipStream_t stream)
{
    (void)in_sizes; (void)n_in; (void)out_size; (void)ws_size;
    const int*   x_ids = (const int*)  d_in[0];
    const float* embed = (const float*)d_in[1];
    const float* ln1   = (const float*)d_in[2];
    const float* Wq    = (const float*)d_in[3];
    const float* Wk    = (const float*)d_in[4];
    const float* Wv    = (const float*)d_in[5];
    const float* Wo    = (const float*)d_in[6];
    const float* qn    = (const float*)d_in[7];
    const float* kn    = (const float*)d_in[8];
    const float* ln2   = (const float*)d_in[9];
    const float* Wg    = (const float*)d_in[10];
    const float* Wu    = (const float*)d_in[11];
    const float* Wd    = (const float*)d_in[12];
    const float* lnout = (const float*)d_in[13];
    float* out = (float*)d_out;

    char* ws = (char*)d_ws;
    const size_t MB = 1 << 20;
    float*  h    = (float*) (ws +   0 * MB);  // 4 MB fp32 residual
    bf16_t* hnh  = (bf16_t*)(ws +   4 * MB);
    bf16_t* hnl  = (bf16_t*)(ws +   6 * MB);
    bf16_t* qkvh = (bf16_t*)(ws +   8 * MB);  // 6 MB [1024][3072]
    bf16_t* qkvl = (bf16_t*)(ws +  14 * MB);
    bf16_t* vTh  = (bf16_t*)(ws +  20 * MB);
    bf16_t* vTl  = (bf16_t*)(ws +  22 * MB);
    bf16_t* oh   = (bf16_t*)(ws +  24 * MB);
    bf16_t* ol   = (bf16_t*)(ws +  26 * MB);
    bf16_t* wAh  = (bf16_t*)(ws +  28 * MB);  //  8 MB [4096][1024] hi-only
    bf16_t* wGUh = (bf16_t*)(ws +  36 * MB);  // 16 MB [8192][1024] interleaved hi
    bf16_t* wdh  = (bf16_t*)(ws +  52 * MB);  //  8 MB [1024][4096] hi-only
    bf16_t* silh = (bf16_t*)(ws +  60 * MB);  //  8 MB [1024][4096]
    bf16_t* sill = (bf16_t*)(ws +  68 * MB);
    float*  wdp  = (float*) (ws +  76 * MB);  // 16 MB split-K partials [4][1024][1024]
    bf16_t* eh   = (bf16_t*)(ws +  92 * MB);  // 62.5 MB embed hi (high-water ~155 MB)

    const long long M1 = 1024 * 1024;

    gather_rms<<<1024, 256, 0, stream>>>(x_ids, embed, ln1, h, hnh, hnl);

    for (int l = 0; l < 6; ++l) {
        const float* wq = Wq + (size_t)l * M1;
        const float* wk = Wk + (size_t)l * M1;
        const float* wv = Wv + (size_t)l * M1;
        const float* wo = Wo + (size_t)l * M1;
        const float* wg = Wg + (size_t)l * 4 * M1;
        const float* wu = Wu + (size_t)l * 4 * M1;
        const float* wd = Wd + (size_t)l * 4 * M1;

        wsplit_kernel<<<4096, 256, 0, stream>>>(wq, wk, wv, wo, wg, wu, wd,
                                                wAh, wGUh, wdh);

        // fused QKV: [1024][3072] = hn @ wA[0:3072]^T  (2-plane, 64x128 tiles:
        // 384 blocks for full CU coverage — 128^2 left 64 CUs idle)
        gemm_bf16<64,128,2,EP_SPLIT><<<dim3(16,24),256,0,stream>>>(
            hnh, hnl, wAh, nullptr, qkvh, qkvl, 1024, 1024, 1024, 3072, 0);

        rope_transpose<<<3072, 256, 0, stream>>>(qkvh, qkvl, qn + l * 64, kn + l * 64,
                                                 vTh, vTl);

        // fused scores+softcap+mask+softmax+PV (triangular-balanced)
        flash_attn<<<dim3(16,16), 128, 0, stream>>>(qkvh, vTh, vTl, oh, ol);

        // Wo residual (2-plane, 64^2 tiles)
        gemm_bf16<64,64,2,EP_RESID><<<dim3(16,16),256,0,stream>>>(
            oh, ol, wAh + 3 * M1, h, nullptr, nullptr, 1024, 1024, 1024, 1024, 0);

        rmsnorm_split<<<1024, 256, 0, stream>>>(h, ln2 + l * 1024, hnh, hnl);

        // fused gate+up+silu: logical [1024][8192] gu, writes sil [1024][4096]
        gemm_bf16<128,128,2,EP_SILU><<<dim3(8,64),256,0,stream>>>(
            hnh, hnl, wGUh, nullptr, silh, sill, 1024, 1024, 1024, 4096, 0);

        // down-proj: split-K x4 (2-plane) -> partials
        gemm_bf16<128,128,2,EP_STORE><<<dim3(8,8,4),256,0,stream>>>(
            silh, sill, wdh, wdp, nullptr, nullptr, 1024, 4096, 4096, 1024, M1);

        // reduce partials into h + next pre-norm (ln1[l+1], or ln_out after last)
        const float* wnext = (l < 5) ? (ln1 + (l + 1) * 1024) : lnout;
        reduce4_rms<<<1024, 256, 0, stream>>>(wdp, h, wnext, hnh, hnl);
    }

    split_kernel<<<32000, 256, 0, stream>>>(embed, eh, nullptr);
    // logits (1-plane, 3-buffer deep pipeline): [1024][32000]
    gemm_logits<<<dim3(8,250), 256, 0, stream>>>(hnh, eh, out);
}

// Round 10
// 1324.554 us; speedup vs baseline: 5.8932x; 1.0598x over previous
//
#include <hip/hip_runtime.h>
#include <math.h>
#include <type_traits>

typedef __bf16 bf16_t;
typedef bf16_t bf16x4 __attribute__((ext_vector_type(4)));
typedef bf16_t bf16x8 __attribute__((ext_vector_type(8)));
typedef float  f32x4  __attribute__((ext_vector_type(4)));

#define RMS_EPS 1e-6f

enum { EP_STORE = 0, EP_RESID = 1, EP_SPLIT = 2, EP_SILU = 3 };

template<int V> using IC = std::integral_constant<int, V>;

static __device__ __forceinline__ f32x4 mfma16(bf16x8 a, bf16x8 b, f32x4 c) {
    return __builtin_amdgcn_mfma_f32_16x16x32_bf16(a, b, c, 0, 0, 0);
}

#define GLDS(gp, lp) __builtin_amdgcn_global_load_lds( \
    (const __attribute__((address_space(1))) void*)(gp), \
    (__attribute__((address_space(3))) void*)(lp), 16, 0, 0)

// counted vector-memory wait (T4): leave N newest loads in flight.
template<int N> static __device__ __forceinline__ void vmwait() {
    if constexpr (N == 0)      asm volatile("s_waitcnt vmcnt(0)" ::: "memory");
    else if constexpr (N == 2) asm volatile("s_waitcnt vmcnt(2)" ::: "memory");
    else if constexpr (N == 3) asm volatile("s_waitcnt vmcnt(3)" ::: "memory");
    else if constexpr (N == 4) asm volatile("s_waitcnt vmcnt(4)" ::: "memory");
    else if constexpr (N == 6) asm volatile("s_waitcnt vmcnt(6)" ::: "memory");
    else if constexpr (N == 8) asm volatile("s_waitcnt vmcnt(8)" ::: "memory");
    __builtin_amdgcn_sched_barrier(0);
}
static __device__ __forceinline__ void bar() { __builtin_amdgcn_s_barrier(); }

// C[M,N] = A[M,K]*B[N,K]^T.
// PLANES==2: A split hi/lo, B hi-only (2 MFMAs).  PLANES==1: pure bf16 (1 MFMA).
// K-loop: counted-vmcnt double-buffered pipeline.
// blockIdx.z = K-chunk for split-K (A/B advance z*K cols; C advances z*sC).
template<int BM, int BN, int PLANES, int EPIL>
__global__ __launch_bounds__(256, (PLANES >= 2 && BM == 128) ? 3 : 4)
void gemm_bf16(const bf16_t* __restrict__ Ah, const bf16_t* __restrict__ Al,
               const bf16_t* __restrict__ Bh,
               float* __restrict__ Cf, bf16_t* __restrict__ Ch, bf16_t* __restrict__ Cl,
               int K, int lda, int ldb, int ldc, long long sC)
{
    constexpr int ASZ = BM * 32, BSZ = BN * 32;
    constexpr int NLD = (BM / 64) * (PLANES >= 2 ? 2 : 1) + (BN / 64);
    __shared__ __align__(16) bf16_t sAh[2][ASZ], sBh[2][BSZ];
    __shared__ __align__(16) bf16_t sAl[PLANES >= 2 ? 2 : 1][PLANES >= 2 ? ASZ : 8];

    const int gx = gridDim.x;
    int id = blockIdx.x + gx * blockIdx.y;
    if (gridDim.z == 1) {  // bijective XCD swizzle (m204)
        int nwg = gx * gridDim.y;
        int q = nwg >> 3, r = nwg & 7;
        int xcd = id & 7, ix = id >> 3;
        id = (xcd < r ? xcd * (q + 1) : r * (q + 1) + (xcd - r) * q) + ix;
    }
    const int bm = id % gx, bn = id / gx;
    const int row0 = bm * BM, col0 = bn * BN;

    const size_t kofs = (size_t)blockIdx.z * K;
    Ah += kofs;  Bh += kofs;
    if constexpr (PLANES >= 2) Al += kofs;

    const int tid = threadIdx.x, lane = tid & 63, wave = tid >> 6;
    const int lr = lane & 15, lg = lane >> 4;
    constexpr int WM = BM / 2, WN = BN / 2, MF = WM / 16, NF = WN / 16;
    const int wm = wave >> 1, wn = wave & 1;

    f32x4 acc[MF][NF];
    #pragma unroll
    for (int m = 0; m < MF; ++m)
        #pragma unroll
        for (int n = 0; n < NF; ++n) acc[m][n] = (f32x4){0.f, 0.f, 0.f, 0.f};

    auto stage = [&](int k0, auto pc) {
        constexpr int p = decltype(pc)::value;
        #pragma unroll
        for (int i = wave; i < BM / 16; i += 4) {
            int s = i * 64 + lane, rr = s >> 2, c = s & 3;
            size_t go = (size_t)(row0 + rr) * lda + k0 + ((c ^ ((rr >> 1) & 3)) << 3);
            GLDS(Ah + go, &sAh[p][i * 512]);
            if constexpr (PLANES >= 2) GLDS(Al + go, &sAl[p][i * 512]);
        }
        #pragma unroll
        for (int i = wave; i < BN / 16; i += 4) {
            int s = i * 64 + lane, rr = s >> 2, c = s & 3;
            size_t go = (size_t)(col0 + rr) * ldb + k0 + ((c ^ ((rr >> 1) & 3)) << 3);
            GLDS(Bh + go, &sBh[p][i * 512]);
        }
    };

    auto compute = [&](auto pc) {
        constexpr int p = decltype(pc)::value;
        bf16x8 ahf[MF], alf[MF], bhf[NF];
        #pragma unroll
        for (int m = 0; m < MF; ++m) {
            int rr = wm * WM + m * 16 + lr;
            int by = rr * 64 + ((lg ^ ((rr >> 1) & 3)) << 4);
            ahf[m] = *(const bf16x8*)((const char*)&sAh[p][0] + by);
            if constexpr (PLANES >= 2)
                alf[m] = *(const bf16x8*)((const char*)&sAl[p][0] + by);
        }
        #pragma unroll
        for (int n = 0; n < NF; ++n) {
            int rr = wn * WN + n * 16 + lr;
            int by = rr * 64 + ((lg ^ ((rr >> 1) & 3)) << 4);
            bhf[n] = *(const bf16x8*)((const char*)&sBh[p][0] + by);
        }
        #pragma unroll
        for (int m = 0; m < MF; ++m)
            #pragma unroll
            for (int n = 0; n < NF; ++n) {
                acc[m][n] = mfma16(ahf[m], bhf[n], acc[m][n]);
                if constexpr (PLANES >= 2)
                    acc[m][n] = mfma16(alf[m], bhf[n], acc[m][n]);
            }
    };

    stage(0, IC<0>{});
    int k0 = 32;
    for (; k0 + 32 < K; k0 += 64) {
        stage(k0, IC<1>{});
        vmwait<NLD>(); bar();
        compute(IC<0>{});
        bar();
        stage(k0 + 32, IC<0>{});
        vmwait<NLD>(); bar();
        compute(IC<1>{});
        bar();
    }
    stage(k0, IC<1>{});
    vmwait<NLD>(); bar();
    compute(IC<0>{});
    bar();
    vmwait<0>(); bar();
    compute(IC<1>{});

    #pragma unroll
    for (int m = 0; m < MF; ++m)
        #pragma unroll
        for (int n = 0; n < NF; ++n)
            #pragma unroll
            for (int r = 0; r < 4; ++r) {
                int grow = row0 + wm * WM + m * 16 + lg * 4 + r;
                int gcol = col0 + wn * WN + n * 16 + lr;
                float v = acc[m][n][r];
                if constexpr (EPIL == EP_SILU) {
                    float pv = __shfl_xor(v, 1, 64);   // partner column (g,u pair)
                    if (!(lr & 1)) {
                        float s = (v / (1.0f + expf(-v))) * pv;
                        size_t off = (size_t)grow * ldc + (gcol >> 1);
                        bf16_t hb = (bf16_t)s;
                        Ch[off] = hb;
                        Cl[off] = (bf16_t)(s - (float)hb);
                    }
                } else {
                    size_t off = (size_t)blockIdx.z * sC + (size_t)grow * ldc + gcol;
                    if constexpr (EPIL == EP_STORE) {
                        Cf[off] = v;
                    } else if constexpr (EPIL == EP_RESID) {
                        Cf[off] += v;
                    } else {  // EP_SPLIT
                        bf16_t hb = (bf16_t)v;
                        Ch[off] = hb;
                        Cl[off] = (bf16_t)(v - (float)hb);
                    }
                }
            }
}

// Logits GEMM, specialized: C[1024,32000] = A[1024,1024] * B[32000,1024]^T,
// hi-only (1 MFMA). TRIPLE-buffered LDS: stage chunk j+2 while computing j ->
// 2-phase load-latency cover; vmcnt(8) leaves 2 stages in flight.
__global__ __launch_bounds__(256, 3)
void gemm_logits(const bf16_t* __restrict__ Ah, const bf16_t* __restrict__ Bh,
                 float* __restrict__ Cf)
{
    constexpr int lda = 1024, ldb = 1024, ldc = 32000;
    __shared__ __align__(16) bf16_t sA[3][128 * 32], sB[3][128 * 32];

    const int gx = gridDim.x;
    int id = blockIdx.x + gx * blockIdx.y;
    {   // bijective XCD swizzle
        int nwg = gx * gridDim.y;
        int q = nwg >> 3, r = nwg & 7;
        int xcd = id & 7, ix = id >> 3;
        id = (xcd < r ? xcd * (q + 1) : r * (q + 1) + (xcd - r) * q) + ix;
    }
    const int bm = id % gx, bn = id / gx;
    const int row0 = bm * 128, col0 = bn * 128;

    const int tid = threadIdx.x, lane = tid & 63, wave = tid >> 6;
    const int lr = lane & 15, lg = lane >> 4;
    const int wm = wave >> 1, wn = wave & 1;

    f32x4 acc[4][4];
    #pragma unroll
    for (int m = 0; m < 4; ++m)
        #pragma unroll
        for (int n = 0; n < 4; ++n) acc[m][n] = (f32x4){0.f, 0.f, 0.f, 0.f};

    auto stage = [&](int k0, int p) {
        #pragma unroll
        for (int i = wave; i < 8; i += 4) {
            int s = i * 64 + lane, rr = s >> 2, c = s & 3;
            size_t go = (size_t)(row0 + rr) * lda + k0 + ((c ^ ((rr >> 1) & 3)) << 3);
            GLDS(Ah + go, &sA[p][i * 512]);
        }
        #pragma unroll
        for (int i = wave; i < 8; i += 4) {
            int s = i * 64 + lane, rr = s >> 2, c = s & 3;
            size_t go = (size_t)(col0 + rr) * ldb + k0 + ((c ^ ((rr >> 1) & 3)) << 3);
            GLDS(Bh + go, &sB[p][i * 512]);
        }
    };

    auto compute = [&](int p) {
        bf16x8 af[4], bf[4];
        #pragma unroll
        for (int m = 0; m < 4; ++m) {
            int rr = wm * 64 + m * 16 + lr;
            int by = rr * 64 + ((lg ^ ((rr >> 1) & 3)) << 4);
            af[m] = *(const bf16x8*)((const char*)&sA[p][0] + by);
        }
        #pragma unroll
        for (int n = 0; n < 4; ++n) {
            int rr = wn * 64 + n * 16 + lr;
            int by = rr * 64 + ((lg ^ ((rr >> 1) & 3)) << 4);
            bf[n] = *(const bf16x8*)((const char*)&sB[p][0] + by);
        }
        #pragma unroll
        for (int m = 0; m < 4; ++m)
            #pragma unroll
            for (int n = 0; n < 4; ++n)
                acc[m][n] = mfma16(af[m], bf[n], acc[m][n]);
    };

    stage(0, 0);
    stage(32, 1);
    for (int j = 0; j < 30; ++j) {
        stage(32 * (j + 2), (j + 2) % 3);
        vmwait<8>(); bar();
        compute(j % 3);
        bar();
    }
    vmwait<4>(); bar();
    compute(0);
    vmwait<0>(); bar();
    compute(1);

    #pragma unroll
    for (int m = 0; m < 4; ++m)
        #pragma unroll
        for (int n = 0; n < 4; ++n)
            #pragma unroll
            for (int r = 0; r < 4; ++r) {
                int grow = row0 + wm * 64 + m * 16 + lg * 4 + r;
                int gcol = col0 + wn * 64 + n * 16 + lr;
                Cf[(size_t)grow * ldc + gcol] = acc[m][n][r];
            }
}

// h += sum of 4 split-K partials (one row per block), then RMS-norm the new
// row with weight w -> hi plane (no consumer of hn-lo remains).
__global__ __launch_bounds__(256)
void reduce4_rms(const float* __restrict__ p, float* __restrict__ h,
                 const float* __restrict__ w, bf16_t* __restrict__ outh)
{
    int row = blockIdx.x, tid = threadIdx.x;
    size_t i = (size_t)row * 256 + tid;
    const size_t S = (1024 * 1024) / 4;
    f32x4 a = ((const f32x4*)p)[i];
    f32x4 b = ((const f32x4*)p)[i + S];
    f32x4 c = ((const f32x4*)p)[i + 2 * S];
    f32x4 d = ((const f32x4*)p)[i + 3 * S];
    f32x4 hv = ((const f32x4*)h)[i];
    #pragma unroll
    for (int j = 0; j < 4; ++j) hv[j] += (a[j] + b[j]) + (c[j] + d[j]);
    ((f32x4*)h)[i] = hv;

    float ss = hv[0]*hv[0] + hv[1]*hv[1] + hv[2]*hv[2] + hv[3]*hv[3];
    #pragma unroll
    for (int m = 1; m < 64; m <<= 1) ss += __shfl_xor(ss, m, 64);
    __shared__ float red[4];
    if ((tid & 63) == 0) red[tid >> 6] = ss;
    __syncthreads();
    float tot = red[0] + red[1] + red[2] + red[3];
    float inv = rsqrtf(tot * (1.0f / 1024.0f) + RMS_EPS);
    f32x4 wv = *(const f32x4*)(w + tid * 4);
    bf16x4 hv4;
    #pragma unroll
    for (int j = 0; j < 4; ++j) hv4[j] = (bf16_t)(hv[j] * inv * wv[j]);
    ((bf16x4*)outh)[i] = hv4;
}

// Flash attention, triangular-balanced: block (px,hh) handles q-chunks
// {px, 31-px} (QBLK=32 rows each), KB=64 keys/tile. 2 waves (16 q-rows each).
// Q,K hi-only; V hi+lo; softcap+causal+online softmax fp32; P hi/lo via
// per-wave LDS; 3-term P.V. O written hi+lo (Wo GEMM keeps activation split).
__global__ __launch_bounds__(128, 2)
void flash_attn(const bf16_t* __restrict__ qkvh,
                const bf16_t* __restrict__ vTh, const bf16_t* __restrict__ vTl,
                bf16_t* __restrict__ oh, bf16_t* __restrict__ ol)
{
    __shared__ __align__(16) bf16_t sQ[32*64], sK[64*64], sVh[64*64], sVl[64*64];
    __shared__ __align__(16) bf16_t sPh[32*64], sPl[32*64];

    const int px = blockIdx.x;
    const int hh = blockIdx.y;
    const int tid = threadIdx.x, lane = tid & 63, w = tid >> 6;
    const int lr = lane & 15, lg = lane >> 4;

    for (int cc = 0; cc < 2; ++cc) {
        const int qb = cc ? 31 - px : px;
        const int q0 = qb * 32;

        #pragma unroll
        for (int ii = 0; ii < 2; ++ii) {
            int r0 = w * 16 + ii * 8;
            int r  = r0 + (lane >> 3);
            int i  = lane & 7;
            GLDS(qkvh + (size_t)(q0 + r) * 3072 + hh * 64 + ((i ^ (r & 7)) << 3),
                 sQ + r0 * 64);
        }
        __syncthreads();

        bf16x8 qa[2];
        #pragma unroll
        for (int ks = 0; ks < 2; ++ks) {
            int r = w * 16 + lr;
            qa[ks] = *(const bf16x8*)((const char*)sQ + r * 128 +
                                      ((((ks << 2) | lg) ^ (r & 7)) << 4));
        }

        f32x4 o_acc[4];
        #pragma unroll
        for (int n = 0; n < 4; ++n) o_acc[n] = (f32x4){0.f, 0.f, 0.f, 0.f};
        float m_run[4] = {-1e30f, -1e30f, -1e30f, -1e30f};
        float l_run[4] = {0.f, 0.f, 0.f, 0.f};

        const int ntiles = ((q0 + 31) >> 6) + 1;
        for (int t = 0; t < ntiles; ++t) {
            const int kv0 = t * 64;
            #pragma unroll
            for (int ii = 0; ii < 4; ++ii) {
                int r0 = w * 32 + ii * 8;
                int r  = r0 + (lane >> 3);
                int i  = lane & 7;
                GLDS(qkvh + (size_t)(kv0 + r) * 3072 + 1024 + hh * 64 + ((i ^ (r & 7)) << 3),
                     sK + r0 * 64);
                GLDS(vTh + (size_t)(hh * 64 + r) * 1024 + kv0 + ((i ^ (r & 7)) << 3),
                     sVh + r0 * 64);
                GLDS(vTl + (size_t)(hh * 64 + r) * 1024 + kv0 + ((i ^ (r & 7)) << 3),
                     sVl + r0 * 64);
            }
            __syncthreads();

            f32x4 s_acc[4];
            #pragma unroll
            for (int n = 0; n < 4; ++n) s_acc[n] = (f32x4){0.f, 0.f, 0.f, 0.f};
            #pragma unroll
            for (int ks = 0; ks < 2; ++ks)
                #pragma unroll
                for (int n = 0; n < 4; ++n) {
                    int r = n * 16 + lr;
                    bf16x8 kb = *(const bf16x8*)((const char*)sK + r * 128 +
                                                 ((((ks << 2) | lg) ^ (r & 7)) << 4));
                    s_acc[n] = mfma16(qa[ks], kb, s_acc[n]);
                }

            #pragma unroll
            for (int j = 0; j < 4; ++j) {
                int qr = q0 + w * 16 + lg * 4 + j;
                float p[4];
                float mx = -1e30f;
                #pragma unroll
                for (int n = 0; n < 4; ++n) {
                    float v = s_acc[n][j] * 0.125f;
                    v = 50.f * tanhf(v * 0.02f);
                    int key = kv0 + n * 16 + lr;
                    if (key > qr) v = -1e30f;
                    p[n] = v;
                    mx = fmaxf(mx, v);
                }
                #pragma unroll
                for (int m = 1; m < 16; m <<= 1) mx = fmaxf(mx, __shfl_xor(mx, m, 64));
                float mn = fmaxf(m_run[j], mx);
                float ef = __expf(m_run[j] - mn);
                m_run[j] = mn;
                float rs = 0.f;
                #pragma unroll
                for (int n = 0; n < 4; ++n) {
                    float e = expf(p[n] - mn);
                    p[n] = e;
                    rs += e;
                }
                #pragma unroll
                for (int m = 1; m < 16; m <<= 1) rs += __shfl_xor(rs, m, 64);
                l_run[j] = l_run[j] * ef + rs;
                #pragma unroll
                for (int n = 0; n < 4; ++n) o_acc[n][j] *= ef;
                int r = w * 16 + lg * 4 + j;
                #pragma unroll
                for (int n = 0; n < 4; ++n) {
                    int c = n * 16 + lr;
                    int byo = r * 128 + ((((c >> 3) ^ (r & 7)) << 4)) + ((c & 7) << 1);
                    bf16_t hb = (bf16_t)p[n];
                    *(bf16_t*)((char*)sPh + byo) = hb;
                    *(bf16_t*)((char*)sPl + byo) = (bf16_t)(p[n] - (float)hb);
                }
            }

            #pragma unroll
            for (int ks = 0; ks < 2; ++ks) {
                int pr = w * 16 + lr;
                int pby = pr * 128 + ((((ks << 2) | lg) ^ (pr & 7)) << 4);
                bf16x8 pa  = *(const bf16x8*)((const char*)sPh + pby);
                bf16x8 pl_ = *(const bf16x8*)((const char*)sPl + pby);
                #pragma unroll
                for (int n = 0; n < 4; ++n) {
                    int vr = n * 16 + lr;
                    int vby = vr * 128 + ((((ks << 2) | lg) ^ (vr & 7)) << 4);
                    bf16x8 vhf = *(const bf16x8*)((const char*)sVh + vby);
                    bf16x8 vlf = *(const bf16x8*)((const char*)sVl + vby);
                    o_acc[n] = mfma16(pa,  vhf, o_acc[n]);
                    o_acc[n] = mfma16(pl_, vhf, o_acc[n]);
                    o_acc[n] = mfma16(pa,  vlf, o_acc[n]);
                }
            }
            __syncthreads();
        }

        #pragma unroll
        for (int j = 0; j < 4; ++j) {
            float inv = 1.0f / l_run[j];
            int qr = q0 + w * 16 + lg * 4 + j;
            #pragma unroll
            for (int n = 0; n < 4; ++n) {
                float v = o_acc[n][j] * inv;
                size_t off = (size_t)qr * 1024 + hh * 64 + n * 16 + lr;
                bf16_t hb = (bf16_t)v;
                oh[off] = hb;
                ol[off] = (bf16_t)(v - (float)hb);
            }
        }
    }
}

__global__ __launch_bounds__(256)
void split_kernel(const float* __restrict__ src, bf16_t* __restrict__ hi,
                  bf16_t* __restrict__ lo)
{
    size_t i = (size_t)blockIdx.x * 256 + threadIdx.x;
    f32x4 v = ((const f32x4*)src)[i];
    bf16x4 hv, lv;
    #pragma unroll
    for (int j = 0; j < 4; ++j) {
        bf16_t hb = (bf16_t)v[j];
        hv[j] = hb;
        lv[j] = (bf16_t)(v[j] - (float)hb);
    }
    ((bf16x4*)hi)[i] = hv;
    if (lo) ((bf16x4*)lo)[i] = lv;
}

// hi-only weight pack, grid-strided (4 chunks/block, 4096 blocks):
// wq|wk|wv|wo -> wAh [4096x1024]; wg|wu -> wGUh INTERLEAVED [8192x1024]
// (row 2i = wg_i, row 2i+1 = wu_i, for the fused-silu GEMM); wd -> wdh.
__global__ __launch_bounds__(256)
void wsplit_kernel(const float* __restrict__ wq, const float* __restrict__ wk,
                   const float* __restrict__ wv, const float* __restrict__ wo,
                   const float* __restrict__ wg, const float* __restrict__ wu,
                   const float* __restrict__ wd,
                   bf16_t* __restrict__ wAh, bf16_t* __restrict__ wGUh,
                   bf16_t* __restrict__ wdh)
{
    #pragma unroll
    for (int k = 0; k < 4; ++k) {
        int b = blockIdx.x * 4 + k;
        const float* src;
        bf16_t* dst;
        size_t so, doff;
        if (b < 4096) {
            src = b < 1024 ? wq : b < 2048 ? wk : b < 3072 ? wv : wo;
            so = (size_t)(b & 1023) * 256 + threadIdx.x;
            doff = (size_t)b * 256 + threadIdx.x;
            dst = wAh;
        } else if (b < 12288) {
            int bb = b - 4096;
            int row = bb < 4096 ? 2 * bb : 2 * (bb - 4096) + 1;
            src = bb < 4096 ? wg : wu;
            so = (size_t)(bb & 4095) * 256 + threadIdx.x;
            doff = (size_t)row * 256 + threadIdx.x;
            dst = wGUh;
        } else {
            src = wd;
            so = (size_t)(b - 12288) * 256 + threadIdx.x;
            doff = so;
            dst = wdh;
        }
        f32x4 v = ((const f32x4*)src)[so];
        bf16x4 hv;
        #pragma unroll
        for (int j = 0; j < 4; ++j) hv[j] = (bf16_t)v[j];
        ((bf16x4*)dst)[doff] = hv;
    }
}

// Fused: gather embed row by token id, write fp32 residual h, RMS-norm -> hi.
__global__ __launch_bounds__(256)
void gather_rms(const int* __restrict__ ids, const float* __restrict__ embed,
                const float* __restrict__ w, float* __restrict__ h,
                bf16_t* __restrict__ outh)
{
    int t = blockIdx.x, tid = threadIdx.x;
    int row = ids[t];
    f32x4 v = ((const f32x4*)(embed + (size_t)row * 1024))[tid];
    ((f32x4*)(h + (size_t)t * 1024))[tid] = v;

    float ss = v[0]*v[0] + v[1]*v[1] + v[2]*v[2] + v[3]*v[3];
    #pragma unroll
    for (int m = 1; m < 64; m <<= 1) ss += __shfl_xor(ss, m, 64);
    __shared__ float red[4];
    if ((tid & 63) == 0) red[tid >> 6] = ss;
    __syncthreads();
    float tot = red[0] + red[1] + red[2] + red[3];
    float inv = rsqrtf(tot * (1.0f / 1024.0f) + RMS_EPS);
    f32x4 wv = *(const f32x4*)(w + tid * 4);
    bf16x4 hv;
    #pragma unroll
    for (int j = 0; j < 4; ++j) hv[j] = (bf16_t)(v[j] * inv * wv[j]);
    ((bf16x4*)outh)[(size_t)t * 256 + tid] = hv;
}

__global__ __launch_bounds__(256)
void rmsnorm_split(const float* __restrict__ in, const float* __restrict__ w,
                   bf16_t* __restrict__ outh)
{
    int row = blockIdx.x, tid = threadIdx.x;
    f32x4 v = *(const f32x4*)(in + (size_t)row * 1024 + tid * 4);
    float ss = v[0]*v[0] + v[1]*v[1] + v[2]*v[2] + v[3]*v[3];
    #pragma unroll
    for (int m = 1; m < 64; m <<= 1) ss += __shfl_xor(ss, m, 64);
    __shared__ float red[4];
    if ((tid & 63) == 0) red[tid >> 6] = ss;
    __syncthreads();
    float tot = red[0] + red[1] + red[2] + red[3];
    float inv = rsqrtf(tot * (1.0f / 1024.0f) + RMS_EPS);
    f32x4 wv = *(const f32x4*)(w + tid * 4);
    bf16x4 hv;
    #pragma unroll
    for (int j = 0; j < 4; ++j) hv[j] = (bf16_t)(v[j] * inv * wv[j]);
    ((bf16x4*)outh)[(size_t)row * 256 + tid] = hv;
}

// Merged: blocks 0-1023  = per-(t,head) RMS(Dh=64)+RoPE on packed qkv [1024][3072]
//         blocks 1024-3071 = v (cols 2048-3071) -> vT [1024][1024], hi/lo planes.
// Reference quirk: rotation angle = head_index * freq (cos[:n], n = H).
__global__ __launch_bounds__(256)
void rope_transpose(bf16_t* __restrict__ qkvh, bf16_t* __restrict__ qkvl,
                    const float* __restrict__ qn, const float* __restrict__ kn,
                    bf16_t* __restrict__ vTh, bf16_t* __restrict__ vTl)
{
    __shared__ bf16_t tile[32][33];
    int b = blockIdx.x;
    if (b >= 1024) {
        int t2 = b - 1024;
        int z = t2 >> 10, rem = t2 & 1023;
        const bf16_t* in = z ? qkvl : qkvh;
        bf16_t* out      = z ? vTl : vTh;
        int bx = (rem & 31) * 32, by = (rem >> 5) * 32;
        int r = threadIdx.x >> 5, c = threadIdx.x & 31;
        #pragma unroll
        for (int rr = r; rr < 32; rr += 8)
            tile[rr][c] = in[(size_t)(by + rr) * 3072 + 2048 + bx + c];
        __syncthreads();
        #pragma unroll
        for (int rr = r; rr < 32; rr += 8)
            out[(size_t)(bx + rr) * 1024 + by + c] = tile[c][rr];
        return;
    }

    int t = b, tid = threadIdx.x;
    int hh = tid >> 4;
    int i  = (tid & 15) * 4;
    size_t qb = ((size_t)t * 3072 + hh * 64 + i) >> 2;
    size_t kb = qb + (1024 >> 2);

    int p0 = i >> 1;
    float f0 = powf(10000.f, -(float)p0 / 32.f);
    float f1 = powf(10000.f, -(float)(p0 + 1) / 32.f);
    float a0 = (float)hh * f0, a1 = (float)hh * f1;
    float c0 = cosf(a0), s0 = sinf(a0);
    float c1 = cosf(a1), s1 = sinf(a1);

    f32x4 qw = *(const f32x4*)(qn + i);
    f32x4 kw = *(const f32x4*)(kn + i);

    {
        bf16x4 h4 = ((const bf16x4*)qkvh)[qb], l4 = ((const bf16x4*)qkvl)[qb];
        float x[4];
        #pragma unroll
        for (int j = 0; j < 4; ++j) x[j] = (float)h4[j] + (float)l4[j];
        float ss = x[0]*x[0] + x[1]*x[1] + x[2]*x[2] + x[3]*x[3];
        #pragma unroll
        for (int m = 1; m < 16; m <<= 1) ss += __shfl_xor(ss, m, 64);
        float inv = rsqrtf(ss * (1.0f / 64.0f) + RMS_EPS);
        float x0 = x[0]*inv*qw[0], x1 = x[1]*inv*qw[1];
        float x2 = x[2]*inv*qw[2], x3 = x[3]*inv*qw[3];
        bf16x4 o4;
        o4[0] = (bf16_t)(x0*c0 - x1*s0);  o4[1] = (bf16_t)(x0*s0 + x1*c0);
        o4[2] = (bf16_t)(x2*c1 - x3*s1);  o4[3] = (bf16_t)(x2*s1 + x3*c1);
        ((bf16x4*)qkvh)[qb] = o4;
    }
    {
        bf16x4 h4 = ((const bf16x4*)qkvh)[kb], l4 = ((const bf16x4*)qkvl)[kb];
        float x[4];
        #pragma unroll
        for (int j = 0; j < 4; ++j) x[j] = (float)h4[j] + (float)l4[j];
        float ss = x[0]*x[0] + x[1]*x[1] + x[2]*x[2] + x[3]*x[3];
        #pragma unroll
        for (int m = 1; m < 16; m <<= 1) ss += __shfl_xor(ss, m, 64);
        float inv = rsqrtf(ss * (1.0f / 64.0f) + RMS_EPS);
        float x0 = x[0]*inv*kw[0], x1 = x[1]*inv*kw[1];
        float x2 = x[2]*inv*kw[2], x3 = x[3]*inv*kw[3];
        bf16x4 o4;
        o4[0] = (bf16_t)(x0*c0 - x1*s0);  o4[1] = (bf16_t)(x0*s0 + x1*c0);
        o4[2] = (bf16_t)(x2*c1 - x3*s1);  o4[3] = (bf16_t)(x2*s1 + x3*c1);
        ((bf16x4*)qkvh)[kb] = o4;
    }
}

extern "C" void kernel_launch(void* const* d_in, const int* in_sizes, int n_in,
                              void* d_out, int out_size, void* d_ws, size_t ws_size,
                              hipStream_t stream)
{
    (void)in_sizes; (void)n_in; (void)out_size; (void)ws_size;
    const int*   x_ids = (const int*)  d_in[0];
    const float* embed = (const float*)d_in[1];
    const float* ln1   = (const float*)d_in[2];
    const float* Wq    = (const float*)d_in[3];
    const float* Wk    = (const float*)d_in[4];
    const float* Wv    = (const float*)d_in[5];
    const float* Wo    = (const float*)d_in[6];
    const float* qn    = (const float*)d_in[7];
    const float* kn    = (const float*)d_in[8];
    const float* ln2   = (const float*)d_in[9];
    const float* Wg    = (const float*)d_in[10];
    const float* Wu    = (const float*)d_in[11];
    const float* Wd    = (const float*)d_in[12];
    const float* lnout = (const float*)d_in[13];
    float* out = (float*)d_out;

    char* ws = (char*)d_ws;
    const size_t MB = 1 << 20;
    float*  h    = (float*) (ws +   0 * MB);  // 4 MB fp32 residual
    bf16_t* hnh  = (bf16_t*)(ws +   4 * MB);
    bf16_t* qkvh = (bf16_t*)(ws +   8 * MB);  // 6 MB [1024][3072]
    bf16_t* qkvl = (bf16_t*)(ws +  14 * MB);
    bf16_t* vTh  = (bf16_t*)(ws +  20 * MB);
    bf16_t* vTl  = (bf16_t*)(ws +  22 * MB);
    bf16_t* oh   = (bf16_t*)(ws +  24 * MB);
    bf16_t* ol   = (bf16_t*)(ws +  26 * MB);
    bf16_t* wAh  = (bf16_t*)(ws +  28 * MB);  //  8 MB [4096][1024] hi-only
    bf16_t* wGUh = (bf16_t*)(ws +  36 * MB);  // 16 MB [8192][1024] interleaved hi
    bf16_t* wdh  = (bf16_t*)(ws +  52 * MB);  //  8 MB [1024][4096] hi-only
    bf16_t* silh = (bf16_t*)(ws +  60 * MB);  //  8 MB [1024][4096]
    bf16_t* sill = (bf16_t*)(ws +  68 * MB);
    float*  wdp  = (float*) (ws +  76 * MB);  // 16 MB split-K partials [4][1024][1024]
    bf16_t* eh   = (bf16_t*)(ws +  92 * MB);  // 62.5 MB embed hi (high-water ~155 MB)

    const long long M1 = 1024 * 1024;

    gather_rms<<<1024, 256, 0, stream>>>(x_ids, embed, ln1, h, hnh);

    for (int l = 0; l < 6; ++l) {
        const float* wq = Wq + (size_t)l * M1;
        const float* wk = Wk + (size_t)l * M1;
        const float* wv = Wv + (size_t)l * M1;
        const float* wo = Wo + (size_t)l * M1;
        const float* wg = Wg + (size_t)l * 4 * M1;
        const float* wu = Wu + (size_t)l * 4 * M1;
        const float* wd = Wd + (size_t)l * 4 * M1;

        wsplit_kernel<<<4096, 256, 0, stream>>>(wq, wk, wv, wo, wg, wu, wd,
                                                wAh, wGUh, wdh);

        // fused QKV (1-plane bf16): [1024][3072] = hn @ wA[0:3072]^T
        gemm_bf16<64,128,1,EP_SPLIT><<<dim3(16,24),256,0,stream>>>(
            hnh, nullptr, wAh, nullptr, qkvh, qkvl, 1024, 1024, 1024, 3072, 0);

        rope_transpose<<<3072, 256, 0, stream>>>(qkvh, qkvl, qn + l * 64, kn + l * 64,
                                                 vTh, vTl);

        // fused scores+softcap+mask+softmax+PV (triangular-balanced)
        flash_attn<<<dim3(16,16), 128, 0, stream>>>(qkvh, vTh, vTl, oh, ol);

        // Wo residual (2-plane: O hi/lo kept as precision insurance)
        gemm_bf16<64,64,2,EP_RESID><<<dim3(16,16),256,0,stream>>>(
            oh, ol, wAh + 3 * M1, h, nullptr, nullptr, 1024, 1024, 1024, 1024, 0);

        rmsnorm_split<<<1024, 256, 0, stream>>>(h, ln2 + l * 1024, hnh);

        // fused gate+up+silu (1-plane): writes sil hi/lo [1024][4096]
        gemm_bf16<128,128,1,EP_SILU><<<dim3(8,64),256,0,stream>>>(
            hnh, nullptr, wGUh, nullptr, silh, sill, 1024, 1024, 1024, 4096, 0);

        // down-proj: split-K x4 (2-plane: sil hi/lo kept) -> partials
        gemm_bf16<128,128,2,EP_STORE><<<dim3(8,8,4),256,0,stream>>>(
            silh, sill, wdh, wdp, nullptr, nullptr, 1024, 4096, 4096, 1024, M1);

        // reduce partials into h + next pre-norm (ln1[l+1], or ln_out after last)
        const float* wnext = (l < 5) ? (ln1 + (l + 1) * 1024) : lnout;
        reduce4_rms<<<1024, 256, 0, stream>>>(wdp, h, wnext, hnh);
    }

    split_kernel<<<32000, 256, 0, stream>>>(embed, eh, nullptr);
    // logits (1-plane, 3-buffer deep pipeline): [1024][32000]
    gemm_logits<<<dim3(8,250), 256, 0, stream>>>(hnh, eh, out);
}

// Round 11
// 1226.285 us; speedup vs baseline: 6.3655x; 1.0801x over previous
//
#include <hip/hip_runtime.h>
#include <math.h>
#include <type_traits>

typedef __bf16 bf16_t;
typedef bf16_t bf16x4 __attribute__((ext_vector_type(4)));
typedef bf16_t bf16x8 __attribute__((ext_vector_type(8)));
typedef float  f32x4  __attribute__((ext_vector_type(4)));

#define RMS_EPS 1e-6f

enum { EP_STORE = 0, EP_RESID = 1, EP_SPLIT = 2, EP_SILU = 3 };

template<int V> using IC = std::integral_constant<int, V>;

static __device__ __forceinline__ f32x4 mfma16(bf16x8 a, bf16x8 b, f32x4 c) {
    return __builtin_amdgcn_mfma_f32_16x16x32_bf16(a, b, c, 0, 0, 0);
}

#define GLDS(gp, lp) __builtin_amdgcn_global_load_lds( \
    (const __attribute__((address_space(1))) void*)(gp), \
    (__attribute__((address_space(3))) void*)(lp), 16, 0, 0)

// counted vector-memory wait (T4): leave N newest loads in flight.
template<int N> static __device__ __forceinline__ void vmwait() {
    if constexpr (N == 0)      asm volatile("s_waitcnt vmcnt(0)" ::: "memory");
    else if constexpr (N == 2) asm volatile("s_waitcnt vmcnt(2)" ::: "memory");
    else if constexpr (N == 3) asm volatile("s_waitcnt vmcnt(3)" ::: "memory");
    else if constexpr (N == 4) asm volatile("s_waitcnt vmcnt(4)" ::: "memory");
    else if constexpr (N == 6) asm volatile("s_waitcnt vmcnt(6)" ::: "memory");
    else if constexpr (N == 8) asm volatile("s_waitcnt vmcnt(8)" ::: "memory");
    __builtin_amdgcn_sched_barrier(0);
}
static __device__ __forceinline__ void bar() { __builtin_amdgcn_s_barrier(); }

// C[M,N] = A[M,K]*B[N,K]^T.
// PLANES==2: A split hi/lo, B hi-only (2 MFMAs).  PLANES==1: pure bf16 (1 MFMA).
// K-loop: counted-vmcnt double-buffered pipeline.
// EP_SILU: B is wGU interleaved (row 2i=wg_i, 2i+1=wu_i); even lanes write
//          silu(g)*u (fp32 math) as bf16 hi at col>>1.
// blockIdx.z = K-chunk for split-K (A/B advance z*K cols; C advances z*sC).
template<int BM, int BN, int PLANES, int EPIL>
__global__ __launch_bounds__(256, (PLANES >= 2 && BM == 128) ? 3 : 4)
void gemm_bf16(const bf16_t* __restrict__ Ah, const bf16_t* __restrict__ Al,
               const bf16_t* __restrict__ Bh,
               float* __restrict__ Cf, bf16_t* __restrict__ Ch, bf16_t* __restrict__ Cl,
               int K, int lda, int ldb, int ldc, long long sC)
{
    constexpr int ASZ = BM * 32, BSZ = BN * 32;
    constexpr int NLD = (BM / 64) * (PLANES >= 2 ? 2 : 1) + (BN / 64);
    __shared__ __align__(16) bf16_t sAh[2][ASZ], sBh[2][BSZ];
    __shared__ __align__(16) bf16_t sAl[PLANES >= 2 ? 2 : 1][PLANES >= 2 ? ASZ : 8];

    const int gx = gridDim.x;
    int id = blockIdx.x + gx * blockIdx.y;
    if (gridDim.z == 1) {  // bijective XCD swizzle (m204)
        int nwg = gx * gridDim.y;
        int q = nwg >> 3, r = nwg & 7;
        int xcd = id & 7, ix = id >> 3;
        id = (xcd < r ? xcd * (q + 1) : r * (q + 1) + (xcd - r) * q) + ix;
    }
    const int bm = id % gx, bn = id / gx;
    const int row0 = bm * BM, col0 = bn * BN;

    const size_t kofs = (size_t)blockIdx.z * K;
    Ah += kofs;  Bh += kofs;
    if constexpr (PLANES >= 2) Al += kofs;

    const int tid = threadIdx.x, lane = tid & 63, wave = tid >> 6;
    const int lr = lane & 15, lg = lane >> 4;
    constexpr int WM = BM / 2, WN = BN / 2, MF = WM / 16, NF = WN / 16;
    const int wm = wave >> 1, wn = wave & 1;

    f32x4 acc[MF][NF];
    #pragma unroll
    for (int m = 0; m < MF; ++m)
        #pragma unroll
        for (int n = 0; n < NF; ++n) acc[m][n] = (f32x4){0.f, 0.f, 0.f, 0.f};

    auto stage = [&](int k0, auto pc) {
        constexpr int p = decltype(pc)::value;
        #pragma unroll
        for (int i = wave; i < BM / 16; i += 4) {
            int s = i * 64 + lane, rr = s >> 2, c = s & 3;
            size_t go = (size_t)(row0 + rr) * lda + k0 + ((c ^ ((rr >> 1) & 3)) << 3);
            GLDS(Ah + go, &sAh[p][i * 512]);
            if constexpr (PLANES >= 2) GLDS(Al + go, &sAl[p][i * 512]);
        }
        #pragma unroll
        for (int i = wave; i < BN / 16; i += 4) {
            int s = i * 64 + lane, rr = s >> 2, c = s & 3;
            size_t go = (size_t)(col0 + rr) * ldb + k0 + ((c ^ ((rr >> 1) & 3)) << 3);
            GLDS(Bh + go, &sBh[p][i * 512]);
        }
    };

    auto compute = [&](auto pc) {
        constexpr int p = decltype(pc)::value;
        bf16x8 ahf[MF], alf[MF], bhf[NF];
        #pragma unroll
        for (int m = 0; m < MF; ++m) {
            int rr = wm * WM + m * 16 + lr;
            int by = rr * 64 + ((lg ^ ((rr >> 1) & 3)) << 4);
            ahf[m] = *(const bf16x8*)((const char*)&sAh[p][0] + by);
            if constexpr (PLANES >= 2)
                alf[m] = *(const bf16x8*)((const char*)&sAl[p][0] + by);
        }
        #pragma unroll
        for (int n = 0; n < NF; ++n) {
            int rr = wn * WN + n * 16 + lr;
            int by = rr * 64 + ((lg ^ ((rr >> 1) & 3)) << 4);
            bhf[n] = *(const bf16x8*)((const char*)&sBh[p][0] + by);
        }
        #pragma unroll
        for (int m = 0; m < MF; ++m)
            #pragma unroll
            for (int n = 0; n < NF; ++n) {
                acc[m][n] = mfma16(ahf[m], bhf[n], acc[m][n]);
                if constexpr (PLANES >= 2)
                    acc[m][n] = mfma16(alf[m], bhf[n], acc[m][n]);
            }
    };

    stage(0, IC<0>{});
    int k0 = 32;
    for (; k0 + 32 < K; k0 += 64) {
        stage(k0, IC<1>{});
        vmwait<NLD>(); bar();
        compute(IC<0>{});
        bar();
        stage(k0 + 32, IC<0>{});
        vmwait<NLD>(); bar();
        compute(IC<1>{});
        bar();
    }
    stage(k0, IC<1>{});
    vmwait<NLD>(); bar();
    compute(IC<0>{});
    bar();
    vmwait<0>(); bar();
    compute(IC<1>{});

    #pragma unroll
    for (int m = 0; m < MF; ++m)
        #pragma unroll
        for (int n = 0; n < NF; ++n)
            #pragma unroll
            for (int r = 0; r < 4; ++r) {
                int grow = row0 + wm * WM + m * 16 + lg * 4 + r;
                int gcol = col0 + wn * WN + n * 16 + lr;
                float v = acc[m][n][r];
                if constexpr (EPIL == EP_SILU) {
                    float pv = __shfl_xor(v, 1, 64);   // partner column (g,u pair)
                    if (!(lr & 1)) {
                        float s = (v / (1.0f + expf(-v))) * pv;
                        size_t off = (size_t)grow * ldc + (gcol >> 1);
                        Ch[off] = (bf16_t)s;
                    }
                } else {
                    size_t off = (size_t)blockIdx.z * sC + (size_t)grow * ldc + gcol;
                    if constexpr (EPIL == EP_STORE) {
                        Cf[off] = v;
                    } else if constexpr (EPIL == EP_RESID) {
                        Cf[off] += v;
                    } else {  // EP_SPLIT
                        bf16_t hb = (bf16_t)v;
                        Ch[off] = hb;
                        Cl[off] = (bf16_t)(v - (float)hb);
                    }
                }
            }
}

// Logits GEMM, specialized: C[1024,32000] = A[1024,1024] * B[32000,1024]^T,
// hi-only (1 MFMA). TRIPLE-buffered LDS: stage chunk j+2 while computing j ->
// 2-phase load-latency cover; vmcnt(8) leaves 2 stages in flight.
__global__ __launch_bounds__(256, 3)
void gemm_logits(const bf16_t* __restrict__ Ah, const bf16_t* __restrict__ Bh,
                 float* __restrict__ Cf)
{
    constexpr int lda = 1024, ldb = 1024, ldc = 32000;
    __shared__ __align__(16) bf16_t sA[3][128 * 32], sB[3][128 * 32];

    const int gx = gridDim.x;
    int id = blockIdx.x + gx * blockIdx.y;
    {   // bijective XCD swizzle
        int nwg = gx * gridDim.y;
        int q = nwg >> 3, r = nwg & 7;
        int xcd = id & 7, ix = id >> 3;
        id = (xcd < r ? xcd * (q + 1) : r * (q + 1) + (xcd - r) * q) + ix;
    }
    const int bm = id % gx, bn = id / gx;
    const int row0 = bm * 128, col0 = bn * 128;

    const int tid = threadIdx.x, lane = tid & 63, wave = tid >> 6;
    const int lr = lane & 15, lg = lane >> 4;
    const int wm = wave >> 1, wn = wave & 1;

    f32x4 acc[4][4];
    #pragma unroll
    for (int m = 0; m < 4; ++m)
        #pragma unroll
        for (int n = 0; n < 4; ++n) acc[m][n] = (f32x4){0.f, 0.f, 0.f, 0.f};

    auto stage = [&](int k0, int p) {
        #pragma unroll
        for (int i = wave; i < 8; i += 4) {
            int s = i * 64 + lane, rr = s >> 2, c = s & 3;
            size_t go = (size_t)(row0 + rr) * lda + k0 + ((c ^ ((rr >> 1) & 3)) << 3);
            GLDS(Ah + go, &sA[p][i * 512]);
        }
        #pragma unroll
        for (int i = wave; i < 8; i += 4) {
            int s = i * 64 + lane, rr = s >> 2, c = s & 3;
            size_t go = (size_t)(col0 + rr) * ldb + k0 + ((c ^ ((rr >> 1) & 3)) << 3);
            GLDS(Bh + go, &sB[p][i * 512]);
        }
    };

    auto compute = [&](int p) {
        bf16x8 af[4], bf[4];
        #pragma unroll
        for (int m = 0; m < 4; ++m) {
            int rr = wm * 64 + m * 16 + lr;
            int by = rr * 64 + ((lg ^ ((rr >> 1) & 3)) << 4);
            af[m] = *(const bf16x8*)((const char*)&sA[p][0] + by);
        }
        #pragma unroll
        for (int n = 0; n < 4; ++n) {
            int rr = wn * 64 + n * 16 + lr;
            int by = rr * 64 + ((lg ^ ((rr >> 1) & 3)) << 4);
            bf[n] = *(const bf16x8*)((const char*)&sB[p][0] + by);
        }
        #pragma unroll
        for (int m = 0; m < 4; ++m)
            #pragma unroll
            for (int n = 0; n < 4; ++n)
                acc[m][n] = mfma16(af[m], bf[n], acc[m][n]);
    };

    stage(0, 0);
    stage(32, 1);
    for (int j = 0; j < 30; ++j) {
        stage(32 * (j + 2), (j + 2) % 3);
        vmwait<8>(); bar();
        compute(j % 3);
        bar();
    }
    vmwait<4>(); bar();
    compute(0);
    vmwait<0>(); bar();
    compute(1);

    #pragma unroll
    for (int m = 0; m < 4; ++m)
        #pragma unroll
        for (int n = 0; n < 4; ++n)
            #pragma unroll
            for (int r = 0; r < 4; ++r) {
                int grow = row0 + wm * 64 + m * 16 + lg * 4 + r;
                int gcol = col0 + wn * 64 + n * 16 + lr;
                Cf[(size_t)grow * ldc + gcol] = acc[m][n][r];
            }
}

// h += sum of 4 split-K partials (one row per block), then RMS-norm the new
// row with weight w -> hi plane.
__global__ __launch_bounds__(256)
void reduce4_rms(const float* __restrict__ p, float* __restrict__ h,
                 const float* __restrict__ w, bf16_t* __restrict__ outh)
{
    int row = blockIdx.x, tid = threadIdx.x;
    size_t i = (size_t)row * 256 + tid;
    const size_t S = (1024 * 1024) / 4;
    f32x4 a = ((const f32x4*)p)[i];
    f32x4 b = ((const f32x4*)p)[i + S];
    f32x4 c = ((const f32x4*)p)[i + 2 * S];
    f32x4 d = ((const f32x4*)p)[i + 3 * S];
    f32x4 hv = ((const f32x4*)h)[i];
    #pragma unroll
    for (int j = 0; j < 4; ++j) hv[j] += (a[j] + b[j]) + (c[j] + d[j]);
    ((f32x4*)h)[i] = hv;

    float ss = hv[0]*hv[0] + hv[1]*hv[1] + hv[2]*hv[2] + hv[3]*hv[3];
    #pragma unroll
    for (int m = 1; m < 64; m <<= 1) ss += __shfl_xor(ss, m, 64);
    __shared__ float red[4];
    if ((tid & 63) == 0) red[tid >> 6] = ss;
    __syncthreads();
    float tot = red[0] + red[1] + red[2] + red[3];
    float inv = rsqrtf(tot * (1.0f / 1024.0f) + RMS_EPS);
    f32x4 wv = *(const f32x4*)(w + tid * 4);
    bf16x4 hv4;
    #pragma unroll
    for (int j = 0; j < 4; ++j) hv4[j] = (bf16_t)(hv[j] * inv * wv[j]);
    ((bf16x4*)outh)[i] = hv4;
}

// Flash attention, triangular-balanced: block (px,hh) handles q-chunks
// {px, 31-px} (QBLK=32 rows each), KB=64 keys/tile. 2 waves (16 q-rows each).
// Q,K hi-only; V hi+lo; softcap+causal+online softmax fp32; P hi/lo via
// per-wave LDS; 3-term P.V (keeps O-hi at full fp32 accuracy before rounding).
// O written hi-only (Wo GEMM is 1-plane now).
__global__ __launch_bounds__(128, 2)
void flash_attn(const bf16_t* __restrict__ qkvh,
                const bf16_t* __restrict__ vTh, const bf16_t* __restrict__ vTl,
                bf16_t* __restrict__ oh)
{
    __shared__ __align__(16) bf16_t sQ[32*64], sK[64*64], sVh[64*64], sVl[64*64];
    __shared__ __align__(16) bf16_t sPh[32*64], sPl[32*64];

    const int px = blockIdx.x;
    const int hh = blockIdx.y;
    const int tid = threadIdx.x, lane = tid & 63, w = tid >> 6;
    const int lr = lane & 15, lg = lane >> 4;

    for (int cc = 0; cc < 2; ++cc) {
        const int qb = cc ? 31 - px : px;
        const int q0 = qb * 32;

        #pragma unroll
        for (int ii = 0; ii < 2; ++ii) {
            int r0 = w * 16 + ii * 8;
            int r  = r0 + (lane >> 3);
            int i  = lane & 7;
            GLDS(qkvh + (size_t)(q0 + r) * 3072 + hh * 64 + ((i ^ (r & 7)) << 3),
                 sQ + r0 * 64);
        }
        __syncthreads();

        bf16x8 qa[2];
        #pragma unroll
        for (int ks = 0; ks < 2; ++ks) {
            int r = w * 16 + lr;
            qa[ks] = *(const bf16x8*)((const char*)sQ + r * 128 +
                                      ((((ks << 2) | lg) ^ (r & 7)) << 4));
        }

        f32x4 o_acc[4];
        #pragma unroll
        for (int n = 0; n < 4; ++n) o_acc[n] = (f32x4){0.f, 0.f, 0.f, 0.f};
        float m_run[4] = {-1e30f, -1e30f, -1e30f, -1e30f};
        float l_run[4] = {0.f, 0.f, 0.f, 0.f};

        const int ntiles = ((q0 + 31) >> 6) + 1;
        for (int t = 0; t < ntiles; ++t) {
            const int kv0 = t * 64;
            #pragma unroll
            for (int ii = 0; ii < 4; ++ii) {
                int r0 = w * 32 + ii * 8;
                int r  = r0 + (lane >> 3);
                int i  = lane & 7;
                GLDS(qkvh + (size_t)(kv0 + r) * 3072 + 1024 + hh * 64 + ((i ^ (r & 7)) << 3),
                     sK + r0 * 64);
                GLDS(vTh + (size_t)(hh * 64 + r) * 1024 + kv0 + ((i ^ (r & 7)) << 3),
                     sVh + r0 * 64);
                GLDS(vTl + (size_t)(hh * 64 + r) * 1024 + kv0 + ((i ^ (r & 7)) << 3),
                     sVl + r0 * 64);
            }
            __syncthreads();

            f32x4 s_acc[4];
            #pragma unroll
            for (int n = 0; n < 4; ++n) s_acc[n] = (f32x4){0.f, 0.f, 0.f, 0.f};
            #pragma unroll
            for (int ks = 0; ks < 2; ++ks)
                #pragma unroll
                for (int n = 0; n < 4; ++n) {
                    int r = n * 16 + lr;
                    bf16x8 kb = *(const bf16x8*)((const char*)sK + r * 128 +
                                                 ((((ks << 2) | lg) ^ (r & 7)) << 4));
                    s_acc[n] = mfma16(qa[ks], kb, s_acc[n]);
                }

            #pragma unroll
            for (int j = 0; j < 4; ++j) {
                int qr = q0 + w * 16 + lg * 4 + j;
                float p[4];
                float mx = -1e30f;
                #pragma unroll
                for (int n = 0; n < 4; ++n) {
                    float v = s_acc[n][j] * 0.125f;
                    v = 50.f * tanhf(v * 0.02f);
                    int key = kv0 + n * 16 + lr;
                    if (key > qr) v = -1e30f;
                    p[n] = v;
                    mx = fmaxf(mx, v);
                }
                #pragma unroll
                for (int m = 1; m < 16; m <<= 1) mx = fmaxf(mx, __shfl_xor(mx, m, 64));
                float mn = fmaxf(m_run[j], mx);
                float ef = __expf(m_run[j] - mn);
                m_run[j] = mn;
                float rs = 0.f;
                #pragma unroll
                for (int n = 0; n < 4; ++n) {
                    float e = expf(p[n] - mn);
                    p[n] = e;
                    rs += e;
                }
                #pragma unroll
                for (int m = 1; m < 16; m <<= 1) rs += __shfl_xor(rs, m, 64);
                l_run[j] = l_run[j] * ef + rs;
                #pragma unroll
                for (int n = 0; n < 4; ++n) o_acc[n][j] *= ef;
                int r = w * 16 + lg * 4 + j;
                #pragma unroll
                for (int n = 0; n < 4; ++n) {
                    int c = n * 16 + lr;
                    int byo = r * 128 + ((((c >> 3) ^ (r & 7)) << 4)) + ((c & 7) << 1);
                    bf16_t hb = (bf16_t)p[n];
                    *(bf16_t*)((char*)sPh + byo) = hb;
                    *(bf16_t*)((char*)sPl + byo) = (bf16_t)(p[n] - (float)hb);
                }
            }

            #pragma unroll
            for (int ks = 0; ks < 2; ++ks) {
                int pr = w * 16 + lr;
                int pby = pr * 128 + ((((ks << 2) | lg) ^ (pr & 7)) << 4);
                bf16x8 pa  = *(const bf16x8*)((const char*)sPh + pby);
                bf16x8 pl_ = *(const bf16x8*)((const char*)sPl + pby);
                #pragma unroll
                for (int n = 0; n < 4; ++n) {
                    int vr = n * 16 + lr;
                    int vby = vr * 128 + ((((ks << 2) | lg) ^ (vr & 7)) << 4);
                    bf16x8 vhf = *(const bf16x8*)((const char*)sVh + vby);
                    bf16x8 vlf = *(const bf16x8*)((const char*)sVl + vby);
                    o_acc[n] = mfma16(pa,  vhf, o_acc[n]);
                    o_acc[n] = mfma16(pl_, vhf, o_acc[n]);
                    o_acc[n] = mfma16(pa,  vlf, o_acc[n]);
                }
            }
            __syncthreads();
        }

        #pragma unroll
        for (int j = 0; j < 4; ++j) {
            float inv = 1.0f / l_run[j];
            int qr = q0 + w * 16 + lg * 4 + j;
            #pragma unroll
            for (int n = 0; n < 4; ++n) {
                size_t off = (size_t)qr * 1024 + hh * 64 + n * 16 + lr;
                oh[off] = (bf16_t)(o_acc[n][j] * inv);
            }
        }
    }
}

__global__ __launch_bounds__(256)
void split_kernel(const float* __restrict__ src, bf16_t* __restrict__ hi,
                  bf16_t* __restrict__ lo)
{
    size_t i = (size_t)blockIdx.x * 256 + threadIdx.x;
    f32x4 v = ((const f32x4*)src)[i];
    bf16x4 hv, lv;
    #pragma unroll
    for (int j = 0; j < 4; ++j) {
        bf16_t hb = (bf16_t)v[j];
        hv[j] = hb;
        lv[j] = (bf16_t)(v[j] - (float)hb);
    }
    ((bf16x4*)hi)[i] = hv;
    if (lo) ((bf16x4*)lo)[i] = lv;
}

// hi-only weight pack, grid-strided (4 chunks/block, 4096 blocks):
// wq|wk|wv|wo -> wAh [4096x1024]; wg|wu -> wGUh INTERLEAVED [8192x1024]
// (row 2i = wg_i, row 2i+1 = wu_i, for the fused-silu GEMM); wd -> wdh.
__global__ __launch_bounds__(256)
void wsplit_kernel(const float* __restrict__ wq, const float* __restrict__ wk,
                   const float* __restrict__ wv, const float* __restrict__ wo,
                   const float* __restrict__ wg, const float* __restrict__ wu,
                   const float* __restrict__ wd,
                   bf16_t* __restrict__ wAh, bf16_t* __restrict__ wGUh,
                   bf16_t* __restrict__ wdh)
{
    #pragma unroll
    for (int k = 0; k < 4; ++k) {
        int b = blockIdx.x * 4 + k;
        const float* src;
        bf16_t* dst;
        size_t so, doff;
        if (b < 4096) {
            src = b < 1024 ? wq : b < 2048 ? wk : b < 3072 ? wv : wo;
            so = (size_t)(b & 1023) * 256 + threadIdx.x;
            doff = (size_t)b * 256 + threadIdx.x;
            dst = wAh;
        } else if (b < 12288) {
            int bb = b - 4096;
            int row = bb < 4096 ? 2 * bb : 2 * (bb - 4096) + 1;
            src = bb < 4096 ? wg : wu;
            so = (size_t)(bb & 4095) * 256 + threadIdx.x;
            doff = (size_t)row * 256 + threadIdx.x;
            dst = wGUh;
        } else {
            src = wd;
            so = (size_t)(b - 12288) * 256 + threadIdx.x;
            doff = so;
            dst = wdh;
        }
        f32x4 v = ((const f32x4*)src)[so];
        bf16x4 hv;
        #pragma unroll
        for (int j = 0; j < 4; ++j) hv[j] = (bf16_t)v[j];
        ((bf16x4*)dst)[doff] = hv;
    }
}

// Fused: gather embed row by token id, write fp32 residual h, RMS-norm -> hi.
__global__ __launch_bounds__(256)
void gather_rms(const int* __restrict__ ids, const float* __restrict__ embed,
                const float* __restrict__ w, float* __restrict__ h,
                bf16_t* __restrict__ outh)
{
    int t = blockIdx.x, tid = threadIdx.x;
    int row = ids[t];
    f32x4 v = ((const f32x4*)(embed + (size_t)row * 1024))[tid];
    ((f32x4*)(h + (size_t)t * 1024))[tid] = v;

    float ss = v[0]*v[0] + v[1]*v[1] + v[2]*v[2] + v[3]*v[3];
    #pragma unroll
    for (int m = 1; m < 64; m <<= 1) ss += __shfl_xor(ss, m, 64);
    __shared__ float red[4];
    if ((tid & 63) == 0) red[tid >> 6] = ss;
    __syncthreads();
    float tot = red[0] + red[1] + red[2] + red[3];
    float inv = rsqrtf(tot * (1.0f / 1024.0f) + RMS_EPS);
    f32x4 wv = *(const f32x4*)(w + tid * 4);
    bf16x4 hv;
    #pragma unroll
    for (int j = 0; j < 4; ++j) hv[j] = (bf16_t)(v[j] * inv * wv[j]);
    ((bf16x4*)outh)[(size_t)t * 256 + tid] = hv;
}

__global__ __launch_bounds__(256)
void rmsnorm_split(const float* __restrict__ in, const float* __restrict__ w,
                   bf16_t* __restrict__ outh)
{
    int row = blockIdx.x, tid = threadIdx.x;
    f32x4 v = *(const f32x4*)(in + (size_t)row * 1024 + tid * 4);
    float ss = v[0]*v[0] + v[1]*v[1] + v[2]*v[2] + v[3]*v[3];
    #pragma unroll
    for (int m = 1; m < 64; m <<= 1) ss += __shfl_xor(ss, m, 64);
    __shared__ float red[4];
    if ((tid & 63) == 0) red[tid >> 6] = ss;
    __syncthreads();
    float tot = red[0] + red[1] + red[2] + red[3];
    float inv = rsqrtf(tot * (1.0f / 1024.0f) + RMS_EPS);
    f32x4 wv = *(const f32x4*)(w + tid * 4);
    bf16x4 hv;
    #pragma unroll
    for (int j = 0; j < 4; ++j) hv[j] = (bf16_t)(v[j] * inv * wv[j]);
    ((bf16x4*)outh)[(size_t)row * 256 + tid] = hv;
}

// Merged: blocks 0-1023  = per-(t,head) RMS(Dh=64)+RoPE on packed qkv [1024][3072]
//         blocks 1024-3071 = v (cols 2048-3071) -> vT [1024][1024], hi/lo planes.
// Reference quirk: rotation angle = head_index * freq (cos[:n], n = H).
__global__ __launch_bounds__(256)
void rope_transpose(bf16_t* __restrict__ qkvh, bf16_t* __restrict__ qkvl,
                    const float* __restrict__ qn, const float* __restrict__ kn,
                    bf16_t* __restrict__ vTh, bf16_t* __restrict__ vTl)
{
    __shared__ bf16_t tile[32][33];
    int b = blockIdx.x;
    if (b >= 1024) {
        int t2 = b - 1024;
        int z = t2 >> 10, rem = t2 & 1023;
        const bf16_t* in = z ? qkvl : qkvh;
        bf16_t* out      = z ? vTl : vTh;
        int bx = (rem & 31) * 32, by = (rem >> 5) * 32;
        int r = threadIdx.x >> 5, c = threadIdx.x & 31;
        #pragma unroll
        for (int rr = r; rr < 32; rr += 8)
            tile[rr][c] = in[(size_t)(by + rr) * 3072 + 2048 + bx + c];
        __syncthreads();
        #pragma unroll
        for (int rr = r; rr < 32; rr += 8)
            out[(size_t)(bx + rr) * 1024 + by + c] = tile[c][rr];
        return;
    }

    int t = b, tid = threadIdx.x;
    int hh = tid >> 4;
    int i  = (tid & 15) * 4;
    size_t qb = ((size_t)t * 3072 + hh * 64 + i) >> 2;
    size_t kb = qb + (1024 >> 2);

    int p0 = i >> 1;
    float f0 = powf(10000.f, -(float)p0 / 32.f);
    float f1 = powf(10000.f, -(float)(p0 + 1) / 32.f);
    float a0 = (float)hh * f0, a1 = (float)hh * f1;
    float c0 = cosf(a0), s0 = sinf(a0);
    float c1 = cosf(a1), s1 = sinf(a1);

    f32x4 qw = *(const f32x4*)(qn + i);
    f32x4 kw = *(const f32x4*)(kn + i);

    {
        bf16x4 h4 = ((const bf16x4*)qkvh)[qb], l4 = ((const bf16x4*)qkvl)[qb];
        float x[4];
        #pragma unroll
        for (int j = 0; j < 4; ++j) x[j] = (float)h4[j] + (float)l4[j];
        float ss = x[0]*x[0] + x[1]*x[1] + x[2]*x[2] + x[3]*x[3];
        #pragma unroll
        for (int m = 1; m < 16; m <<= 1) ss += __shfl_xor(ss, m, 64);
        float inv = rsqrtf(ss * (1.0f / 64.0f) + RMS_EPS);
        float x0 = x[0]*inv*qw[0], x1 = x[1]*inv*qw[1];
        float x2 = x[2]*inv*qw[2], x3 = x[3]*inv*qw[3];
        bf16x4 o4;
        o4[0] = (bf16_t)(x0*c0 - x1*s0);  o4[1] = (bf16_t)(x0*s0 + x1*c0);
        o4[2] = (bf16_t)(x2*c1 - x3*s1);  o4[3] = (bf16_t)(x2*s1 + x3*c1);
        ((bf16x4*)qkvh)[qb] = o4;
    }
    {
        bf16x4 h4 = ((const bf16x4*)qkvh)[kb], l4 = ((const bf16x4*)qkvl)[kb];
        float x[4];
        #pragma unroll
        for (int j = 0; j < 4; ++j) x[j] = (float)h4[j] + (float)l4[j];
        float ss = x[0]*x[0] + x[1]*x[1] + x[2]*x[2] + x[3]*x[3];
        #pragma unroll
        for (int m = 1; m < 16; m <<= 1) ss += __shfl_xor(ss, m, 64);
        float inv = rsqrtf(ss * (1.0f / 64.0f) + RMS_EPS);
        float x0 = x[0]*inv*kw[0], x1 = x[1]*inv*kw[1];
        float x2 = x[2]*inv*kw[2], x3 = x[3]*inv*kw[3];
        bf16x4 o4;
        o4[0] = (bf16_t)(x0*c0 - x1*s0);  o4[1] = (bf16_t)(x0*s0 + x1*c0);
        o4[2] = (bf16_t)(x2*c1 - x3*s1);  o4[3] = (bf16_t)(x2*s1 + x3*c1);
        ((bf16x4*)qkvh)[kb] = o4;
    }
}

extern "C" void kernel_launch(void* const* d_in, const int* in_sizes, int n_in,
                              void* d_out, int out_size, void* d_ws, size_t ws_size,
                              hipStream_t stream)
{
    (void)in_sizes; (void)n_in; (void)out_size; (void)ws_size;
    const int*   x_ids = (const int*)  d_in[0];
    const float* embed = (const float*)d_in[1];
    const float* ln1   = (const float*)d_in[2];
    const float* Wq    = (const float*)d_in[3];
    const float* Wk    = (const float*)d_in[4];
    const float* Wv    = (const float*)d_in[5];
    const float* Wo    = (const float*)d_in[6];
    const float* qn    = (const float*)d_in[7];
    const float* kn    = (const float*)d_in[8];
    const float* ln2   = (const float*)d_in[9];
    const float* Wg    = (const float*)d_in[10];
    const float* Wu    = (const float*)d_in[11];
    const float* Wd    = (const float*)d_in[12];
    const float* lnout = (const float*)d_in[13];
    float* out = (float*)d_out;

    char* ws = (char*)d_ws;
    const size_t MB = 1 << 20;
    float*  h    = (float*) (ws +   0 * MB);  // 4 MB fp32 residual
    bf16_t* hnh  = (bf16_t*)(ws +   4 * MB);
    bf16_t* qkvh = (bf16_t*)(ws +   8 * MB);  // 6 MB [1024][3072]
    bf16_t* qkvl = (bf16_t*)(ws +  14 * MB);
    bf16_t* vTh  = (bf16_t*)(ws +  20 * MB);
    bf16_t* vTl  = (bf16_t*)(ws +  22 * MB);
    bf16_t* oh   = (bf16_t*)(ws +  24 * MB);
    bf16_t* wAh  = (bf16_t*)(ws +  28 * MB);  //  8 MB [4096][1024] hi-only
    bf16_t* wGUh = (bf16_t*)(ws +  36 * MB);  // 16 MB [8192][1024] interleaved hi
    bf16_t* wdh  = (bf16_t*)(ws +  52 * MB);  //  8 MB [1024][4096] hi-only
    bf16_t* silh = (bf16_t*)(ws +  60 * MB);  //  8 MB [1024][4096]
    float*  wdp  = (float*) (ws +  68 * MB);  // 16 MB split-K partials [4][1024][1024]
    bf16_t* eh   = (bf16_t*)(ws +  84 * MB);  // 62.5 MB embed hi (high-water ~147 MB)

    const long long M1 = 1024 * 1024;

    gather_rms<<<1024, 256, 0, stream>>>(x_ids, embed, ln1, h, hnh);

    for (int l = 0; l < 6; ++l) {
        const float* wq = Wq + (size_t)l * M1;
        const float* wk = Wk + (size_t)l * M1;
        const float* wv = Wv + (size_t)l * M1;
        const float* wo = Wo + (size_t)l * M1;
        const float* wg = Wg + (size_t)l * 4 * M1;
        const float* wu = Wu + (size_t)l * 4 * M1;
        const float* wd = Wd + (size_t)l * 4 * M1;

        wsplit_kernel<<<4096, 256, 0, stream>>>(wq, wk, wv, wo, wg, wu, wd,
                                                wAh, wGUh, wdh);

        // fused QKV (1-plane bf16): [1024][3072] = hn @ wA[0:3072]^T
        gemm_bf16<64,128,1,EP_SPLIT><<<dim3(16,24),256,0,stream>>>(
            hnh, nullptr, wAh, nullptr, qkvh, qkvl, 1024, 1024, 1024, 3072, 0);

        rope_transpose<<<3072, 256, 0, stream>>>(qkvh, qkvl, qn + l * 64, kn + l * 64,
                                                 vTh, vTl);

        // fused scores+softcap+mask+softmax+PV (triangular-balanced); O hi-only
        flash_attn<<<dim3(16,16), 128, 0, stream>>>(qkvh, vTh, vTl, oh);

        // Wo residual (1-plane bf16, 64^2 tiles)
        gemm_bf16<64,64,1,EP_RESID><<<dim3(16,16),256,0,stream>>>(
            oh, nullptr, wAh + 3 * M1, h, nullptr, nullptr, 1024, 1024, 1024, 1024, 0);

        rmsnorm_split<<<1024, 256, 0, stream>>>(h, ln2 + l * 1024, hnh);

        // fused gate+up+silu (1-plane): writes sil hi [1024][4096]
        gemm_bf16<128,128,1,EP_SILU><<<dim3(8,64),256,0,stream>>>(
            hnh, nullptr, wGUh, nullptr, silh, nullptr, 1024, 1024, 1024, 4096, 0);

        // down-proj: split-K x4 (1-plane bf16) -> partials
        gemm_bf16<128,128,1,EP_STORE><<<dim3(8,8,4),256,0,stream>>>(
            silh, nullptr, wdh, wdp, nullptr, nullptr, 1024, 4096, 4096, 1024, M1);

        // reduce partials into h + next pre-norm (ln1[l+1], or ln_out after last)
        const float* wnext = (l < 5) ? (ln1 + (l + 1) * 1024) : lnout;
        reduce4_rms<<<1024, 256, 0, stream>>>(wdp, h, wnext, hnh);
    }

    split_kernel<<<32000, 256, 0, stream>>>(embed, eh, nullptr);
    // logits (1-plane, 3-buffer deep pipeline): [1024][32000]
    gemm_logits<<<dim3(8,250), 256, 0, stream>>>(hnh, eh, out);
}